// Round 14
// baseline (284.227 us; speedup 1.0000x reference)
//
#include <hip/hip_runtime.h>
#include <hip/hip_fp16.h>
#include <math.h>

constexpr int B = 4, N = 4096, D = 256;
constexpr int BN = B * N;
constexpr float EPS = 1e-5f;
// softmax scale (D^-0.5 = 1/16) * log2(e), folded into q at f16-cast time
constexpr float QSC2 = 0.0625f * 1.44269504088896340736f;

constexpr int SPLIT = 4;     // KV splits -> grid 256 blocks (1/CU)
constexpr int KVB = 32;      // keys per attn tile
constexpr int NTK = (N / SPLIT) / KVB;  // 32 tiles (NTK % 3 == 2 assumed)
constexpr float THR = 8.0f;  // defer-max threshold (base-2)

typedef __attribute__((ext_vector_type(8))) _Float16 f16x8;
typedef __attribute__((ext_vector_type(2))) __fp16 fp16x2;
typedef __attribute__((ext_vector_type(4))) float f32x4;
typedef __attribute__((ext_vector_type(16))) float f32x16;

__device__ inline f32x4 mfma_f16(f16x8 a, f16x8 b, f32x4 c) {
  return __builtin_amdgcn_mfma_f32_16x16x32_f16(a, b, c, 0, 0, 0);
}
__device__ inline f32x16 mfma32(f16x8 a, f16x8 b, f32x16 c) {
  return __builtin_amdgcn_mfma_f32_32x32x16_f16(a, b, c, 0, 0, 0);
}
__device__ inline ushort f2h(float x) {
  __half h = __float2half(x);
  return *(ushort*)&h;
}
__device__ inline float h2f(ushort u) {
  __half h;
  *(ushort*)&h = u;
  return __half2float(h);
}
__device__ inline unsigned pkh(float a, float b) {
  fp16x2 r = __builtin_amdgcn_cvt_pkrtz(a, b);
  return *(unsigned*)&r;
}
// async global->LDS, 16B per lane; lds dest = uniform base + lane*16 (HW rule)
__device__ inline void gload16(const ushort* g, ushort* l) {
  __builtin_amdgcn_global_load_lds(
      (const __attribute__((address_space(1))) void*)g,
      (__attribute__((address_space(3))) void*)l, 16, 0, 0);
}

// ---------------- LayerNorm -> normalized x as f16 hi/lo planes ------------
__global__ __launch_bounds__(256) void ln_kernel(
    const float* __restrict__ x, const float* __restrict__ g,
    const float* __restrict__ bta, ushort* __restrict__ nxh,
    ushort* __restrict__ nxl) {
  const int row = blockIdx.x;
  const int t = threadIdx.x;
  const float v = x[(size_t)row * D + t];
  float s = v, ss = v * v;
#pragma unroll
  for (int o = 32; o > 0; o >>= 1) {
    s += __shfl_down(s, o);
    ss += __shfl_down(ss, o);
  }
  __shared__ float red[8];
  if ((t & 63) == 0) {
    red[t >> 6] = s;
    red[(t >> 6) + 4] = ss;
  }
  __syncthreads();
  s = red[0] + red[1] + red[2] + red[3];
  ss = red[4] + red[5] + red[6] + red[7];
  const float mu = s * (1.0f / D);
  const float var = ss * (1.0f / D) - mu * mu;
  const float rsig = rsqrtf(var + EPS);
  const float nx = (v - mu) * rsig * g[t] + bta[t];
  const ushort h = f2h(nx);
  nxh[(size_t)row * D + t] = h;
  nxl[(size_t)row * D + t] = f2h(nx - h2f(h));
}

// ------------- cast + transpose weights to f16 (wt[768][256], wot[256][256])
__global__ __launch_bounds__(256) void castw_kernel(
    const float* __restrict__ w_qkv, const float* __restrict__ w_out,
    ushort* __restrict__ wt, ushort* __restrict__ wot) {
  const int id = blockIdx.x * 256 + threadIdx.x;
  if (id < 768 * 256) {
    const int n = id >> 8, k = id & 255;
    wt[id] = f2h(w_qkv[(size_t)k * 768 + n]);
  } else {
    const int j = id - 768 * 256;
    const int n = j >> 8, k = j & 255;
    wot[j] = f2h(w_out[(size_t)k * 256 + n]);
  }
}

// ---------------- QKV GEMM via MFMA (no LDS; weights L2-hot) ---------------
__global__ __launch_bounds__(256, 4) void qkv_kernel(
    const ushort* __restrict__ nxh, const ushort* __restrict__ nxl,
    const ushort* __restrict__ wt, const float* __restrict__ coord,
    ushort* __restrict__ qfp, ushort* __restrict__ kfp,
    ushort* __restrict__ vtp) {
  const int t = threadIdx.x;
  const int w = t >> 6, lane = t & 63;
  const int lrow = lane & 15, lhi = lane >> 4;
  const int m0 = blockIdx.x * 128 + w * 32;
  const int c0 = blockIdx.y * 64;  // within [0,768)
  f32x4 acc[2][4];
#pragma unroll
  for (int qs = 0; qs < 2; ++qs)
#pragma unroll
    for (int nt = 0; nt < 4; ++nt) acc[qs][nt] = f32x4{0.f, 0.f, 0.f, 0.f};

#pragma unroll
  for (int kc = 0; kc < D; kc += 32) {
    f16x8 ah[2], al[2], bw[4];
#pragma unroll
    for (int qs = 0; qs < 2; ++qs) {
      const size_t ao = (size_t)(m0 + qs * 16 + lrow) * D + kc + lhi * 8;
      ah[qs] = *(const f16x8*)(nxh + ao);
      al[qs] = *(const f16x8*)(nxl + ao);
    }
#pragma unroll
    for (int nt = 0; nt < 4; ++nt)
      bw[nt] = *(const f16x8*)(wt + (size_t)(c0 + nt * 16 + lrow) * D + kc +
                               lhi * 8);
#pragma unroll
    for (int qs = 0; qs < 2; ++qs)
#pragma unroll
      for (int nt = 0; nt < 4; ++nt) {
        acc[qs][nt] = mfma_f16(ah[qs], bw[nt], acc[qs][nt]);
        acc[qs][nt] = mfma_f16(al[qs], bw[nt], acc[qs][nt]);
      }
  }

  const int region = blockIdx.y >> 2;  // 0:q 1:k 2:v
  const int cbase = c0 & 255;
  if (region < 2) {
    const float sc = (region == 0) ? QSC2 : 1.0f;
    ushort* dp = (region == 0) ? qfp : kfp;
#pragma unroll
    for (int qs = 0; qs < 2; ++qs)
#pragma unroll
      for (int nt = 0; nt < 4; ++nt)
#pragma unroll
        for (int i = 0; i < 4; ++i) {
          const int row = m0 + qs * 16 + lhi * 4 + i;
          const int col = cbase + nt * 16 + lrow;
          const float val =
              (acc[qs][nt][i] + coord[(size_t)row * D + col]) * sc;
          dp[(size_t)row * D + col] = f2h(val);
        }
  } else {
#pragma unroll
    for (int qs = 0; qs < 2; ++qs)
#pragma unroll
      for (int nt = 0; nt < 4; ++nt)
#pragma unroll
        for (int i = 0; i < 4; ++i) {
          const int row = m0 + qs * 16 + lhi * 4 + i;
          const int col = cbase + nt * 16 + lrow;
          const int bb = row >> 12, n = row & (N - 1);
          vtp[((size_t)bb * D + col) * N + n] = f2h(acc[qs][nt][i]);
        }
  }
}

// ---------------- MFMA flash attention (32x32 swapped-operand) -------------
// 8 warps x 32 q-rows (block = 256 rows), KVB=32 keys/tile, SPLIT=4.
// TRIPLE-buffered K/V staging, ONE s_barrier per tile (round-13 structure).
// Round-14 changes:
//  * V LDS layout = d-PAIR rows of 128B: granule G=(d>>1)*8+slot,
//    slot = ((d&1)*4 + sg) ^ ((d>>1)&7), sg = key-granule (kk*2+h).
//    8-slot XOR swizzle -> 32-bank-even V reads (round-13's 64B rows had
//    only 4 slots -> 4-way conflict, SQ_LDS_BANK_CONFLICT doubled).
//  * tile loop unrolled x3 so the buffer index is compile-time.
__global__ __launch_bounds__(512, 2) void attn_kernel(
    const ushort* __restrict__ qf, const ushort* __restrict__ kf,
    const ushort* __restrict__ vt, ushort* __restrict__ pob,
    float* __restrict__ mlb) {
  __shared__ ushort kbuf[3][8192];  // [key 0..31][32 granules]   16KB each
  __shared__ ushort vbuf[3][8192];  // [d-pair 0..127][8 granules] 16KB each

  const int tid = threadIdx.x;
  const int lane = tid & 63;
  const int q = lane & 31, h = lane >> 5;
  const int w = tid >> 6;
  const int b = blockIdx.y, s = blockIdx.z;
  const int qw = blockIdx.x * 256 + w * 32;
  const int kbeg = s * (N / SPLIT);

  const ushort* qrow = qf + ((size_t)b * N + qw + q) * D;
  const ushort* kfb = kf + (size_t)b * N * D;
  const ushort* vtb = vt + (size_t)b * D * N;
  ushort* pog = pob + (size_t)s * BN * D;
  float* mlg = mlb + (size_t)s * BN * 2;

  // persistent Q chunks 0..7 (d 0..127); chunks 8..15 streamed per tile
  f16x8 qfr[8];
#pragma unroll
  for (int c = 0; c < 8; ++c)
    qfr[c] = *(const f16x8*)(qrow + c * 16 + h * 8);

  f32x16 o[8];
#pragma unroll
  for (int dt = 0; dt < 8; ++dt)
#pragma unroll
    for (int r = 0; r < 16; ++r) o[dt][r] = 0.f;
  float m = -1e30f, lsum = 0.f;

  // stage one 32-key K+V tile; 4 granule-loads per thread (2 K + 2 V).
  // K: granule G -> key=G>>5, slot=G&31; src d-gran = slot^(key&7)
  // V: granule G -> r=G>>3, slot=G&7; u=slot^(r&7); d=2r+(u>>2); sg=u&3
  auto stage = [&](int bi, int k0) {
#pragma unroll
    for (int i = 0; i < 2; ++i) {
      const int g = i * 512 + tid;
      const int key = g >> 5, slot = g & 31;
      gload16(kfb + (size_t)(k0 + key) * D + ((slot ^ (key & 7)) * 8),
              &kbuf[bi][g * 8]);
    }
#pragma unroll
    for (int i = 0; i < 2; ++i) {
      const int g = i * 512 + tid;
      const int r = g >> 3, slot = g & 7;
      const int u = slot ^ (r & 7);
      const int d = r * 2 + (u >> 2);
      gload16(vtb + (size_t)d * N + k0 + ((u & 3) * 8), &vbuf[bi][g * 8]);
    }
  };

  stage(0, kbeg);

#define ATTN_BODY(CUR, T, LASTB)                                             \
  {                                                                          \
    f16x8 qs[8];                                                             \
    _Pragma("unroll") for (int c = 0; c < 8; ++c)                            \
        qs[c] = *(const f16x8*)(qrow + (8 + c) * 16 + h * 8);                \
    if (!(LASTB)) {                                                          \
      stage(((CUR) + 1) % 3, kbeg + ((T) + 1) * KVB);                        \
      asm volatile("s_waitcnt vmcnt(12)" ::: "memory");                      \
    } else {                                                                 \
      asm volatile("s_waitcnt vmcnt(8)" ::: "memory");                       \
    }                                                                        \
    __builtin_amdgcn_sched_barrier(0);                                       \
    __builtin_amdgcn_s_barrier();                                            \
    __builtin_amdgcn_sched_barrier(0);                                       \
    f32x16 pa, pb;                                                           \
    _Pragma("unroll") for (int r = 0; r < 16; ++r) { pa[r] = 0.f; pb[r] = 0.f; } \
    const int ksw = (q & 7);                                                 \
    __builtin_amdgcn_s_setprio(1);                                           \
    _Pragma("unroll") for (int c = 0; c < 8; ++c) {                          \
      const f16x8 ka =                                                       \
          *(const f16x8*)&kbuf[CUR][q * 256 + (((c * 2 + h) ^ ksw) * 8)];    \
      const f16x8 kb_ = *(const f16x8*)&kbuf[CUR][q * 256 +                  \
                                                  ((((c + 8) * 2 + h) ^ ksw) * 8)]; \
      pa = mfma32(ka, qfr[c], pa);                                           \
      pb = mfma32(kb_, qs[c], pb);                                           \
    }                                                                        \
    __builtin_amdgcn_s_setprio(0);                                           \
    f32x16 p;                                                                \
    _Pragma("unroll") for (int r = 0; r < 16; ++r) p[r] = pa[r] + pb[r];     \
    float tm[8];                                                             \
    _Pragma("unroll") for (int j = 0; j < 8; ++j)                            \
        tm[j] = fmaxf(p[2 * j], p[2 * j + 1]);                               \
    float pmax = fmaxf(fmaxf(fmaxf(tm[0], tm[1]), fmaxf(tm[2], tm[3])),      \
                       fmaxf(fmaxf(tm[4], tm[5]), fmaxf(tm[6], tm[7])));     \
    const float pm = fmaxf(pmax, __shfl_xor(pmax, 32));                      \
    const bool need = pm > m + THR;                                          \
    if (__any(need)) {                                                       \
      const float mn = fmaxf(m, pm);                                         \
      const float f = exp2f(m - mn);                                         \
      m = mn;                                                                \
      lsum *= f;                                                             \
      _Pragma("unroll") for (int dt = 0; dt < 8; ++dt) o[dt] *= f;           \
    }                                                                        \
    _Pragma("unroll") for (int r = 0; r < 16; ++r) {                         \
      p[r] = exp2f(p[r] - m);                                                 \
      lsum += p[r];                                                          \
    }                                                                        \
    f16x8 pf[2];                                                             \
    _Pragma("unroll") for (int kk = 0; kk < 2; ++kk) {                       \
      const int sub = kk * 8;                                                \
      unsigned x = pkh(p[sub + 0], p[sub + 1]);                              \
      unsigned z = pkh(p[sub + 2], p[sub + 3]);                              \
      unsigned y = pkh(p[sub + 4], p[sub + 5]);                              \
      unsigned wv = pkh(p[sub + 6], p[sub + 7]);                             \
      const unsigned xs = __shfl_xor(x, 32);                                 \
      const unsigned zs = __shfl_xor(z, 32);                                 \
      const unsigned ys = __shfl_xor(y, 32);                                 \
      const unsigned ws = __shfl_xor(wv, 32);                                \
      union { f16x8 v; unsigned u[4]; } pu;                                  \
      pu.u[0] = h ? ys : x;                                                  \
      pu.u[1] = h ? ws : z;                                                  \
      pu.u[2] = h ? y : xs;                                                  \
      pu.u[3] = h ? wv : zs;                                                 \
      pf[kk] = pu.v;                                                         \
    }                                                                        \
    __builtin_amdgcn_s_setprio(1);                                           \
    _Pragma("unroll") for (int dt = 0; dt < 8; ++dt) {                       \
      const int d = dt * 32 + q;                                             \
      const int rr = d >> 1;                                                 \
      _Pragma("unroll") for (int kk = 0; kk < 2; ++kk) {                     \
        const int u = (d & 1) * 4 + kk * 2 + h;                              \
        const f16x8 vf = *(const f16x8*)&vbuf[CUR][rr * 64 +                 \
                                                   ((u ^ (rr & 7)) * 8)];    \
        o[dt] = mfma32(vf, pf[kk], o[dt]);                                   \
      }                                                                      \
    }                                                                        \
    __builtin_amdgcn_s_setprio(0);                                           \
  }

  // NTK = 32 = 10*3 + 2: triple-unrolled with compile-time buffer index.
  for (int tb = 0; tb < NTK - 2; tb += 3) {
    ATTN_BODY(0, tb + 0, false);
    ATTN_BODY(1, tb + 1, false);
    ATTN_BODY(2, tb + 2, false);
  }
  ATTN_BODY(0, NTK - 2, false);
  ATTN_BODY(1, NTK - 1, true);
#undef ATTN_BODY

  // ---- epilogue: cross-half lsum, normalize, write O (row = qw+q) ----
  const float lt = lsum + __shfl_xor(lsum, 32);
  const float inv = 1.0f / lt;
  ushort* orow = pog + ((size_t)b * N + qw + q) * D;
#pragma unroll
  for (int dt = 0; dt < 8; ++dt)
#pragma unroll
    for (int r4 = 0; r4 < 4; ++r4) {
      const unsigned u0 =
          pkh(o[dt][r4 * 4 + 0] * inv, o[dt][r4 * 4 + 1] * inv);
      const unsigned u1 =
          pkh(o[dt][r4 * 4 + 2] * inv, o[dt][r4 * 4 + 3] * inv);
      uint2 val;
      val.x = u0;
      val.y = u1;
      *(uint2*)(orow + dt * 32 + r4 * 8 + h * 4) = val;
    }
  if (h == 0) {
    const size_t r = (size_t)b * N + qw + q;
    mlg[r * 2] = m;
    mlg[r * 2 + 1] = lt;
  }
}

// ---------------- merge KV-split partials -> f16 hi/lo planes --------------
__global__ __launch_bounds__(256) void merge_kernel(
    const ushort* __restrict__ pob, const float* __restrict__ mlb,
    ushort* __restrict__ aoh, ushort* __restrict__ aol) {
  const int t = threadIdx.x;
  const int row = blockIdx.x * 8 + (t >> 5);
  const int d0 = (t & 31) * 8;
  float mv[SPLIT], lv[SPLIT];
  float mm = -1e30f;
#pragma unroll
  for (int s = 0; s < SPLIT; ++s) {
    mv[s] = mlb[(size_t)s * BN * 2 + row * 2];
    lv[s] = mlb[(size_t)s * BN * 2 + row * 2 + 1];
    mm = fmaxf(mm, mv[s]);
  }
  float wsum = 0.f, a[SPLIT];
#pragma unroll
  for (int s = 0; s < SPLIT; ++s) {
    a[s] = exp2f(mv[s] - mm) * lv[s];
    wsum += a[s];
  }
  const float invw = 1.0f / wsum;
  const size_t off = (size_t)row * D + d0;
  float r[8] = {};
#pragma unroll
  for (int s = 0; s < SPLIT; ++s) {
    const f16x8 p = *(const f16x8*)(pob + (size_t)s * BN * D + off);
    const float c = a[s] * invw;
#pragma unroll
    for (int j = 0; j < 8; ++j) r[j] += c * (float)p[j];
  }
  f16x8 rh, rl;
#pragma unroll
  for (int j = 0; j < 8; ++j) {
    rh[j] = (_Float16)r[j];
    rl[j] = (_Float16)(r[j] - (float)rh[j]);
  }
  *(f16x8*)(aoh + off) = rh;
  *(f16x8*)(aol + off) = rl;
}

// ---------------- output projection via MFMA (no LDS) ----------------
__global__ __launch_bounds__(256, 4) void proj_kernel(
    const ushort* __restrict__ aoh, const ushort* __restrict__ aol,
    const ushort* __restrict__ wot, const float* __restrict__ bias,
    float* __restrict__ out) {
  const int t = threadIdx.x;
  const int w = t >> 6, lane = t & 63;
  const int lrow = lane & 15, lhi = lane >> 4;
  const int m0 = blockIdx.x * 128 + w * 32;
  const int c0 = blockIdx.y * 64;
  f32x4 acc[2][4];
#pragma unroll
  for (int qs = 0; qs < 2; ++qs)
#pragma unroll
    for (int nt = 0; nt < 4; ++nt) acc[qs][nt] = f32x4{0.f, 0.f, 0.f, 0.f};

#pragma unroll
  for (int kc = 0; kc < D; kc += 32) {
    f16x8 ah[2], al[2], bw[4];
#pragma unroll
    for (int qs = 0; qs < 2; ++qs) {
      const size_t ao = (size_t)(m0 + qs * 16 + lrow) * D + kc + lhi * 8;
      ah[qs] = *(const f16x8*)(aoh + ao);
      al[qs] = *(const f16x8*)(aol + ao);
    }
#pragma unroll
    for (int nt = 0; nt < 4; ++nt)
      bw[nt] = *(const f16x8*)(wot + (size_t)(c0 + nt * 16 + lrow) * D + kc +
                               lhi * 8);
#pragma unroll
    for (int qs = 0; qs < 2; ++qs)
#pragma unroll
      for (int nt = 0; nt < 4; ++nt) {
        acc[qs][nt] = mfma_f16(ah[qs], bw[nt], acc[qs][nt]);
        acc[qs][nt] = mfma_f16(al[qs], bw[nt], acc[qs][nt]);
      }
  }
#pragma unroll
  for (int qs = 0; qs < 2; ++qs)
#pragma unroll
    for (int nt = 0; nt < 4; ++nt)
#pragma unroll
      for (int i = 0; i < 4; ++i) {
        const int row = m0 + qs * 16 + lhi * 4 + i;
        const int col = c0 + nt * 16 + lrow;
        out[(size_t)row * D + col] = acc[qs][nt][i] + bias[col];
      }
}

extern "C" void kernel_launch(void* const* d_in, const int* in_sizes, int n_in,
                              void* d_out, int out_size, void* d_ws, size_t ws_size,
                              hipStream_t stream) {
  const float* x = (const float*)d_in[0];
  const float* coord = (const float*)d_in[1];
  const float* ln_g = (const float*)d_in[2];
  const float* ln_b = (const float*)d_in[3];
  const float* w_qkv = (const float*)d_in[4];
  const float* w_out = (const float*)d_in[5];
  const float* b_out = (const float*)d_in[6];
  float* out = (float*)d_out;

  const size_t P = (size_t)BN * D;

  ushort* qfp = (ushort*)d_ws;
  ushort* kfp = qfp + P;
  ushort* vtp = kfp + P;
  ushort* pob = vtp + P;                      // SPLIT partial-O planes
  float* mlb = (float*)(pob + (size_t)SPLIT * P);
  ushort* wt = (ushort*)(mlb + (size_t)SPLIT * BN * 2);
  ushort* wot = wt + 768 * 256;
  // aliases (liveness-disjoint):
  ushort* nxh = pob;       // written by ln, consumed by qkv, dead before attn
  ushort* nxl = pob + P;
  ushort* aoh = qfp;       // written by merge after q/k are dead
  ushort* aol = kfp;

  hipLaunchKernelGGL(ln_kernel, dim3(BN), dim3(256), 0, stream,
                     x, ln_g, ln_b, nxh, nxl);
  hipLaunchKernelGGL(castw_kernel, dim3(1024), dim3(256), 0, stream,
                     w_qkv, w_out, wt, wot);
  hipLaunchKernelGGL(qkv_kernel, dim3(BN / 128, 12), dim3(256), 0, stream,
                     nxh, nxl, wt, coord, qfp, kfp, vtp);
  hipLaunchKernelGGL(attn_kernel, dim3(N / 256, B, SPLIT), dim3(512), 0,
                     stream, qfp, kfp, vtp, pob, mlb);
  hipLaunchKernelGGL(merge_kernel, dim3(BN / 8), dim3(256), 0, stream,
                     pob, mlb, aoh, aol);
  hipLaunchKernelGGL(proj_kernel, dim3(BN / 128, 4), dim3(256), 0, stream,
                     aoh, aol, wot, b_out, out);
}

// Round 15
// 203.773 us; speedup vs baseline: 1.3948x; 1.3948x over previous
//
#include <hip/hip_runtime.h>
#include <hip/hip_fp16.h>
#include <math.h>

constexpr int B = 4, N = 4096, D = 256;
constexpr int BN = B * N;
constexpr float EPS = 1e-5f;
// softmax scale (D^-0.5 = 1/16) * log2(e), folded into q at f16-cast time
constexpr float QSC2 = 0.0625f * 1.44269504088896340736f;

constexpr int SPLIT = 4;     // KV splits -> grid 256 blocks (1/CU)
constexpr int KVB = 32;      // keys per attn tile
constexpr int NTK = (N / SPLIT) / KVB;  // 32 tiles
constexpr float THR = 8.0f;  // defer-max threshold (base-2)

typedef __attribute__((ext_vector_type(8))) _Float16 f16x8;
typedef __attribute__((ext_vector_type(2))) __fp16 fp16x2;
typedef __attribute__((ext_vector_type(4))) float f32x4;
typedef __attribute__((ext_vector_type(16))) float f32x16;

__device__ inline f32x4 mfma_f16(f16x8 a, f16x8 b, f32x4 c) {
  return __builtin_amdgcn_mfma_f32_16x16x32_f16(a, b, c, 0, 0, 0);
}
__device__ inline f32x16 mfma32(f16x8 a, f16x8 b, f32x16 c) {
  return __builtin_amdgcn_mfma_f32_32x32x16_f16(a, b, c, 0, 0, 0);
}
__device__ inline ushort f2h(float x) {
  __half h = __float2half(x);
  return *(ushort*)&h;
}
__device__ inline float h2f(ushort u) {
  __half h;
  *(ushort*)&h = u;
  return __half2float(h);
}
__device__ inline unsigned pkh(float a, float b) {
  fp16x2 r = __builtin_amdgcn_cvt_pkrtz(a, b);
  return *(unsigned*)&r;
}
// async global->LDS, 16B per lane; lds dest = uniform base + lane*16 (HW rule)
__device__ inline void gload16(const ushort* g, ushort* l) {
  __builtin_amdgcn_global_load_lds(
      (const __attribute__((address_space(1))) void*)g,
      (__attribute__((address_space(3))) void*)l, 16, 0, 0);
}

// ---------------- LayerNorm -> normalized x as f16 hi/lo planes ------------
__global__ __launch_bounds__(256) void ln_kernel(
    const float* __restrict__ x, const float* __restrict__ g,
    const float* __restrict__ bta, ushort* __restrict__ nxh,
    ushort* __restrict__ nxl) {
  const int row = blockIdx.x;
  const int t = threadIdx.x;
  const float v = x[(size_t)row * D + t];
  float s = v, ss = v * v;
#pragma unroll
  for (int o = 32; o > 0; o >>= 1) {
    s += __shfl_down(s, o);
    ss += __shfl_down(ss, o);
  }
  __shared__ float red[8];
  if ((t & 63) == 0) {
    red[t >> 6] = s;
    red[(t >> 6) + 4] = ss;
  }
  __syncthreads();
  s = red[0] + red[1] + red[2] + red[3];
  ss = red[4] + red[5] + red[6] + red[7];
  const float mu = s * (1.0f / D);
  const float var = ss * (1.0f / D) - mu * mu;
  const float rsig = rsqrtf(var + EPS);
  const float nx = (v - mu) * rsig * g[t] + bta[t];
  const ushort h = f2h(nx);
  nxh[(size_t)row * D + t] = h;
  nxl[(size_t)row * D + t] = f2h(nx - h2f(h));
}

// ------------- cast + transpose weights to f16 (wt[768][256], wot[256][256])
__global__ __launch_bounds__(256) void castw_kernel(
    const float* __restrict__ w_qkv, const float* __restrict__ w_out,
    ushort* __restrict__ wt, ushort* __restrict__ wot) {
  const int id = blockIdx.x * 256 + threadIdx.x;
  if (id < 768 * 256) {
    const int n = id >> 8, k = id & 255;
    wt[id] = f2h(w_qkv[(size_t)k * 768 + n]);
  } else {
    const int j = id - 768 * 256;
    const int n = j >> 8, k = j & 255;
    wot[j] = f2h(w_out[(size_t)k * 256 + n]);
  }
}

// ---------------- QKV GEMM via MFMA (no LDS; weights L2-hot) ---------------
__global__ __launch_bounds__(256, 4) void qkv_kernel(
    const ushort* __restrict__ nxh, const ushort* __restrict__ nxl,
    const ushort* __restrict__ wt, const float* __restrict__ coord,
    ushort* __restrict__ qfp, ushort* __restrict__ kfp,
    ushort* __restrict__ vtp) {
  const int t = threadIdx.x;
  const int w = t >> 6, lane = t & 63;
  const int lrow = lane & 15, lhi = lane >> 4;
  const int m0 = blockIdx.x * 128 + w * 32;
  const int c0 = blockIdx.y * 64;  // within [0,768)
  f32x4 acc[2][4];
#pragma unroll
  for (int qs = 0; qs < 2; ++qs)
#pragma unroll
    for (int nt = 0; nt < 4; ++nt) acc[qs][nt] = f32x4{0.f, 0.f, 0.f, 0.f};

#pragma unroll
  for (int kc = 0; kc < D; kc += 32) {
    f16x8 ah[2], al[2], bw[4];
#pragma unroll
    for (int qs = 0; qs < 2; ++qs) {
      const size_t ao = (size_t)(m0 + qs * 16 + lrow) * D + kc + lhi * 8;
      ah[qs] = *(const f16x8*)(nxh + ao);
      al[qs] = *(const f16x8*)(nxl + ao);
    }
#pragma unroll
    for (int nt = 0; nt < 4; ++nt)
      bw[nt] = *(const f16x8*)(wt + (size_t)(c0 + nt * 16 + lrow) * D + kc +
                               lhi * 8);
#pragma unroll
    for (int qs = 0; qs < 2; ++qs)
#pragma unroll
      for (int nt = 0; nt < 4; ++nt) {
        acc[qs][nt] = mfma_f16(ah[qs], bw[nt], acc[qs][nt]);
        acc[qs][nt] = mfma_f16(al[qs], bw[nt], acc[qs][nt]);
      }
  }

  const int region = blockIdx.y >> 2;  // 0:q 1:k 2:v
  const int cbase = c0 & 255;
  if (region < 2) {
    const float sc = (region == 0) ? QSC2 : 1.0f;
    ushort* dp = (region == 0) ? qfp : kfp;
#pragma unroll
    for (int qs = 0; qs < 2; ++qs)
#pragma unroll
      for (int nt = 0; nt < 4; ++nt)
#pragma unroll
        for (int i = 0; i < 4; ++i) {
          const int row = m0 + qs * 16 + lhi * 4 + i;
          const int col = cbase + nt * 16 + lrow;
          const float val =
              (acc[qs][nt][i] + coord[(size_t)row * D + col]) * sc;
          dp[(size_t)row * D + col] = f2h(val);
        }
  } else {
#pragma unroll
    for (int qs = 0; qs < 2; ++qs)
#pragma unroll
      for (int nt = 0; nt < 4; ++nt)
#pragma unroll
        for (int i = 0; i < 4; ++i) {
          const int row = m0 + qs * 16 + lhi * 4 + i;
          const int col = cbase + nt * 16 + lrow;
          const int bb = row >> 12, n = row & (N - 1);
          vtp[((size_t)bb * D + col) * N + n] = f2h(acc[qs][nt][i]);
        }
  }
}

// ---------------- MFMA flash attention (32x32 swapped-operand) -------------
// 8 warps x 32 q-rows (block = 256 rows), KVB=32 keys/tile, SPLIT=4.
// TRIPLE-buffered K/V staging, ONE s_barrier per tile, ROLLED loop (round-14
// lesson: the x3 macro unroll blew past L1I -> instruction refetch tripled
// FETCH_SIZE and cost +70us; keep ONE body copy).
// V LDS layout = d-PAIR rows of 128B (the proven-good half of round 14):
// granule G=(d>>1)*8+slot, slot = ((d&1)*4 + sg) ^ ((d>>1)&7), sg = key-
// granule (kk*2+h). 8-slot XOR swizzle -> V reads spread over all banks
// (round-13's 64B rows = 4 slots = 4-way conflict, 16.8M conflict cycles).
// S^T = mfma32(K, Q): lane holds col=qrow(lane&31); p[reg] = P[q][key] with
// key = (reg&3) + 8*(reg>>2) + 4*h. Cross-lane via __shfl_xor(.,32) only.
__global__ __launch_bounds__(512, 2) void attn_kernel(
    const ushort* __restrict__ qf, const ushort* __restrict__ kf,
    const ushort* __restrict__ vt, ushort* __restrict__ pob,
    float* __restrict__ mlb) {
  __shared__ ushort kbuf[3][8192];  // [key 0..31][32 granules]    16KB each
  __shared__ ushort vbuf[3][8192];  // [d-pair 0..127][8 granules] 16KB each

  const int tid = threadIdx.x;
  const int lane = tid & 63;
  const int q = lane & 31, h = lane >> 5;
  const int w = tid >> 6;
  const int b = blockIdx.y, s = blockIdx.z;
  const int qw = blockIdx.x * 256 + w * 32;
  const int kbeg = s * (N / SPLIT);

  const ushort* qrow = qf + ((size_t)b * N + qw + q) * D;
  const ushort* kfb = kf + (size_t)b * N * D;
  const ushort* vtb = vt + (size_t)b * D * N;
  ushort* pog = pob + (size_t)s * BN * D;
  float* mlg = mlb + (size_t)s * BN * 2;

  // persistent Q chunks 0..7 (d 0..127); chunks 8..15 streamed per tile
  f16x8 qfr[8];
#pragma unroll
  for (int c = 0; c < 8; ++c)
    qfr[c] = *(const f16x8*)(qrow + c * 16 + h * 8);

  f32x16 o[8];
#pragma unroll
  for (int dt = 0; dt < 8; ++dt)
#pragma unroll
    for (int r = 0; r < 16; ++r) o[dt][r] = 0.f;
  float m = -1e30f, lsum = 0.f;

  // stage one 32-key K+V tile; 4 granule-loads per thread (2 K + 2 V).
  // K: granule G -> key=G>>5, slot=G&31; src d-gran = slot^(key&7)
  // V: granule G -> r=G>>3, slot=G&7; u=slot^(r&7); d=2r+(u>>2); sg=u&3
  auto stage = [&](int bi, int k0) {
#pragma unroll
    for (int i = 0; i < 2; ++i) {
      const int g = i * 512 + tid;
      const int key = g >> 5, slot = g & 31;
      gload16(kfb + (size_t)(k0 + key) * D + ((slot ^ (key & 7)) * 8),
              &kbuf[bi][g * 8]);
    }
#pragma unroll
    for (int i = 0; i < 2; ++i) {
      const int g = i * 512 + tid;
      const int r = g >> 3, slot = g & 7;
      const int u = slot ^ (r & 7);
      const int d = r * 2 + (u >> 2);
      gload16(vtb + (size_t)d * N + k0 + ((u & 3) * 8), &vbuf[bi][g * 8]);
    }
  };

  stage(0, kbeg);

  for (int t = 0; t < NTK; ++t) {
    const int cur = t % 3;
    // stream Q chunks 8..15 (issued BEFORE next-tile stage so vmcnt(12)
    // drains exactly the current tile's 4 stage loads)
    f16x8 qs[8];
#pragma unroll
    for (int c = 0; c < 8; ++c)
      qs[c] = *(const f16x8*)(qrow + (8 + c) * 16 + h * 8);
    if (t + 1 < NTK) {
      stage((t + 1) % 3, kbeg + (t + 1) * KVB);
      asm volatile("s_waitcnt vmcnt(12)" ::: "memory");  // drain stage(t)
    } else {
      asm volatile("s_waitcnt vmcnt(8)" ::: "memory");   // qs still in flight
    }
    __builtin_amdgcn_sched_barrier(0);
    __builtin_amdgcn_s_barrier();   // the ONLY barrier per tile
    __builtin_amdgcn_sched_barrier(0);

    // ---- S^T = K Q : one 32x32 C-tile, 2 partial-sum chains ----
    f32x16 pa, pb;
#pragma unroll
    for (int r = 0; r < 16; ++r) { pa[r] = 0.f; pb[r] = 0.f; }
    const int ksw = (q & 7);
    __builtin_amdgcn_s_setprio(1);
#pragma unroll
    for (int c = 0; c < 8; ++c) {
      const f16x8 ka = *(const f16x8*)&kbuf[cur][q * 256 +
                                                 (((c * 2 + h) ^ ksw) * 8)];
      const f16x8 kb_ = *(const f16x8*)&kbuf[cur][q * 256 +
                                                  ((((c + 8) * 2 + h) ^ ksw) * 8)];
      pa = mfma32(ka, qfr[c], pa);
      pb = mfma32(kb_, qs[c], pb);
    }
    __builtin_amdgcn_s_setprio(0);
    f32x16 p;
#pragma unroll
    for (int r = 0; r < 16; ++r) p[r] = pa[r] + pb[r];

    // ---- softmax: in-lane tree + cross-half shfl ----
    float tm[8];
#pragma unroll
    for (int j = 0; j < 8; ++j) tm[j] = fmaxf(p[2 * j], p[2 * j + 1]);
    float pmax = fmaxf(fmaxf(fmaxf(tm[0], tm[1]), fmaxf(tm[2], tm[3])),
                       fmaxf(fmaxf(tm[4], tm[5]), fmaxf(tm[6], tm[7])));
    const float pm = fmaxf(pmax, __shfl_xor(pmax, 32));
    const bool need = pm > m + THR;
    if (__any(need)) {
      const float mn = fmaxf(m, pm);
      const float f = exp2f(m - mn);
      m = mn;
      lsum *= f;
#pragma unroll
      for (int dt = 0; dt < 8; ++dt) o[dt] *= f;
    }
#pragma unroll
    for (int r = 0; r < 16; ++r) {
      p[r] = exp2f(p[r] - m);
      lsum += p[r];
    }

    // ---- pack P -> 2 PV B-frags (16 keys each) via cvt_pkrtz + shfl ----
    // lane(q,h) owns packed words: x=keys(4h,4h+1) z=(4h+2,4h+3)
    // y=(8+4h,9+4h) wv=(10+4h,11+4h). B-frag word_j = keys(h*8+2j,+1):
    // word0 = h? partner-y : x ; word1 = h? partner-wv : z ;
    // word2 = h? y : partner-x ; word3 = h? wv : partner-z.
    f16x8 pf[2];
#pragma unroll
    for (int kk = 0; kk < 2; ++kk) {
      const int sub = kk * 8;
      unsigned x = pkh(p[sub + 0], p[sub + 1]);
      unsigned z = pkh(p[sub + 2], p[sub + 3]);
      unsigned y = pkh(p[sub + 4], p[sub + 5]);
      unsigned wv = pkh(p[sub + 6], p[sub + 7]);
      const unsigned xs = __shfl_xor(x, 32);
      const unsigned zs = __shfl_xor(z, 32);
      const unsigned ys = __shfl_xor(y, 32);
      const unsigned ws = __shfl_xor(wv, 32);
      union { f16x8 v; unsigned u[4]; } pu;
      pu.u[0] = h ? ys : x;
      pu.u[1] = h ? ws : z;
      pu.u[2] = h ? y : xs;
      pu.u[3] = h ? wv : zs;
      pf[kk] = pu.v;
    }

    // ---- O^T += V^T P^T : 8 d-tiles x 2 key-chunks ----
    __builtin_amdgcn_s_setprio(1);
#pragma unroll
    for (int dt = 0; dt < 8; ++dt) {
      const int d = dt * 32 + q;
      const int rr = d >> 1;
#pragma unroll
      for (int kk = 0; kk < 2; ++kk) {
        const int u = (d & 1) * 4 + kk * 2 + h;
        const f16x8 vf = *(const f16x8*)&vbuf[cur][rr * 64 +
                                                   ((u ^ (rr & 7)) * 8)];
        o[dt] = mfma32(vf, pf[kk], o[dt]);
      }
    }
    __builtin_amdgcn_s_setprio(0);
    // NO end-of-tile barrier: triple buffering makes stage(t+1) safe.
  }

  // ---- epilogue: cross-half lsum, normalize, write O (row = qw+q) ----
  const float lt = lsum + __shfl_xor(lsum, 32);
  const float inv = 1.0f / lt;
  ushort* orow = pog + ((size_t)b * N + qw + q) * D;
#pragma unroll
  for (int dt = 0; dt < 8; ++dt)
#pragma unroll
    for (int r4 = 0; r4 < 4; ++r4) {
      const unsigned u0 =
          pkh(o[dt][r4 * 4 + 0] * inv, o[dt][r4 * 4 + 1] * inv);
      const unsigned u1 =
          pkh(o[dt][r4 * 4 + 2] * inv, o[dt][r4 * 4 + 3] * inv);
      uint2 val;
      val.x = u0;
      val.y = u1;
      *(uint2*)(orow + dt * 32 + r4 * 8 + h * 4) = val;
    }
  if (h == 0) {
    const size_t r = (size_t)b * N + qw + q;
    mlg[r * 2] = m;
    mlg[r * 2 + 1] = lt;
  }
}

// ---------------- merge KV-split partials -> f16 hi/lo planes --------------
__global__ __launch_bounds__(256) void merge_kernel(
    const ushort* __restrict__ pob, const float* __restrict__ mlb,
    ushort* __restrict__ aoh, ushort* __restrict__ aol) {
  const int t = threadIdx.x;
  const int row = blockIdx.x * 8 + (t >> 5);
  const int d0 = (t & 31) * 8;
  float mv[SPLIT], lv[SPLIT];
  float mm = -1e30f;
#pragma unroll
  for (int s = 0; s < SPLIT; ++s) {
    mv[s] = mlb[(size_t)s * BN * 2 + row * 2];
    lv[s] = mlb[(size_t)s * BN * 2 + row * 2 + 1];
    mm = fmaxf(mm, mv[s]);
  }
  float wsum = 0.f, a[SPLIT];
#pragma unroll
  for (int s = 0; s < SPLIT; ++s) {
    a[s] = exp2f(mv[s] - mm) * lv[s];
    wsum += a[s];
  }
  const float invw = 1.0f / wsum;
  const size_t off = (size_t)row * D + d0;
  float r[8] = {};
#pragma unroll
  for (int s = 0; s < SPLIT; ++s) {
    const f16x8 p = *(const f16x8*)(pob + (size_t)s * BN * D + off);
    const float c = a[s] * invw;
#pragma unroll
    for (int j = 0; j < 8; ++j) r[j] += c * (float)p[j];
  }
  f16x8 rh, rl;
#pragma unroll
  for (int j = 0; j < 8; ++j) {
    rh[j] = (_Float16)r[j];
    rl[j] = (_Float16)(r[j] - (float)rh[j]);
  }
  *(f16x8*)(aoh + off) = rh;
  *(f16x8*)(aol + off) = rl;
}

// ---------------- output projection via MFMA (no LDS) ----------------
__global__ __launch_bounds__(256, 4) void proj_kernel(
    const ushort* __restrict__ aoh, const ushort* __restrict__ aol,
    const ushort* __restrict__ wot, const float* __restrict__ bias,
    float* __restrict__ out) {
  const int t = threadIdx.x;
  const int w = t >> 6, lane = t & 63;
  const int lrow = lane & 15, lhi = lane >> 4;
  const int m0 = blockIdx.x * 128 + w * 32;
  const int c0 = blockIdx.y * 64;
  f32x4 acc[2][4];
#pragma unroll
  for (int qs = 0; qs < 2; ++qs)
#pragma unroll
    for (int nt = 0; nt < 4; ++nt) acc[qs][nt] = f32x4{0.f, 0.f, 0.f, 0.f};

#pragma unroll
  for (int kc = 0; kc < D; kc += 32) {
    f16x8 ah[2], al[2], bw[4];
#pragma unroll
    for (int qs = 0; qs < 2; ++qs) {
      const size_t ao = (size_t)(m0 + qs * 16 + lrow) * D + kc + lhi * 8;
      ah[qs] = *(const f16x8*)(aoh + ao);
      al[qs] = *(const f16x8*)(aol + ao);
    }
#pragma unroll
    for (int nt = 0; nt < 4; ++nt)
      bw[nt] = *(const f16x8*)(wot + (size_t)(c0 + nt * 16 + lrow) * D + kc +
                               lhi * 8);
#pragma unroll
    for (int qs = 0; qs < 2; ++qs)
#pragma unroll
      for (int nt = 0; nt < 4; ++nt) {
        acc[qs][nt] = mfma_f16(ah[qs], bw[nt], acc[qs][nt]);
        acc[qs][nt] = mfma_f16(al[qs], bw[nt], acc[qs][nt]);
      }
  }
#pragma unroll
  for (int qs = 0; qs < 2; ++qs)
#pragma unroll
    for (int nt = 0; nt < 4; ++nt)
#pragma unroll
      for (int i = 0; i < 4; ++i) {
        const int row = m0 + qs * 16 + lhi * 4 + i;
        const int col = c0 + nt * 16 + lrow;
        out[(size_t)row * D + col] = acc[qs][nt][i] + bias[col];
      }
}

extern "C" void kernel_launch(void* const* d_in, const int* in_sizes, int n_in,
                              void* d_out, int out_size, void* d_ws, size_t ws_size,
                              hipStream_t stream) {
  const float* x = (const float*)d_in[0];
  const float* coord = (const float*)d_in[1];
  const float* ln_g = (const float*)d_in[2];
  const float* ln_b = (const float*)d_in[3];
  const float* w_qkv = (const float*)d_in[4];
  const float* w_out = (const float*)d_in[5];
  const float* b_out = (const float*)d_in[6];
  float* out = (float*)d_out;

  const size_t P = (size_t)BN * D;

  ushort* qfp = (ushort*)d_ws;
  ushort* kfp = qfp + P;
  ushort* vtp = kfp + P;
  ushort* pob = vtp + P;                      // SPLIT partial-O planes
  float* mlb = (float*)(pob + (size_t)SPLIT * P);
  ushort* wt = (ushort*)(mlb + (size_t)SPLIT * BN * 2);
  ushort* wot = wt + 768 * 256;
  // aliases (liveness-disjoint):
  ushort* nxh = pob;       // written by ln, consumed by qkv, dead before attn
  ushort* nxl = pob + P;
  ushort* aoh = qfp;       // written by merge after q/k are dead
  ushort* aol = kfp;

  hipLaunchKernelGGL(ln_kernel, dim3(BN), dim3(256), 0, stream,
                     x, ln_g, ln_b, nxh, nxl);
  hipLaunchKernelGGL(castw_kernel, dim3(1024), dim3(256), 0, stream,
                     w_qkv, w_out, wt, wot);
  hipLaunchKernelGGL(qkv_kernel, dim3(BN / 128, 12), dim3(256), 0, stream,
                     nxh, nxl, wt, coord, qfp, kfp, vtp);
  hipLaunchKernelGGL(attn_kernel, dim3(N / 256, B, SPLIT), dim3(512), 0,
                     stream, qfp, kfp, vtp, pob, mlb);
  hipLaunchKernelGGL(merge_kernel, dim3(BN / 8), dim3(256), 0, stream,
                     pob, mlb, aoh, aol);
  hipLaunchKernelGGL(proj_kernel, dim3(BN / 128, 4), dim3(256), 0, stream,
                     aoh, aol, wot, b_out, out);
}

// Round 17
// 195.178 us; speedup vs baseline: 1.4562x; 1.0440x over previous
//
#include <hip/hip_runtime.h>
#include <hip/hip_fp16.h>
#include <math.h>

constexpr int B = 4, N = 4096, D = 256;
constexpr int BN = B * N;
constexpr float EPS = 1e-5f;
// softmax scale (D^-0.5 = 1/16) * log2(e), folded into q at f16-cast time
constexpr float QSC2 = 0.0625f * 1.44269504088896340736f;

constexpr int SPLIT = 4;     // KV splits -> grid 256 blocks (1/CU)
constexpr int KVB = 32;      // keys per attn tile
constexpr int NTK = (N / SPLIT) / KVB;  // 32 tiles
constexpr float THR = 8.0f;  // defer-max threshold (base-2)

typedef __attribute__((ext_vector_type(8))) _Float16 f16x8;
typedef __attribute__((ext_vector_type(2))) __fp16 fp16x2;
typedef __attribute__((ext_vector_type(4))) float f32x4;
typedef __attribute__((ext_vector_type(16))) float f32x16;

__device__ inline f32x4 mfma_f16(f16x8 a, f16x8 b, f32x4 c) {
  return __builtin_amdgcn_mfma_f32_16x16x32_f16(a, b, c, 0, 0, 0);
}
__device__ inline f32x16 mfma32(f16x8 a, f16x8 b, f32x16 c) {
  return __builtin_amdgcn_mfma_f32_32x32x16_f16(a, b, c, 0, 0, 0);
}
__device__ inline ushort f2h(float x) {
  __half h = __float2half(x);
  return *(ushort*)&h;
}
__device__ inline float h2f(ushort u) {
  __half h;
  *(ushort*)&h = u;
  return __half2float(h);
}
__device__ inline unsigned pkh(float a, float b) {
  fp16x2 r = __builtin_amdgcn_cvt_pkrtz(a, b);
  return *(unsigned*)&r;
}
// async global->LDS, 16B per lane; lds dest = uniform base + lane*16 (HW rule)
__device__ inline void gload16(const ushort* g, ushort* l) {
  __builtin_amdgcn_global_load_lds(
      (const __attribute__((address_space(1))) void*)g,
      (__attribute__((address_space(3))) void*)l, 16, 0, 0);
}

// ---------------- LayerNorm -> normalized x as f16 hi/lo planes ------------
__global__ __launch_bounds__(256) void ln_kernel(
    const float* __restrict__ x, const float* __restrict__ g,
    const float* __restrict__ bta, ushort* __restrict__ nxh,
    ushort* __restrict__ nxl) {
  const int row = blockIdx.x;
  const int t = threadIdx.x;
  const float v = x[(size_t)row * D + t];
  float s = v, ss = v * v;
#pragma unroll
  for (int o = 32; o > 0; o >>= 1) {
    s += __shfl_down(s, o);
    ss += __shfl_down(ss, o);
  }
  __shared__ float red[8];
  if ((t & 63) == 0) {
    red[t >> 6] = s;
    red[(t >> 6) + 4] = ss;
  }
  __syncthreads();
  s = red[0] + red[1] + red[2] + red[3];
  ss = red[4] + red[5] + red[6] + red[7];
  const float mu = s * (1.0f / D);
  const float var = ss * (1.0f / D) - mu * mu;
  const float rsig = rsqrtf(var + EPS);
  const float nx = (v - mu) * rsig * g[t] + bta[t];
  const ushort h = f2h(nx);
  nxh[(size_t)row * D + t] = h;
  nxl[(size_t)row * D + t] = f2h(nx - h2f(h));
}

// ------------- cast + transpose weights to f16 (wt[768][256], wot[256][256])
__global__ __launch_bounds__(256) void castw_kernel(
    const float* __restrict__ w_qkv, const float* __restrict__ w_out,
    ushort* __restrict__ wt, ushort* __restrict__ wot) {
  const int id = blockIdx.x * 256 + threadIdx.x;
  if (id < 768 * 256) {
    const int n = id >> 8, k = id & 255;
    wt[id] = f2h(w_qkv[(size_t)k * 768 + n]);
  } else {
    const int j = id - 768 * 256;
    const int n = j >> 8, k = j & 255;
    wot[j] = f2h(w_out[(size_t)k * 256 + n]);
  }
}

// ---------------- QKV GEMM via MFMA (no LDS; weights L2-hot) ---------------
__global__ __launch_bounds__(256, 4) void qkv_kernel(
    const ushort* __restrict__ nxh, const ushort* __restrict__ nxl,
    const ushort* __restrict__ wt, const float* __restrict__ coord,
    ushort* __restrict__ qfp, ushort* __restrict__ kfp,
    ushort* __restrict__ vtp) {
  const int t = threadIdx.x;
  const int w = t >> 6, lane = t & 63;
  const int lrow = lane & 15, lhi = lane >> 4;
  const int m0 = blockIdx.x * 128 + w * 32;
  const int c0 = blockIdx.y * 64;  // within [0,768)
  f32x4 acc[2][4];
#pragma unroll
  for (int qs = 0; qs < 2; ++qs)
#pragma unroll
    for (int nt = 0; nt < 4; ++nt) acc[qs][nt] = f32x4{0.f, 0.f, 0.f, 0.f};

#pragma unroll
  for (int kc = 0; kc < D; kc += 32) {
    f16x8 ah[2], al[2], bw[4];
#pragma unroll
    for (int qs = 0; qs < 2; ++qs) {
      const size_t ao = (size_t)(m0 + qs * 16 + lrow) * D + kc + lhi * 8;
      ah[qs] = *(const f16x8*)(nxh + ao);
      al[qs] = *(const f16x8*)(nxl + ao);
    }
#pragma unroll
    for (int nt = 0; nt < 4; ++nt)
      bw[nt] = *(const f16x8*)(wt + (size_t)(c0 + nt * 16 + lrow) * D + kc +
                               lhi * 8);
#pragma unroll
    for (int qs = 0; qs < 2; ++qs)
#pragma unroll
      for (int nt = 0; nt < 4; ++nt) {
        acc[qs][nt] = mfma_f16(ah[qs], bw[nt], acc[qs][nt]);
        acc[qs][nt] = mfma_f16(al[qs], bw[nt], acc[qs][nt]);
      }
  }

  const int region = blockIdx.y >> 2;  // 0:q 1:k 2:v
  const int cbase = c0 & 255;
  if (region < 2) {
    const float sc = (region == 0) ? QSC2 : 1.0f;
    ushort* dp = (region == 0) ? qfp : kfp;
#pragma unroll
    for (int qs = 0; qs < 2; ++qs)
#pragma unroll
      for (int nt = 0; nt < 4; ++nt)
#pragma unroll
        for (int i = 0; i < 4; ++i) {
          const int row = m0 + qs * 16 + lhi * 4 + i;
          const int col = cbase + nt * 16 + lrow;
          const float val =
              (acc[qs][nt][i] + coord[(size_t)row * D + col]) * sc;
          dp[(size_t)row * D + col] = f2h(val);
        }
  } else {
#pragma unroll
    for (int qs = 0; qs < 2; ++qs)
#pragma unroll
      for (int nt = 0; nt < 4; ++nt)
#pragma unroll
        for (int i = 0; i < 4; ++i) {
          const int row = m0 + qs * 16 + lhi * 4 + i;
          const int col = cbase + nt * 16 + lrow;
          const int bb = row >> 12, n = row & (N - 1);
          vtp[((size_t)bb * D + col) * N + n] = f2h(acc[qs][nt][i]);
        }
  }
}

// ---------------- MFMA flash attention (32x32 swapped-operand) -------------
// 8 warps x 32 q-rows (block = 256 rows), KVB=32 keys/tile, SPLIT=4.
// QUAD-buffered K/V staging (32KB x4 = 128KB LDS), ONE s_barrier per tile,
// rolled loop (round-14 L1I lesson). Round-16: T15 deferred-PV pipeline —
// body t does: QK(t) MFMA chain -> [rescale o by f(t-1)] -> PV(t-1) MFMAs
// (queue behind QK) -> softmax(t) VALU runs WHILE PV(t-1) drains the matrix
// pipe. Quad (not triple) buffering is required: concurrent waves span body
// t (reads buf t for QK, buf t-1 for PV) and body t+1's pre-barrier stage
// (writes buf t+2); deltas 2,3 mod 4 != 0 -> safe.
// Flash algebra: o enters body t at scale m(t-2); o *= f(t-1) then
// += P~(t-1)V(t-1) [both at m(t-1)]; SM(t) computes f(t) for body t+1.
// S^T = mfma32(K, Q): lane holds col=qrow(lane&31); p[reg] = P[q][key] with
// key = (reg&3) + 8*(reg>>2) + 4*h. Cross-lane via __shfl_xor(.,32) only.
// V LDS = d-pair rows of 128B with 8-slot XOR swizzle (round-15, conflicts
// halved); K rows 512B with 32-slot swizzle.
__global__ __launch_bounds__(512, 2) void attn_kernel(
    const ushort* __restrict__ qf, const ushort* __restrict__ kf,
    const ushort* __restrict__ vt, ushort* __restrict__ pob,
    float* __restrict__ mlb) {
  __shared__ ushort kbuf[4][8192];  // [key 0..31][32 granules]    16KB each
  __shared__ ushort vbuf[4][8192];  // [d-pair 0..127][8 granules] 16KB each

  const int tid = threadIdx.x;
  const int lane = tid & 63;
  const int q = lane & 31, h = lane >> 5;
  const int w = tid >> 6;
  const int b = blockIdx.y, s = blockIdx.z;
  const int qw = blockIdx.x * 256 + w * 32;
  const int kbeg = s * (N / SPLIT);

  const ushort* qrow = qf + ((size_t)b * N + qw + q) * D;
  const ushort* kfb = kf + (size_t)b * N * D;
  const ushort* vtb = vt + (size_t)b * D * N;
  ushort* pog = pob + (size_t)s * BN * D;
  float* mlg = mlb + (size_t)s * BN * 2;

  // persistent Q chunks 0..7 (d 0..127); chunks 8..15 streamed per tile
  f16x8 qfr[8];
#pragma unroll
  for (int c = 0; c < 8; ++c)
    qfr[c] = *(const f16x8*)(qrow + c * 16 + h * 8);

  f32x16 o[8];
#pragma unroll
  for (int dt = 0; dt < 8; ++dt)
#pragma unroll
    for (int r = 0; r < 16; ++r) o[dt][r] = 0.f;
  float m = -1e30f, lsum = 0.f;
  float f_prev = 1.0f;
  bool need_prev = false;
  f16x8 pf_prev[2];

  // stage one 32-key K+V tile; 4 granule-loads per thread (2 K + 2 V).
  // K: granule G -> key=G>>5, slot=G&31; src d-gran = slot^(key&7)
  // V: granule G -> r=G>>3, slot=G&7; u=slot^(r&7); d=2r+(u>>2); sg=u&3
  auto stage = [&](int bi, int k0) {
#pragma unroll
    for (int i = 0; i < 2; ++i) {
      const int g = i * 512 + tid;
      const int key = g >> 5, slot = g & 31;
      gload16(kfb + (size_t)(k0 + key) * D + ((slot ^ (key & 7)) * 8),
              &kbuf[bi][g * 8]);
    }
#pragma unroll
    for (int i = 0; i < 2; ++i) {
      const int g = i * 512 + tid;
      const int r = g >> 3, slot = g & 7;
      const int u = slot ^ (r & 7);
      const int d = r * 2 + (u >> 2);
      gload16(vtb + (size_t)d * N + k0 + ((u & 3) * 8), &vbuf[bi][g * 8]);
    }
  };

  stage(0, kbeg);

  for (int t = 0; t < NTK; ++t) {
    const int cur = t & 3;
    const int prv = (t + 3) & 3;
    // stream Q chunks 8..15 (issued BEFORE next-tile stage so vmcnt(12)
    // drains exactly the current tile's 4 stage loads)
    f16x8 qs[8];
#pragma unroll
    for (int c = 0; c < 8; ++c)
      qs[c] = *(const f16x8*)(qrow + (8 + c) * 16 + h * 8);
    if (t + 1 < NTK) {
      stage((t + 1) & 3, kbeg + (t + 1) * KVB);
      asm volatile("s_waitcnt vmcnt(12)" ::: "memory");  // drain stage(t)
    } else {
      asm volatile("s_waitcnt vmcnt(8)" ::: "memory");   // qs still in flight
    }
    __builtin_amdgcn_sched_barrier(0);
    __builtin_amdgcn_s_barrier();   // the ONLY barrier per tile
    __builtin_amdgcn_sched_barrier(0);

    // ---- QK(t): S^T = K Q, single 16-MFMA chain into p ----
    f32x16 p;
#pragma unroll
    for (int r = 0; r < 16; ++r) p[r] = 0.f;
    const int ksw = (q & 7);
    __builtin_amdgcn_s_setprio(1);
#pragma unroll
    for (int c = 0; c < 16; ++c) {
      const f16x8 qv = (c < 8) ? qfr[c] : qs[c - 8];
      const f16x8 ka = *(const f16x8*)&kbuf[cur][q * 256 +
                                                 (((c * 2 + h) ^ ksw) * 8)];
      p = mfma32(ka, qv, p);
    }
    __builtin_amdgcn_s_setprio(0);

    // ---- deferred: rescale o by f(t-1), then PV(t-1) ----
    if (t > 0) {
      if (need_prev) {
#pragma unroll
        for (int dt = 0; dt < 8; ++dt) o[dt] *= f_prev;
      }
      __builtin_amdgcn_s_setprio(1);
#pragma unroll
      for (int dt = 0; dt < 8; ++dt) {
        const int d = dt * 32 + q;
        const int rr = d >> 1;
#pragma unroll
        for (int kk = 0; kk < 2; ++kk) {
          const int u = (d & 1) * 4 + kk * 2 + h;
          const f16x8 vf = *(const f16x8*)&vbuf[prv][rr * 64 +
                                                     ((u ^ (rr & 7)) * 8)];
          o[dt] = mfma32(vf, pf_prev[kk], o[dt]);
        }
      }
      __builtin_amdgcn_s_setprio(0);
    }

    // ---- softmax(t): runs while PV(t-1) drains the matrix pipe ----
    float tm[8];
#pragma unroll
    for (int j = 0; j < 8; ++j) tm[j] = fmaxf(p[2 * j], p[2 * j + 1]);
    float pmax = fmaxf(fmaxf(fmaxf(tm[0], tm[1]), fmaxf(tm[2], tm[3])),
                       fmaxf(fmaxf(tm[4], tm[5]), fmaxf(tm[6], tm[7])));
    const float pm = fmaxf(pmax, __shfl_xor(pmax, 32));
    const bool need = pm > m + THR;
    if (__any(need)) {
      const float mn = fmaxf(m, pm);
      f_prev = exp2f(m - mn);
      m = mn;
      lsum *= f_prev;
      need_prev = true;
    } else {
      need_prev = false;
    }
#pragma unroll
    for (int r = 0; r < 16; ++r) {
      p[r] = exp2f(p[r] - m);
      lsum += p[r];
    }

    // ---- pack P -> pf_prev (2 B-frags of 16 keys) via cvt_pkrtz + shfl ----
    // lane(q,h) owns packed words: x=keys(4h,4h+1) z=(4h+2,4h+3)
    // y=(8+4h,9+4h) wv=(10+4h,11+4h). B-frag word_j = keys(h*8+2j,+1):
    // word0 = h? partner-y : x ; word1 = h? partner-wv : z ;
    // word2 = h? y : partner-x ; word3 = h? wv : partner-z.
#pragma unroll
    for (int kk = 0; kk < 2; ++kk) {
      const int sub = kk * 8;
      unsigned x = pkh(p[sub + 0], p[sub + 1]);
      unsigned z = pkh(p[sub + 2], p[sub + 3]);
      unsigned y = pkh(p[sub + 4], p[sub + 5]);
      unsigned wv = pkh(p[sub + 6], p[sub + 7]);
      const unsigned xs = __shfl_xor(x, 32);
      const unsigned zs = __shfl_xor(z, 32);
      const unsigned ys = __shfl_xor(y, 32);
      const unsigned ws = __shfl_xor(wv, 32);
      union { f16x8 v; unsigned u[4]; } pu;
      pu.u[0] = h ? ys : x;
      pu.u[1] = h ? ws : z;
      pu.u[2] = h ? y : xs;
      pu.u[3] = h ? wv : zs;
      pf_prev[kk] = pu.v;
    }
  }

  // ---- epilogue: final rescale + PV(NTK-1), then normalize & write ----
  if (need_prev) {
#pragma unroll
    for (int dt = 0; dt < 8; ++dt) o[dt] *= f_prev;
  }
  {
    const int prv = (NTK - 1) & 3;
#pragma unroll
    for (int dt = 0; dt < 8; ++dt) {
      const int d = dt * 32 + q;
      const int rr = d >> 1;
#pragma unroll
      for (int kk = 0; kk < 2; ++kk) {
        const int u = (d & 1) * 4 + kk * 2 + h;
        const f16x8 vf = *(const f16x8*)&vbuf[prv][rr * 64 +
                                                   ((u ^ (rr & 7)) * 8)];
        o[dt] = mfma32(vf, pf_prev[kk], o[dt]);
      }
    }
  }
  const float lt = lsum + __shfl_xor(lsum, 32);
  const float inv = 1.0f / lt;
  ushort* orow = pog + ((size_t)b * N + qw + q) * D;
#pragma unroll
  for (int dt = 0; dt < 8; ++dt)
#pragma unroll
    for (int r4 = 0; r4 < 4; ++r4) {
      const unsigned u0 =
          pkh(o[dt][r4 * 4 + 0] * inv, o[dt][r4 * 4 + 1] * inv);
      const unsigned u1 =
          pkh(o[dt][r4 * 4 + 2] * inv, o[dt][r4 * 4 + 3] * inv);
      uint2 val;
      val.x = u0;
      val.y = u1;
      *(uint2*)(orow + dt * 32 + r4 * 8 + h * 4) = val;
    }
  if (h == 0) {
    const size_t r = (size_t)b * N + qw + q;
    mlg[r * 2] = m;
    mlg[r * 2 + 1] = lt;
  }
}

// ---------------- merge KV-split partials -> f16 hi/lo planes --------------
__global__ __launch_bounds__(256) void merge_kernel(
    const ushort* __restrict__ pob, const float* __restrict__ mlb,
    ushort* __restrict__ aoh, ushort* __restrict__ aol) {
  const int t = threadIdx.x;
  const int row = blockIdx.x * 8 + (t >> 5);
  const int d0 = (t & 31) * 8;
  float mv[SPLIT], lv[SPLIT];
  float mm = -1e30f;
#pragma unroll
  for (int s = 0; s < SPLIT; ++s) {
    mv[s] = mlb[(size_t)s * BN * 2 + row * 2];
    lv[s] = mlb[(size_t)s * BN * 2 + row * 2 + 1];
    mm = fmaxf(mm, mv[s]);
  }
  float wsum = 0.f, a[SPLIT];
#pragma unroll
  for (int s = 0; s < SPLIT; ++s) {
    a[s] = exp2f(mv[s] - mm) * lv[s];
    wsum += a[s];
  }
  const float invw = 1.0f / wsum;
  const size_t off = (size_t)row * D + d0;
  float r[8] = {};
#pragma unroll
  for (int s = 0; s < SPLIT; ++s) {
    const f16x8 p = *(const f16x8*)(pob + (size_t)s * BN * D + off);
    const float c = a[s] * invw;
#pragma unroll
    for (int j = 0; j < 8; ++j) r[j] += c * (float)p[j];
  }
  f16x8 rh, rl;
#pragma unroll
  for (int j = 0; j < 8; ++j) {
    rh[j] = (_Float16)r[j];
    rl[j] = (_Float16)(r[j] - (float)rh[j]);
  }
  *(f16x8*)(aoh + off) = rh;
  *(f16x8*)(aol + off) = rl;
}

// ---------------- output projection via MFMA (no LDS) ----------------
__global__ __launch_bounds__(256, 4) void proj_kernel(
    const ushort* __restrict__ aoh, const ushort* __restrict__ aol,
    const ushort* __restrict__ wot, const float* __restrict__ bias,
    float* __restrict__ out) {
  const int t = threadIdx.x;
  const int w = t >> 6, lane = t & 63;
  const int lrow = lane & 15, lhi = lane >> 4;
  const int m0 = blockIdx.x * 128 + w * 32;
  const int c0 = blockIdx.y * 64;
  f32x4 acc[2][4];
#pragma unroll
  for (int qs = 0; qs < 2; ++qs)
#pragma unroll
    for (int nt = 0; nt < 4; ++nt) acc[qs][nt] = f32x4{0.f, 0.f, 0.f, 0.f};

#pragma unroll
  for (int kc = 0; kc < D; kc += 32) {
    f16x8 ah[2], al[2], bw[4];
#pragma unroll
    for (int qs = 0; qs < 2; ++qs) {
      const size_t ao = (size_t)(m0 + qs * 16 + lrow) * D + kc + lhi * 8;
      ah[qs] = *(const f16x8*)(aoh + ao);
      al[qs] = *(const f16x8*)(aol + ao);
    }
#pragma unroll
    for (int nt = 0; nt < 4; ++nt)
      bw[nt] = *(const f16x8*)(wot + (size_t)(c0 + nt * 16 + lrow) * D + kc +
                               lhi * 8);
#pragma unroll
    for (int qs = 0; qs < 2; ++qs)
#pragma unroll
      for (int nt = 0; nt < 4; ++nt) {
        acc[qs][nt] = mfma_f16(ah[qs], bw[nt], acc[qs][nt]);
        acc[qs][nt] = mfma_f16(al[qs], bw[nt], acc[qs][nt]);
      }
  }
#pragma unroll
  for (int qs = 0; qs < 2; ++qs)
#pragma unroll
    for (int nt = 0; nt < 4; ++nt)
#pragma unroll
      for (int i = 0; i < 4; ++i) {
        const int row = m0 + qs * 16 + lhi * 4 + i;
        const int col = c0 + nt * 16 + lrow;
        out[(size_t)row * D + col] = acc[qs][nt][i] + bias[col];
      }
}

extern "C" void kernel_launch(void* const* d_in, const int* in_sizes, int n_in,
                              void* d_out, int out_size, void* d_ws, size_t ws_size,
                              hipStream_t stream) {
  const float* x = (const float*)d_in[0];
  const float* coord = (const float*)d_in[1];
  const float* ln_g = (const float*)d_in[2];
  const float* ln_b = (const float*)d_in[3];
  const float* w_qkv = (const float*)d_in[4];
  const float* w_out = (const float*)d_in[5];
  const float* b_out = (const float*)d_in[6];
  float* out = (float*)d_out;

  const size_t P = (size_t)BN * D;

  ushort* qfp = (ushort*)d_ws;
  ushort* kfp = qfp + P;
  ushort* vtp = kfp + P;
  ushort* pob = vtp + P;                      // SPLIT partial-O planes
  float* mlb = (float*)(pob + (size_t)SPLIT * P);
  ushort* wt = (ushort*)(mlb + (size_t)SPLIT * BN * 2);
  ushort* wot = wt + 768 * 256;
  // aliases (liveness-disjoint):
  ushort* nxh = pob;       // written by ln, consumed by qkv, dead before attn
  ushort* nxl = pob + P;
  ushort* aoh = qfp;       // written by merge after q/k are dead
  ushort* aol = kfp;

  hipLaunchKernelGGL(ln_kernel, dim3(BN), dim3(256), 0, stream,
                     x, ln_g, ln_b, nxh, nxl);
  hipLaunchKernelGGL(castw_kernel, dim3(1024), dim3(256), 0, stream,
                     w_qkv, w_out, wt, wot);
  hipLaunchKernelGGL(qkv_kernel, dim3(BN / 128, 12), dim3(256), 0, stream,
                     nxh, nxl, wt, coord, qfp, kfp, vtp);
  hipLaunchKernelGGL(attn_kernel, dim3(N / 256, B, SPLIT), dim3(512), 0,
                     stream, qfp, kfp, vtp, pob, mlb);
  hipLaunchKernelGGL(merge_kernel, dim3(BN / 8), dim3(256), 0, stream,
                     pob, mlb, aoh, aol);
  hipLaunchKernelGGL(proj_kernel, dim3(BN / 128, 4), dim3(256), 0, stream,
                     aoh, aol, wot, b_out, out);
}

// Round 18
// 185.927 us; speedup vs baseline: 1.5287x; 1.0498x over previous
//
#include <hip/hip_runtime.h>
#include <hip/hip_fp16.h>
#include <math.h>

constexpr int B = 4, N = 4096, D = 256;
constexpr int BN = B * N;
constexpr float EPS = 1e-5f;
// softmax scale (D^-0.5 = 1/16) * log2(e), folded into q at f16-cast time
constexpr float QSC2 = 0.0625f * 1.44269504088896340736f;

constexpr int SPLIT = 4;     // KV splits -> grid 256 blocks (1/CU)
constexpr int KVB = 32;      // keys per attn tile
constexpr int NTK = (N / SPLIT) / KVB;  // 32 tiles
constexpr float THR = 8.0f;  // defer-max threshold (base-2)

typedef __attribute__((ext_vector_type(8))) _Float16 f16x8;
typedef __attribute__((ext_vector_type(2))) __fp16 fp16x2;
typedef __attribute__((ext_vector_type(4))) float f32x4;
typedef __attribute__((ext_vector_type(16))) float f32x16;

__device__ inline f32x4 mfma_f16(f16x8 a, f16x8 b, f32x4 c) {
  return __builtin_amdgcn_mfma_f32_16x16x32_f16(a, b, c, 0, 0, 0);
}
__device__ inline f32x16 mfma32(f16x8 a, f16x8 b, f32x16 c) {
  return __builtin_amdgcn_mfma_f32_32x32x16_f16(a, b, c, 0, 0, 0);
}
__device__ inline ushort f2h(float x) {
  __half h = __float2half(x);
  return *(ushort*)&h;
}
__device__ inline float h2f(ushort u) {
  __half h;
  *(ushort*)&h = u;
  return __half2float(h);
}
__device__ inline unsigned pkh(float a, float b) {
  fp16x2 r = __builtin_amdgcn_cvt_pkrtz(a, b);
  return *(unsigned*)&r;
}
// async global->LDS, 16B per lane; lds dest = uniform base + lane*16 (HW rule)
__device__ inline void gload16(const ushort* g, ushort* l) {
  __builtin_amdgcn_global_load_lds(
      (const __attribute__((address_space(1))) void*)g,
      (__attribute__((address_space(3))) void*)l, 16, 0, 0);
}

// ---------------- LayerNorm -> normalized x as single f16 plane ------------
// (round-18: dropped the lo-plane; error budget analysis says f16 alone adds
// ~0.2-0.5% output perturbation vs the 0.114 absmax threshold)
__global__ __launch_bounds__(256) void ln_kernel(
    const float* __restrict__ x, const float* __restrict__ g,
    const float* __restrict__ bta, ushort* __restrict__ nxh) {
  const int row = blockIdx.x;
  const int t = threadIdx.x;
  const float v = x[(size_t)row * D + t];
  float s = v, ss = v * v;
#pragma unroll
  for (int o = 32; o > 0; o >>= 1) {
    s += __shfl_down(s, o);
    ss += __shfl_down(ss, o);
  }
  __shared__ float red[8];
  if ((t & 63) == 0) {
    red[t >> 6] = s;
    red[(t >> 6) + 4] = ss;
  }
  __syncthreads();
  s = red[0] + red[1] + red[2] + red[3];
  ss = red[4] + red[5] + red[6] + red[7];
  const float mu = s * (1.0f / D);
  const float var = ss * (1.0f / D) - mu * mu;
  const float rsig = rsqrtf(var + EPS);
  const float nx = (v - mu) * rsig * g[t] + bta[t];
  nxh[(size_t)row * D + t] = f2h(nx);
}

// ------------- cast + transpose weights to f16 (wt[768][256], wot[256][256])
__global__ __launch_bounds__(256) void castw_kernel(
    const float* __restrict__ w_qkv, const float* __restrict__ w_out,
    ushort* __restrict__ wt, ushort* __restrict__ wot) {
  const int id = blockIdx.x * 256 + threadIdx.x;
  if (id < 768 * 256) {
    const int n = id >> 8, k = id & 255;
    wt[id] = f2h(w_qkv[(size_t)k * 768 + n]);
  } else {
    const int j = id - 768 * 256;
    const int n = j >> 8, k = j & 255;
    wot[j] = f2h(w_out[(size_t)k * 256 + n]);
  }
}

// ---------------- QKV GEMM via MFMA (no LDS; weights L2-hot) ---------------
// Single-plane A (round-18): 8 MFMAs/kc, half of the hi/lo version.
__global__ __launch_bounds__(256, 4) void qkv_kernel(
    const ushort* __restrict__ nxh, const ushort* __restrict__ wt,
    const float* __restrict__ coord, ushort* __restrict__ qfp,
    ushort* __restrict__ kfp, ushort* __restrict__ vtp) {
  const int t = threadIdx.x;
  const int w = t >> 6, lane = t & 63;
  const int lrow = lane & 15, lhi = lane >> 4;
  const int m0 = blockIdx.x * 128 + w * 32;
  const int c0 = blockIdx.y * 64;  // within [0,768)
  f32x4 acc[2][4];
#pragma unroll
  for (int qs = 0; qs < 2; ++qs)
#pragma unroll
    for (int nt = 0; nt < 4; ++nt) acc[qs][nt] = f32x4{0.f, 0.f, 0.f, 0.f};

#pragma unroll
  for (int kc = 0; kc < D; kc += 32) {
    f16x8 ah[2], bw[4];
#pragma unroll
    for (int qs = 0; qs < 2; ++qs)
      ah[qs] = *(const f16x8*)(nxh + (size_t)(m0 + qs * 16 + lrow) * D + kc +
                               lhi * 8);
#pragma unroll
    for (int nt = 0; nt < 4; ++nt)
      bw[nt] = *(const f16x8*)(wt + (size_t)(c0 + nt * 16 + lrow) * D + kc +
                               lhi * 8);
#pragma unroll
    for (int qs = 0; qs < 2; ++qs)
#pragma unroll
      for (int nt = 0; nt < 4; ++nt)
        acc[qs][nt] = mfma_f16(ah[qs], bw[nt], acc[qs][nt]);
  }

  const int region = blockIdx.y >> 2;  // 0:q 1:k 2:v
  const int cbase = c0 & 255;
  if (region < 2) {
    const float sc = (region == 0) ? QSC2 : 1.0f;
    ushort* dp = (region == 0) ? qfp : kfp;
#pragma unroll
    for (int qs = 0; qs < 2; ++qs)
#pragma unroll
      for (int nt = 0; nt < 4; ++nt)
#pragma unroll
        for (int i = 0; i < 4; ++i) {
          const int row = m0 + qs * 16 + lhi * 4 + i;
          const int col = cbase + nt * 16 + lrow;
          const float val =
              (acc[qs][nt][i] + coord[(size_t)row * D + col]) * sc;
          dp[(size_t)row * D + col] = f2h(val);
        }
  } else {
#pragma unroll
    for (int qs = 0; qs < 2; ++qs)
#pragma unroll
      for (int nt = 0; nt < 4; ++nt)
#pragma unroll
        for (int i = 0; i < 4; ++i) {
          const int row = m0 + qs * 16 + lhi * 4 + i;
          const int col = cbase + nt * 16 + lrow;
          const int bb = row >> 12, n = row & (N - 1);
          vtp[((size_t)bb * D + col) * N + n] = f2h(acc[qs][nt][i]);
        }
  }
}

// ---------------- MFMA flash attention (32x32 swapped-operand) -------------
// 8 warps x 32 q-rows (block = 256 rows), KVB=32 keys/tile, SPLIT=4.
// QUAD-buffered K/V staging (128KB LDS), ONE s_barrier per tile, rolled loop,
// T15 deferred-PV pipeline (round-17: 114us, MfmaUtil 25%, VALU 28%).
__global__ __launch_bounds__(512, 2) void attn_kernel(
    const ushort* __restrict__ qf, const ushort* __restrict__ kf,
    const ushort* __restrict__ vt, ushort* __restrict__ pob,
    float* __restrict__ mlb) {
  __shared__ ushort kbuf[4][8192];  // [key 0..31][32 granules]    16KB each
  __shared__ ushort vbuf[4][8192];  // [d-pair 0..127][8 granules] 16KB each

  const int tid = threadIdx.x;
  const int lane = tid & 63;
  const int q = lane & 31, h = lane >> 5;
  const int w = tid >> 6;
  const int b = blockIdx.y, s = blockIdx.z;
  const int qw = blockIdx.x * 256 + w * 32;
  const int kbeg = s * (N / SPLIT);

  const ushort* qrow = qf + ((size_t)b * N + qw + q) * D;
  const ushort* kfb = kf + (size_t)b * N * D;
  const ushort* vtb = vt + (size_t)b * D * N;
  ushort* pog = pob + (size_t)s * BN * D;
  float* mlg = mlb + (size_t)s * BN * 2;

  // persistent Q chunks 0..7 (d 0..127); chunks 8..15 streamed per tile
  f16x8 qfr[8];
#pragma unroll
  for (int c = 0; c < 8; ++c)
    qfr[c] = *(const f16x8*)(qrow + c * 16 + h * 8);

  f32x16 o[8];
#pragma unroll
  for (int dt = 0; dt < 8; ++dt)
#pragma unroll
    for (int r = 0; r < 16; ++r) o[dt][r] = 0.f;
  float m = -1e30f, lsum = 0.f;
  float f_prev = 1.0f;
  bool need_prev = false;
  f16x8 pf_prev[2];

  // stage one 32-key K+V tile; 4 granule-loads per thread (2 K + 2 V).
  // K: granule G -> key=G>>5, slot=G&31; src d-gran = slot^(key&7)
  // V: granule G -> r=G>>3, slot=G&7; u=slot^(r&7); d=2r+(u>>2); sg=u&3
  auto stage = [&](int bi, int k0) {
#pragma unroll
    for (int i = 0; i < 2; ++i) {
      const int g = i * 512 + tid;
      const int key = g >> 5, slot = g & 31;
      gload16(kfb + (size_t)(k0 + key) * D + ((slot ^ (key & 7)) * 8),
              &kbuf[bi][g * 8]);
    }
#pragma unroll
    for (int i = 0; i < 2; ++i) {
      const int g = i * 512 + tid;
      const int r = g >> 3, slot = g & 7;
      const int u = slot ^ (r & 7);
      const int d = r * 2 + (u >> 2);
      gload16(vtb + (size_t)d * N + k0 + ((u & 3) * 8), &vbuf[bi][g * 8]);
    }
  };

  stage(0, kbeg);

  for (int t = 0; t < NTK; ++t) {
    const int cur = t & 3;
    const int prv = (t + 3) & 3;
    // stream Q chunks 8..15 (issued BEFORE next-tile stage so vmcnt(12)
    // drains exactly the current tile's 4 stage loads)
    f16x8 qs[8];
#pragma unroll
    for (int c = 0; c < 8; ++c)
      qs[c] = *(const f16x8*)(qrow + (8 + c) * 16 + h * 8);
    if (t + 1 < NTK) {
      stage((t + 1) & 3, kbeg + (t + 1) * KVB);
      asm volatile("s_waitcnt vmcnt(12)" ::: "memory");  // drain stage(t)
    } else {
      asm volatile("s_waitcnt vmcnt(8)" ::: "memory");   // qs still in flight
    }
    __builtin_amdgcn_sched_barrier(0);
    __builtin_amdgcn_s_barrier();   // the ONLY barrier per tile
    __builtin_amdgcn_sched_barrier(0);

    // ---- QK(t): S^T = K Q, single 16-MFMA chain into p ----
    f32x16 p;
#pragma unroll
    for (int r = 0; r < 16; ++r) p[r] = 0.f;
    const int ksw = (q & 7);
    __builtin_amdgcn_s_setprio(1);
#pragma unroll
    for (int c = 0; c < 16; ++c) {
      const f16x8 qv = (c < 8) ? qfr[c] : qs[c - 8];
      const f16x8 ka = *(const f16x8*)&kbuf[cur][q * 256 +
                                                 (((c * 2 + h) ^ ksw) * 8)];
      p = mfma32(ka, qv, p);
    }
    __builtin_amdgcn_s_setprio(0);

    // ---- deferred: rescale o by f(t-1), then PV(t-1) ----
    if (t > 0) {
      if (need_prev) {
#pragma unroll
        for (int dt = 0; dt < 8; ++dt) o[dt] *= f_prev;
      }
      __builtin_amdgcn_s_setprio(1);
#pragma unroll
      for (int dt = 0; dt < 8; ++dt) {
        const int d = dt * 32 + q;
        const int rr = d >> 1;
#pragma unroll
        for (int kk = 0; kk < 2; ++kk) {
          const int u = (d & 1) * 4 + kk * 2 + h;
          const f16x8 vf = *(const f16x8*)&vbuf[prv][rr * 64 +
                                                     ((u ^ (rr & 7)) * 8)];
          o[dt] = mfma32(vf, pf_prev[kk], o[dt]);
        }
      }
      __builtin_amdgcn_s_setprio(0);
    }

    // ---- softmax(t): runs while PV(t-1) drains the matrix pipe ----
    float tm[8];
#pragma unroll
    for (int j = 0; j < 8; ++j) tm[j] = fmaxf(p[2 * j], p[2 * j + 1]);
    float pmax = fmaxf(fmaxf(fmaxf(tm[0], tm[1]), fmaxf(tm[2], tm[3])),
                       fmaxf(fmaxf(tm[4], tm[5]), fmaxf(tm[6], tm[7])));
    const float pm = fmaxf(pmax, __shfl_xor(pmax, 32));
    const bool need = pm > m + THR;
    if (__any(need)) {
      const float mn = fmaxf(m, pm);
      f_prev = exp2f(m - mn);
      m = mn;
      lsum *= f_prev;
      need_prev = true;
    } else {
      need_prev = false;
    }
#pragma unroll
    for (int r = 0; r < 16; ++r) {
      p[r] = exp2f(p[r] - m);
      lsum += p[r];
    }

    // ---- pack P -> pf_prev (2 B-frags of 16 keys) via cvt_pkrtz + shfl ----
    // lane(q,h) owns packed words: x=keys(4h,4h+1) z=(4h+2,4h+3)
    // y=(8+4h,9+4h) wv=(10+4h,11+4h). B-frag word_j = keys(h*8+2j,+1):
    // word0 = h? partner-y : x ; word1 = h? partner-wv : z ;
    // word2 = h? y : partner-x ; word3 = h? wv : partner-z.
#pragma unroll
    for (int kk = 0; kk < 2; ++kk) {
      const int sub = kk * 8;
      unsigned x = pkh(p[sub + 0], p[sub + 1]);
      unsigned z = pkh(p[sub + 2], p[sub + 3]);
      unsigned y = pkh(p[sub + 4], p[sub + 5]);
      unsigned wv = pkh(p[sub + 6], p[sub + 7]);
      const unsigned xs = __shfl_xor(x, 32);
      const unsigned zs = __shfl_xor(z, 32);
      const unsigned ys = __shfl_xor(y, 32);
      const unsigned ws = __shfl_xor(wv, 32);
      union { f16x8 v; unsigned u[4]; } pu;
      pu.u[0] = h ? ys : x;
      pu.u[1] = h ? ws : z;
      pu.u[2] = h ? y : xs;
      pu.u[3] = h ? wv : zs;
      pf_prev[kk] = pu.v;
    }
  }

  // ---- epilogue: final rescale + PV(NTK-1), then normalize & write ----
  if (need_prev) {
#pragma unroll
    for (int dt = 0; dt < 8; ++dt) o[dt] *= f_prev;
  }
  {
    const int prv = (NTK - 1) & 3;
#pragma unroll
    for (int dt = 0; dt < 8; ++dt) {
      const int d = dt * 32 + q;
      const int rr = d >> 1;
#pragma unroll
      for (int kk = 0; kk < 2; ++kk) {
        const int u = (d & 1) * 4 + kk * 2 + h;
        const f16x8 vf = *(const f16x8*)&vbuf[prv][rr * 64 +
                                                   ((u ^ (rr & 7)) * 8)];
        o[dt] = mfma32(vf, pf_prev[kk], o[dt]);
      }
    }
  }
  const float lt = lsum + __shfl_xor(lsum, 32);
  const float inv = 1.0f / lt;
  ushort* orow = pog + ((size_t)b * N + qw + q) * D;
#pragma unroll
  for (int dt = 0; dt < 8; ++dt)
#pragma unroll
    for (int r4 = 0; r4 < 4; ++r4) {
      const unsigned u0 =
          pkh(o[dt][r4 * 4 + 0] * inv, o[dt][r4 * 4 + 1] * inv);
      const unsigned u1 =
          pkh(o[dt][r4 * 4 + 2] * inv, o[dt][r4 * 4 + 3] * inv);
      uint2 val;
      val.x = u0;
      val.y = u1;
      *(uint2*)(orow + dt * 32 + r4 * 8 + h * 4) = val;
    }
  if (h == 0) {
    const size_t r = (size_t)b * N + qw + q;
    mlg[r * 2] = m;
    mlg[r * 2 + 1] = lt;
  }
}

// ---------------- merge KV-split partials -> single f16 plane --------------
__global__ __launch_bounds__(256) void merge_kernel(
    const ushort* __restrict__ pob, const float* __restrict__ mlb,
    ushort* __restrict__ aoh) {
  const int t = threadIdx.x;
  const int row = blockIdx.x * 8 + (t >> 5);
  const int d0 = (t & 31) * 8;
  float mv[SPLIT], lv[SPLIT];
  float mm = -1e30f;
#pragma unroll
  for (int s = 0; s < SPLIT; ++s) {
    mv[s] = mlb[(size_t)s * BN * 2 + row * 2];
    lv[s] = mlb[(size_t)s * BN * 2 + row * 2 + 1];
    mm = fmaxf(mm, mv[s]);
  }
  float wsum = 0.f, a[SPLIT];
#pragma unroll
  for (int s = 0; s < SPLIT; ++s) {
    a[s] = exp2f(mv[s] - mm) * lv[s];
    wsum += a[s];
  }
  const float invw = 1.0f / wsum;
  const size_t off = (size_t)row * D + d0;
  float r[8] = {};
#pragma unroll
  for (int s = 0; s < SPLIT; ++s) {
    const f16x8 p = *(const f16x8*)(pob + (size_t)s * BN * D + off);
    const float c = a[s] * invw;
#pragma unroll
    for (int j = 0; j < 8; ++j) r[j] += c * (float)p[j];
  }
  f16x8 rh;
#pragma unroll
  for (int j = 0; j < 8; ++j) rh[j] = (_Float16)r[j];
  *(f16x8*)(aoh + off) = rh;
}

// ---------------- output projection via MFMA (no LDS, single-plane A) ------
__global__ __launch_bounds__(256, 4) void proj_kernel(
    const ushort* __restrict__ aoh, const ushort* __restrict__ wot,
    const float* __restrict__ bias, float* __restrict__ out) {
  const int t = threadIdx.x;
  const int w = t >> 6, lane = t & 63;
  const int lrow = lane & 15, lhi = lane >> 4;
  const int m0 = blockIdx.x * 128 + w * 32;
  const int c0 = blockIdx.y * 64;
  f32x4 acc[2][4];
#pragma unroll
  for (int qs = 0; qs < 2; ++qs)
#pragma unroll
    for (int nt = 0; nt < 4; ++nt) acc[qs][nt] = f32x4{0.f, 0.f, 0.f, 0.f};

#pragma unroll
  for (int kc = 0; kc < D; kc += 32) {
    f16x8 ah[2], bw[4];
#pragma unroll
    for (int qs = 0; qs < 2; ++qs)
      ah[qs] = *(const f16x8*)(aoh + (size_t)(m0 + qs * 16 + lrow) * D + kc +
                               lhi * 8);
#pragma unroll
    for (int nt = 0; nt < 4; ++nt)
      bw[nt] = *(const f16x8*)(wot + (size_t)(c0 + nt * 16 + lrow) * D + kc +
                               lhi * 8);
#pragma unroll
    for (int qs = 0; qs < 2; ++qs)
#pragma unroll
      for (int nt = 0; nt < 4; ++nt)
        acc[qs][nt] = mfma_f16(ah[qs], bw[nt], acc[qs][nt]);
  }
#pragma unroll
  for (int qs = 0; qs < 2; ++qs)
#pragma unroll
    for (int nt = 0; nt < 4; ++nt)
#pragma unroll
      for (int i = 0; i < 4; ++i) {
        const int row = m0 + qs * 16 + lhi * 4 + i;
        const int col = c0 + nt * 16 + lrow;
        out[(size_t)row * D + col] = acc[qs][nt][i] + bias[col];
      }
}

extern "C" void kernel_launch(void* const* d_in, const int* in_sizes, int n_in,
                              void* d_out, int out_size, void* d_ws, size_t ws_size,
                              hipStream_t stream) {
  const float* x = (const float*)d_in[0];
  const float* coord = (const float*)d_in[1];
  const float* ln_g = (const float*)d_in[2];
  const float* ln_b = (const float*)d_in[3];
  const float* w_qkv = (const float*)d_in[4];
  const float* w_out = (const float*)d_in[5];
  const float* b_out = (const float*)d_in[6];
  float* out = (float*)d_out;

  const size_t P = (size_t)BN * D;

  ushort* qfp = (ushort*)d_ws;
  ushort* kfp = qfp + P;
  ushort* vtp = kfp + P;
  ushort* pob = vtp + P;                      // SPLIT partial-O planes
  float* mlb = (float*)(pob + (size_t)SPLIT * P);
  ushort* wt = (ushort*)(mlb + (size_t)SPLIT * BN * 2);
  ushort* wot = wt + 768 * 256;
  // aliases (liveness-disjoint):
  ushort* nxh = pob;       // written by ln, consumed by qkv, dead before attn
  ushort* aoh = qfp;       // written by merge after q/k are dead

  hipLaunchKernelGGL(ln_kernel, dim3(BN), dim3(256), 0, stream,
                     x, ln_g, ln_b, nxh);
  hipLaunchKernelGGL(castw_kernel, dim3(1024), dim3(256), 0, stream,
                     w_qkv, w_out, wt, wot);
  hipLaunchKernelGGL(qkv_kernel, dim3(BN / 128, 12), dim3(256), 0, stream,
                     nxh, wt, coord, qfp, kfp, vtp);
  hipLaunchKernelGGL(attn_kernel, dim3(N / 256, B, SPLIT), dim3(512), 0,
                     stream, qfp, kfp, vtp, pob, mlb);
  hipLaunchKernelGGL(merge_kernel, dim3(BN / 8), dim3(256), 0, stream,
                     pob, mlb, aoh);
  hipLaunchKernelGGL(proj_kernel, dim3(BN / 128, 4), dim3(256), 0, stream,
                     aoh, wot, b_out, out);
}

// Round 19
// 185.096 us; speedup vs baseline: 1.5356x; 1.0045x over previous
//
#include <hip/hip_runtime.h>
#include <hip/hip_fp16.h>
#include <math.h>

constexpr int B = 4, N = 4096, D = 256;
constexpr int BN = B * N;
constexpr float EPS = 1e-5f;
// softmax scale (D^-0.5 = 1/16) * log2(e), folded into q at f16-cast time
constexpr float QSC2 = 0.0625f * 1.44269504088896340736f;

constexpr int SPLIT = 4;     // KV splits -> grid 256 blocks (1/CU)
constexpr int KVB = 32;      // keys per attn tile
constexpr int NTK = (N / SPLIT) / KVB;  // 32 tiles
constexpr float THR = 8.0f;  // defer-max threshold (base-2)

typedef __attribute__((ext_vector_type(8))) _Float16 f16x8;
typedef __attribute__((ext_vector_type(2))) __fp16 fp16x2;
typedef __attribute__((ext_vector_type(4))) float f32x4;
typedef __attribute__((ext_vector_type(16))) float f32x16;

__device__ inline f32x4 mfma_f16(f16x8 a, f16x8 b, f32x4 c) {
  return __builtin_amdgcn_mfma_f32_16x16x32_f16(a, b, c, 0, 0, 0);
}
__device__ inline f32x16 mfma32(f16x8 a, f16x8 b, f32x16 c) {
  return __builtin_amdgcn_mfma_f32_32x32x16_f16(a, b, c, 0, 0, 0);
}
__device__ inline ushort f2h(float x) {
  __half h = __float2half(x);
  return *(ushort*)&h;
}
__device__ inline float h2f(ushort u) {
  __half h;
  *(ushort*)&h = u;
  return __half2float(h);
}
__device__ inline unsigned pkh(float a, float b) {
  fp16x2 r = __builtin_amdgcn_cvt_pkrtz(a, b);
  return *(unsigned*)&r;
}
// async global->LDS, 16B per lane; lds dest = uniform base + lane*16 (HW rule)
__device__ inline void gload16(const ushort* g, ushort* l) {
  __builtin_amdgcn_global_load_lds(
      (const __attribute__((address_space(1))) void*)g,
      (__attribute__((address_space(3))) void*)l, 16, 0, 0);
}

// ---------------- LayerNorm -> normalized x as single f16 plane ------------
__global__ __launch_bounds__(256) void ln_kernel(
    const float* __restrict__ x, const float* __restrict__ g,
    const float* __restrict__ bta, ushort* __restrict__ nxh) {
  const int row = blockIdx.x;
  const int t = threadIdx.x;
  const float v = x[(size_t)row * D + t];
  float s = v, ss = v * v;
#pragma unroll
  for (int o = 32; o > 0; o >>= 1) {
    s += __shfl_down(s, o);
    ss += __shfl_down(ss, o);
  }
  __shared__ float red[8];
  if ((t & 63) == 0) {
    red[t >> 6] = s;
    red[(t >> 6) + 4] = ss;
  }
  __syncthreads();
  s = red[0] + red[1] + red[2] + red[3];
  ss = red[4] + red[5] + red[6] + red[7];
  const float mu = s * (1.0f / D);
  const float var = ss * (1.0f / D) - mu * mu;
  const float rsig = rsqrtf(var + EPS);
  const float nx = (v - mu) * rsig * g[t] + bta[t];
  nxh[(size_t)row * D + t] = f2h(nx);
}

// ------------- cast + transpose weights to f16 (wt[768][256], wot[256][256])
__global__ __launch_bounds__(256) void castw_kernel(
    const float* __restrict__ w_qkv, const float* __restrict__ w_out,
    ushort* __restrict__ wt, ushort* __restrict__ wot) {
  const int id = blockIdx.x * 256 + threadIdx.x;
  if (id < 768 * 256) {
    const int n = id >> 8, k = id & 255;
    wt[id] = f2h(w_qkv[(size_t)k * 768 + n]);
  } else {
    const int j = id - 768 * 256;
    const int n = j >> 8, k = j & 255;
    wot[j] = f2h(w_out[(size_t)k * 256 + n]);
  }
}

// ---------------- QKV GEMM via MFMA (no LDS; weights L2-hot) ---------------
__global__ __launch_bounds__(256, 4) void qkv_kernel(
    const ushort* __restrict__ nxh, const ushort* __restrict__ wt,
    const float* __restrict__ coord, ushort* __restrict__ qfp,
    ushort* __restrict__ kfp, ushort* __restrict__ vtp) {
  const int t = threadIdx.x;
  const int w = t >> 6, lane = t & 63;
  const int lrow = lane & 15, lhi = lane >> 4;
  const int m0 = blockIdx.x * 128 + w * 32;
  const int c0 = blockIdx.y * 64;  // within [0,768)
  f32x4 acc[2][4];
#pragma unroll
  for (int qs = 0; qs < 2; ++qs)
#pragma unroll
    for (int nt = 0; nt < 4; ++nt) acc[qs][nt] = f32x4{0.f, 0.f, 0.f, 0.f};

#pragma unroll
  for (int kc = 0; kc < D; kc += 32) {
    f16x8 ah[2], bw[4];
#pragma unroll
    for (int qs = 0; qs < 2; ++qs)
      ah[qs] = *(const f16x8*)(nxh + (size_t)(m0 + qs * 16 + lrow) * D + kc +
                               lhi * 8);
#pragma unroll
    for (int nt = 0; nt < 4; ++nt)
      bw[nt] = *(const f16x8*)(wt + (size_t)(c0 + nt * 16 + lrow) * D + kc +
                               lhi * 8);
#pragma unroll
    for (int qs = 0; qs < 2; ++qs)
#pragma unroll
      for (int nt = 0; nt < 4; ++nt)
        acc[qs][nt] = mfma_f16(ah[qs], bw[nt], acc[qs][nt]);
  }

  const int region = blockIdx.y >> 2;  // 0:q 1:k 2:v
  const int cbase = c0 & 255;
  if (region < 2) {
    const float sc = (region == 0) ? QSC2 : 1.0f;
    ushort* dp = (region == 0) ? qfp : kfp;
#pragma unroll
    for (int qs = 0; qs < 2; ++qs)
#pragma unroll
      for (int nt = 0; nt < 4; ++nt)
#pragma unroll
        for (int i = 0; i < 4; ++i) {
          const int row = m0 + qs * 16 + lhi * 4 + i;
          const int col = cbase + nt * 16 + lrow;
          const float val =
              (acc[qs][nt][i] + coord[(size_t)row * D + col]) * sc;
          dp[(size_t)row * D + col] = f2h(val);
        }
  } else {
#pragma unroll
    for (int qs = 0; qs < 2; ++qs)
#pragma unroll
      for (int nt = 0; nt < 4; ++nt)
#pragma unroll
        for (int i = 0; i < 4; ++i) {
          const int row = m0 + qs * 16 + lhi * 4 + i;
          const int col = cbase + nt * 16 + lrow;
          const int bb = row >> 12, n = row & (N - 1);
          vtp[((size_t)bb * D + col) * N + n] = f2h(acc[qs][nt][i]);
        }
  }
}

// ---------------- MFMA flash attention (32x32 swapped-operand) -------------
// 8 warps x 32 q-rows (block = 256 rows), KVB=32 keys/tile, SPLIT=4.
// QUAD-buffered K/V staging (128KB LDS), ONE s_barrier per tile, rolled loop,
// T15 deferred-PV pipeline (round-17: 114us, MfmaUtil 25%, VALU 28%).
__global__ __launch_bounds__(512, 2) void attn_kernel(
    const ushort* __restrict__ qf, const ushort* __restrict__ kf,
    const ushort* __restrict__ vt, ushort* __restrict__ pob,
    float* __restrict__ mlb) {
  __shared__ ushort kbuf[4][8192];  // [key 0..31][32 granules]    16KB each
  __shared__ ushort vbuf[4][8192];  // [d-pair 0..127][8 granules] 16KB each

  const int tid = threadIdx.x;
  const int lane = tid & 63;
  const int q = lane & 31, h = lane >> 5;
  const int w = tid >> 6;
  const int b = blockIdx.y, s = blockIdx.z;
  const int qw = blockIdx.x * 256 + w * 32;
  const int kbeg = s * (N / SPLIT);

  const ushort* qrow = qf + ((size_t)b * N + qw + q) * D;
  const ushort* kfb = kf + (size_t)b * N * D;
  const ushort* vtb = vt + (size_t)b * D * N;
  ushort* pog = pob + (size_t)s * BN * D;
  float* mlg = mlb + (size_t)s * BN * 2;

  // persistent Q chunks 0..7 (d 0..127); chunks 8..15 streamed per tile
  f16x8 qfr[8];
#pragma unroll
  for (int c = 0; c < 8; ++c)
    qfr[c] = *(const f16x8*)(qrow + c * 16 + h * 8);

  f32x16 o[8];
#pragma unroll
  for (int dt = 0; dt < 8; ++dt)
#pragma unroll
    for (int r = 0; r < 16; ++r) o[dt][r] = 0.f;
  float m = -1e30f, lsum = 0.f;
  float f_prev = 1.0f;
  bool need_prev = false;
  f16x8 pf_prev[2];

  // stage one 32-key K+V tile; 4 granule-loads per thread (2 K + 2 V).
  // K: granule G -> key=G>>5, slot=G&31; src d-gran = slot^(key&7)
  // V: granule G -> r=G>>3, slot=G&7; u=slot^(r&7); d=2r+(u>>2); sg=u&3
  auto stage = [&](int bi, int k0) {
#pragma unroll
    for (int i = 0; i < 2; ++i) {
      const int g = i * 512 + tid;
      const int key = g >> 5, slot = g & 31;
      gload16(kfb + (size_t)(k0 + key) * D + ((slot ^ (key & 7)) * 8),
              &kbuf[bi][g * 8]);
    }
#pragma unroll
    for (int i = 0; i < 2; ++i) {
      const int g = i * 512 + tid;
      const int r = g >> 3, slot = g & 7;
      const int u = slot ^ (r & 7);
      const int d = r * 2 + (u >> 2);
      gload16(vtb + (size_t)d * N + k0 + ((u & 3) * 8), &vbuf[bi][g * 8]);
    }
  };

  stage(0, kbeg);

  for (int t = 0; t < NTK; ++t) {
    const int cur = t & 3;
    const int prv = (t + 3) & 3;
    // stream Q chunks 8..15 (issued BEFORE next-tile stage so vmcnt(12)
    // drains exactly the current tile's 4 stage loads)
    f16x8 qs[8];
#pragma unroll
    for (int c = 0; c < 8; ++c)
      qs[c] = *(const f16x8*)(qrow + (8 + c) * 16 + h * 8);
    if (t + 1 < NTK) {
      stage((t + 1) & 3, kbeg + (t + 1) * KVB);
      asm volatile("s_waitcnt vmcnt(12)" ::: "memory");  // drain stage(t)
    } else {
      asm volatile("s_waitcnt vmcnt(8)" ::: "memory");   // qs still in flight
    }
    __builtin_amdgcn_sched_barrier(0);
    __builtin_amdgcn_s_barrier();   // the ONLY barrier per tile
    __builtin_amdgcn_sched_barrier(0);

    // ---- QK(t): S^T = K Q, single 16-MFMA chain into p ----
    f32x16 p;
#pragma unroll
    for (int r = 0; r < 16; ++r) p[r] = 0.f;
    const int ksw = (q & 7);
    __builtin_amdgcn_s_setprio(1);
#pragma unroll
    for (int c = 0; c < 16; ++c) {
      const f16x8 qv = (c < 8) ? qfr[c] : qs[c - 8];
      const f16x8 ka = *(const f16x8*)&kbuf[cur][q * 256 +
                                                 (((c * 2 + h) ^ ksw) * 8)];
      p = mfma32(ka, qv, p);
    }
    __builtin_amdgcn_s_setprio(0);

    // ---- deferred: rescale o by f(t-1), then PV(t-1) ----
    if (t > 0) {
      if (need_prev) {
#pragma unroll
        for (int dt = 0; dt < 8; ++dt) o[dt] *= f_prev;
      }
      __builtin_amdgcn_s_setprio(1);
#pragma unroll
      for (int dt = 0; dt < 8; ++dt) {
        const int d = dt * 32 + q;
        const int rr = d >> 1;
#pragma unroll
        for (int kk = 0; kk < 2; ++kk) {
          const int u = (d & 1) * 4 + kk * 2 + h;
          const f16x8 vf = *(const f16x8*)&vbuf[prv][rr * 64 +
                                                     ((u ^ (rr & 7)) * 8)];
          o[dt] = mfma32(vf, pf_prev[kk], o[dt]);
        }
      }
      __builtin_amdgcn_s_setprio(0);
    }

    // ---- softmax(t): runs while PV(t-1) drains the matrix pipe ----
    float tm[8];
#pragma unroll
    for (int j = 0; j < 8; ++j) tm[j] = fmaxf(p[2 * j], p[2 * j + 1]);
    float pmax = fmaxf(fmaxf(fmaxf(tm[0], tm[1]), fmaxf(tm[2], tm[3])),
                       fmaxf(fmaxf(tm[4], tm[5]), fmaxf(tm[6], tm[7])));
    const float pm = fmaxf(pmax, __shfl_xor(pmax, 32));
    const bool need = pm > m + THR;
    if (__any(need)) {
      const float mn = fmaxf(m, pm);
      f_prev = exp2f(m - mn);
      m = mn;
      lsum *= f_prev;
      need_prev = true;
    } else {
      need_prev = false;
    }
#pragma unroll
    for (int r = 0; r < 16; ++r) {
      p[r] = exp2f(p[r] - m);
      lsum += p[r];
    }

    // ---- pack P -> pf_prev (2 B-frags of 16 keys) via cvt_pkrtz + shfl ----
    // lane(q,h) owns packed words: x=keys(4h,4h+1) z=(4h+2,4h+3)
    // y=(8+4h,9+4h) wv=(10+4h,11+4h). B-frag word_j = keys(h*8+2j,+1):
    // word0 = h? partner-y : x ; word1 = h? partner-wv : z ;
    // word2 = h? y : partner-x ; word3 = h? wv : partner-z.
#pragma unroll
    for (int kk = 0; kk < 2; ++kk) {
      const int sub = kk * 8;
      unsigned x = pkh(p[sub + 0], p[sub + 1]);
      unsigned z = pkh(p[sub + 2], p[sub + 3]);
      unsigned y = pkh(p[sub + 4], p[sub + 5]);
      unsigned wv = pkh(p[sub + 6], p[sub + 7]);
      const unsigned xs = __shfl_xor(x, 32);
      const unsigned zs = __shfl_xor(z, 32);
      const unsigned ys = __shfl_xor(y, 32);
      const unsigned ws = __shfl_xor(wv, 32);
      union { f16x8 v; unsigned u[4]; } pu;
      pu.u[0] = h ? ys : x;
      pu.u[1] = h ? ws : z;
      pu.u[2] = h ? y : xs;
      pu.u[3] = h ? wv : zs;
      pf_prev[kk] = pu.v;
    }
  }

  // ---- epilogue: final rescale + PV(NTK-1), then normalize & write ----
  if (need_prev) {
#pragma unroll
    for (int dt = 0; dt < 8; ++dt) o[dt] *= f_prev;
  }
  {
    const int prv = (NTK - 1) & 3;
#pragma unroll
    for (int dt = 0; dt < 8; ++dt) {
      const int d = dt * 32 + q;
      const int rr = d >> 1;
#pragma unroll
      for (int kk = 0; kk < 2; ++kk) {
        const int u = (d & 1) * 4 + kk * 2 + h;
        const f16x8 vf = *(const f16x8*)&vbuf[prv][rr * 64 +
                                                   ((u ^ (rr & 7)) * 8)];
        o[dt] = mfma32(vf, pf_prev[kk], o[dt]);
      }
    }
  }
  const float lt = lsum + __shfl_xor(lsum, 32);
  const float inv = 1.0f / lt;
  ushort* orow = pog + ((size_t)b * N + qw + q) * D;
#pragma unroll
  for (int dt = 0; dt < 8; ++dt)
#pragma unroll
    for (int r4 = 0; r4 < 4; ++r4) {
      const unsigned u0 =
          pkh(o[dt][r4 * 4 + 0] * inv, o[dt][r4 * 4 + 1] * inv);
      const unsigned u1 =
          pkh(o[dt][r4 * 4 + 2] * inv, o[dt][r4 * 4 + 3] * inv);
      uint2 val;
      val.x = u0;
      val.y = u1;
      *(uint2*)(orow + dt * 32 + r4 * 8 + h * 4) = val;
    }
  if (h == 0) {
    const size_t r = (size_t)b * N + qw + q;
    mlg[r * 2] = m;
    mlg[r * 2 + 1] = lt;
  }
}

// -------- fused merge + output projection via MFMA (round-19) --------------
// The KV-split merge is a per-row convex combination O = sum_s c[s]*O_s; the
// A-fragment for lane (lrow,lhi) covers exactly one row, so each thread
// computes its 2 rows' weights once and blends the 4 partial-plane fragments
// in-register inside the GEMM A-load. Kills merge's write + proj's re-read.
__global__ __launch_bounds__(256, 4) void projm_kernel(
    const ushort* __restrict__ pob, const float* __restrict__ mlb,
    const ushort* __restrict__ wot, const float* __restrict__ bias,
    float* __restrict__ out) {
  const int t = threadIdx.x;
  const int w = t >> 6, lane = t & 63;
  const int lrow = lane & 15, lhi = lane >> 4;
  const int m0 = blockIdx.x * 128 + w * 32;
  const int c0 = blockIdx.y * 64;

  // per-thread merge weights for rows m0+lrow, m0+16+lrow
  float cw[2][SPLIT];
#pragma unroll
  for (int qs = 0; qs < 2; ++qs) {
    const int row = m0 + qs * 16 + lrow;
    float mv[SPLIT], lv[SPLIT], mm = -1e30f;
#pragma unroll
    for (int s = 0; s < SPLIT; ++s) {
      mv[s] = mlb[(size_t)s * BN * 2 + row * 2];
      lv[s] = mlb[(size_t)s * BN * 2 + row * 2 + 1];
      mm = fmaxf(mm, mv[s]);
    }
    float wsum = 0.f;
#pragma unroll
    for (int s = 0; s < SPLIT; ++s) {
      cw[qs][s] = exp2f(mv[s] - mm) * lv[s];
      wsum += cw[qs][s];
    }
    const float invw = 1.0f / wsum;
#pragma unroll
    for (int s = 0; s < SPLIT; ++s) cw[qs][s] *= invw;
  }

  f32x4 acc[2][4];
#pragma unroll
  for (int qs = 0; qs < 2; ++qs)
#pragma unroll
    for (int nt = 0; nt < 4; ++nt) acc[qs][nt] = f32x4{0.f, 0.f, 0.f, 0.f};

#pragma unroll
  for (int kc = 0; kc < D; kc += 32) {
    f16x8 ah[2], bw[4];
#pragma unroll
    for (int qs = 0; qs < 2; ++qs) {
      const size_t off = (size_t)(m0 + qs * 16 + lrow) * D + kc + lhi * 8;
      float v[8] = {};
#pragma unroll
      for (int s = 0; s < SPLIT; ++s) {
        const f16x8 ps = *(const f16x8*)(pob + (size_t)s * BN * D + off);
        const float c = cw[qs][s];
#pragma unroll
        for (int j = 0; j < 8; ++j) v[j] += c * (float)ps[j];
      }
      f16x8 a;
#pragma unroll
      for (int j = 0; j < 8; ++j) a[j] = (_Float16)v[j];
      ah[qs] = a;
    }
#pragma unroll
    for (int nt = 0; nt < 4; ++nt)
      bw[nt] = *(const f16x8*)(wot + (size_t)(c0 + nt * 16 + lrow) * D + kc +
                               lhi * 8);
#pragma unroll
    for (int qs = 0; qs < 2; ++qs)
#pragma unroll
      for (int nt = 0; nt < 4; ++nt)
        acc[qs][nt] = mfma_f16(ah[qs], bw[nt], acc[qs][nt]);
  }
#pragma unroll
  for (int qs = 0; qs < 2; ++qs)
#pragma unroll
    for (int nt = 0; nt < 4; ++nt)
#pragma unroll
      for (int i = 0; i < 4; ++i) {
        const int row = m0 + qs * 16 + lhi * 4 + i;
        const int col = c0 + nt * 16 + lrow;
        out[(size_t)row * D + col] = acc[qs][nt][i] + bias[col];
      }
}

extern "C" void kernel_launch(void* const* d_in, const int* in_sizes, int n_in,
                              void* d_out, int out_size, void* d_ws, size_t ws_size,
                              hipStream_t stream) {
  const float* x = (const float*)d_in[0];
  const float* coord = (const float*)d_in[1];
  const float* ln_g = (const float*)d_in[2];
  const float* ln_b = (const float*)d_in[3];
  const float* w_qkv = (const float*)d_in[4];
  const float* w_out = (const float*)d_in[5];
  const float* b_out = (const float*)d_in[6];
  float* out = (float*)d_out;

  const size_t P = (size_t)BN * D;

  ushort* qfp = (ushort*)d_ws;
  ushort* kfp = qfp + P;
  ushort* vtp = kfp + P;
  ushort* pob = vtp + P;                      // SPLIT partial-O planes
  float* mlb = (float*)(pob + (size_t)SPLIT * P);
  ushort* wt = (ushort*)(mlb + (size_t)SPLIT * BN * 2);
  ushort* wot = wt + 768 * 256;
  // alias (liveness-disjoint):
  ushort* nxh = pob;       // written by ln, consumed by qkv, dead before attn

  hipLaunchKernelGGL(ln_kernel, dim3(BN), dim3(256), 0, stream,
                     x, ln_g, ln_b, nxh);
  hipLaunchKernelGGL(castw_kernel, dim3(1024), dim3(256), 0, stream,
                     w_qkv, w_out, wt, wot);
  hipLaunchKernelGGL(qkv_kernel, dim3(BN / 128, 12), dim3(256), 0, stream,
                     nxh, wt, coord, qfp, kfp, vtp);
  hipLaunchKernelGGL(attn_kernel, dim3(N / 256, B, SPLIT), dim3(512), 0,
                     stream, qfp, kfp, vtp, pob, mlb);
  hipLaunchKernelGGL(projm_kernel, dim3(BN / 128, 4), dim3(256), 0, stream,
                     pob, mlb, wot, b_out, out);
}

// Round 21
// 174.307 us; speedup vs baseline: 1.6306x; 1.0619x over previous
//
#include <hip/hip_runtime.h>
#include <hip/hip_fp16.h>
#include <math.h>

constexpr int B = 4, N = 4096, D = 256;
constexpr int BN = B * N;
constexpr float EPS = 1e-5f;
// softmax scale (D^-0.5 = 1/16) * log2(e), folded into q at f16-cast time
constexpr float QSC2 = 0.0625f * 1.44269504088896340736f;

constexpr int SPLIT = 4;     // KV splits -> grid 256 blocks (1/CU)
constexpr int KVB = 32;      // keys per attn tile
constexpr int NTK = (N / SPLIT) / KVB;  // 32 tiles
constexpr float THR = 8.0f;  // defer-max threshold (base-2)

typedef __attribute__((ext_vector_type(8))) _Float16 f16x8;
typedef __attribute__((ext_vector_type(2))) __fp16 fp16x2;
typedef __attribute__((ext_vector_type(4))) float f32x4;
typedef __attribute__((ext_vector_type(16))) float f32x16;

__device__ inline f32x4 mfma_f16(f16x8 a, f16x8 b, f32x4 c) {
  return __builtin_amdgcn_mfma_f32_16x16x32_f16(a, b, c, 0, 0, 0);
}
__device__ inline f32x16 mfma32(f16x8 a, f16x8 b, f32x16 c) {
  return __builtin_amdgcn_mfma_f32_32x32x16_f16(a, b, c, 0, 0, 0);
}
__device__ inline ushort f2h(float x) {
  __half h = __float2half(x);
  return *(ushort*)&h;
}
__device__ inline float h2f(ushort u) {
  __half h;
  *(ushort*)&h = u;
  return __half2float(h);
}
__device__ inline unsigned pkh(float a, float b) {
  fp16x2 r = __builtin_amdgcn_cvt_pkrtz(a, b);
  return *(unsigned*)&r;
}
// async global->LDS, 16B per lane; lds dest = uniform base + lane*16 (HW rule)
__device__ inline void gload16(const ushort* g, ushort* l) {
  __builtin_amdgcn_global_load_lds(
      (const __attribute__((address_space(1))) void*)g,
      (__attribute__((address_space(3))) void*)l, 16, 0, 0);
}

// ---- LayerNorm (8 rows/block, vectorized) + folded weight cast/transpose --
__global__ __launch_bounds__(256) void lncast_kernel(
    const float* __restrict__ x, const float* __restrict__ g,
    const float* __restrict__ bta, ushort* __restrict__ nxh,
    const float* __restrict__ w_qkv, const float* __restrict__ w_out,
    ushort* __restrict__ wt, ushort* __restrict__ wot) {
  const int tid = threadIdx.x;
  const int lane = tid & 63;
  const int row = blockIdx.x * 8 + (tid >> 6) * 2 + (lane >> 5);
  const int e0 = (lane & 31) * 8;
  const float4 a = *(const float4*)&x[(size_t)row * D + e0];
  const float4 bv = *(const float4*)&x[(size_t)row * D + e0 + 4];
  float s = a.x + a.y + a.z + a.w + bv.x + bv.y + bv.z + bv.w;
  float ss = a.x * a.x + a.y * a.y + a.z * a.z + a.w * a.w +
             bv.x * bv.x + bv.y * bv.y + bv.z * bv.z + bv.w * bv.w;
#pragma unroll
  for (int off = 1; off < 32; off <<= 1) {
    s += __shfl_xor(s, off);
    ss += __shfl_xor(ss, off);
  }
  const float mu = s * (1.0f / D);
  const float rsig = rsqrtf(ss * (1.0f / D) - mu * mu + EPS);
  const float4 g0 = *(const float4*)&g[e0];
  const float4 g1 = *(const float4*)&g[e0 + 4];
  const float4 b0 = *(const float4*)&bta[e0];
  const float4 b1 = *(const float4*)&bta[e0 + 4];
  f16x8 r;
  r[0] = (_Float16)((a.x - mu) * rsig * g0.x + b0.x);
  r[1] = (_Float16)((a.y - mu) * rsig * g0.y + b0.y);
  r[2] = (_Float16)((a.z - mu) * rsig * g0.z + b0.z);
  r[3] = (_Float16)((a.w - mu) * rsig * g0.w + b0.w);
  r[4] = (_Float16)((bv.x - mu) * rsig * g1.x + b1.x);
  r[5] = (_Float16)((bv.y - mu) * rsig * g1.y + b1.y);
  r[6] = (_Float16)((bv.z - mu) * rsig * g1.z + b1.z);
  r[7] = (_Float16)((bv.w - mu) * rsig * g1.w + b1.w);
  *(f16x8*)&nxh[(size_t)row * D + e0] = r;

  if (blockIdx.x < 1024) {
    const int id = blockIdx.x * 256 + tid;
    if (id < 768 * 256) {
      const int n = id >> 8, k = id & 255;
      wt[id] = f2h(w_qkv[(size_t)k * 768 + n]);
    } else {
      const int j = id - 768 * 256;
      const int n = j >> 8, k = j & 255;
      wot[j] = f2h(w_out[(size_t)k * 256 + n]);
    }
  }
}

// ---------------- QKV GEMM via MFMA (no LDS for A/W; weights L2-hot) -------
// Region-2 (V) output goes through an LDS transpose tile so the global write
// is coalesced 64B/thread. ROUND-21 FIX: the read phase's global base must be
// the BLOCK base (blockIdx.x*128), not m0 (which includes w*32 — round-20's
// bug displaced waves 1-3 by +32/64/96 tokens, absmax 6.28).
__global__ __launch_bounds__(256, 4) void qkv_kernel(
    const ushort* __restrict__ nxh, const ushort* __restrict__ wt,
    const float* __restrict__ coord, ushort* __restrict__ qfp,
    ushort* __restrict__ kfp, ushort* __restrict__ vtp) {
  __shared__ ushort vs[64 * 132];  // [col 0..63][n 0..127], stride 132
  const int t = threadIdx.x;
  const int w = t >> 6, lane = t & 63;
  const int lrow = lane & 15, lhi = lane >> 4;
  const int m0 = blockIdx.x * 128 + w * 32;
  const int c0 = blockIdx.y * 64;  // within [0,768)
  f32x4 acc[2][4];
#pragma unroll
  for (int qs = 0; qs < 2; ++qs)
#pragma unroll
    for (int nt = 0; nt < 4; ++nt) acc[qs][nt] = f32x4{0.f, 0.f, 0.f, 0.f};

#pragma unroll
  for (int kc = 0; kc < D; kc += 32) {
    f16x8 ah[2], bw[4];
#pragma unroll
    for (int qs = 0; qs < 2; ++qs)
      ah[qs] = *(const f16x8*)(nxh + (size_t)(m0 + qs * 16 + lrow) * D + kc +
                               lhi * 8);
#pragma unroll
    for (int nt = 0; nt < 4; ++nt)
      bw[nt] = *(const f16x8*)(wt + (size_t)(c0 + nt * 16 + lrow) * D + kc +
                               lhi * 8);
#pragma unroll
    for (int qs = 0; qs < 2; ++qs)
#pragma unroll
      for (int nt = 0; nt < 4; ++nt)
        acc[qs][nt] = mfma_f16(ah[qs], bw[nt], acc[qs][nt]);
  }

  const int region = blockIdx.y >> 2;  // 0:q 1:k 2:v
  const int cbase = c0 & 255;
  if (region < 2) {
    const float sc = (region == 0) ? QSC2 : 1.0f;
    ushort* dp = (region == 0) ? qfp : kfp;
#pragma unroll
    for (int qs = 0; qs < 2; ++qs)
#pragma unroll
      for (int nt = 0; nt < 4; ++nt)
#pragma unroll
        for (int i = 0; i < 4; ++i) {
          const int row = m0 + qs * 16 + lhi * 4 + i;
          const int col = cbase + nt * 16 + lrow;
          const float val =
              (acc[qs][nt][i] + coord[(size_t)row * D + col]) * sc;
          dp[(size_t)row * D + col] = f2h(val);
        }
  } else {
    // stage into LDS: vs[col][n], col = nt*16+lrow, n = w*32+qs*16+lhi*4+i
#pragma unroll
    for (int qs = 0; qs < 2; ++qs)
#pragma unroll
      for (int nt = 0; nt < 4; ++nt) {
        ushort4 pk;
        pk.x = f2h(acc[qs][nt][0]);
        pk.y = f2h(acc[qs][nt][1]);
        pk.z = f2h(acc[qs][nt][2]);
        pk.w = f2h(acc[qs][nt][3]);
        *(ushort4*)&vs[(nt * 16 + lrow) * 132 + w * 32 + qs * 16 + lhi * 4] =
            pk;
      }
    __syncthreads();
    // coalesced write: thread -> 32 consecutive n of one col (64B).
    // Base is BLOCK-uniform (no w term).
    const int c = t >> 2, seg = (t & 3) * 32;
    const int nb0 = blockIdx.x * 128;
    const int bb = nb0 >> 12, nb = nb0 & (N - 1);
    ushort* dst = vtp + ((size_t)bb * D + cbase + c) * N + nb + seg;
    const ushort* src = &vs[c * 132 + seg];
#pragma unroll
    for (int k2 = 0; k2 < 8; ++k2)
      *(uint2*)(dst + k2 * 4) = *(const uint2*)(src + k2 * 4);
  }
}

// ---------------- MFMA flash attention (32x32 swapped-operand) -------------
// 8 warps x 32 q-rows (block = 256 rows), KVB=32 keys/tile, SPLIT=4.
// QUAD-buffered K/V staging (128KB LDS), ONE s_barrier per tile, rolled loop,
// T15 deferred-PV pipeline (round-17: 114us, MfmaUtil 25%, VALU 28%).
__global__ __launch_bounds__(512, 2) void attn_kernel(
    const ushort* __restrict__ qf, const ushort* __restrict__ kf,
    const ushort* __restrict__ vt, ushort* __restrict__ pob,
    float* __restrict__ mlb) {
  __shared__ ushort kbuf[4][8192];  // [key 0..31][32 granules]    16KB each
  __shared__ ushort vbuf[4][8192];  // [d-pair 0..127][8 granules] 16KB each

  const int tid = threadIdx.x;
  const int lane = tid & 63;
  const int q = lane & 31, h = lane >> 5;
  const int w = tid >> 6;
  const int b = blockIdx.y, s = blockIdx.z;
  const int qw = blockIdx.x * 256 + w * 32;
  const int kbeg = s * (N / SPLIT);

  const ushort* qrow = qf + ((size_t)b * N + qw + q) * D;
  const ushort* kfb = kf + (size_t)b * N * D;
  const ushort* vtb = vt + (size_t)b * D * N;
  ushort* pog = pob + (size_t)s * BN * D;
  float* mlg = mlb + (size_t)s * BN * 2;

  // persistent Q chunks 0..7 (d 0..127); chunks 8..15 streamed per tile
  f16x8 qfr[8];
#pragma unroll
  for (int c = 0; c < 8; ++c)
    qfr[c] = *(const f16x8*)(qrow + c * 16 + h * 8);

  f32x16 o[8];
#pragma unroll
  for (int dt = 0; dt < 8; ++dt)
#pragma unroll
    for (int r = 0; r < 16; ++r) o[dt][r] = 0.f;
  float m = -1e30f, lsum = 0.f;
  float f_prev = 1.0f;
  bool need_prev = false;
  f16x8 pf_prev[2];

  // stage one 32-key K+V tile; 4 granule-loads per thread (2 K + 2 V).
  // K: granule G -> key=G>>5, slot=G&31; src d-gran = slot^(key&7)
  // V: granule G -> r=G>>3, slot=G&7; u=slot^(r&7); d=2r+(u>>2); sg=u&3
  auto stage = [&](int bi, int k0) {
#pragma unroll
    for (int i = 0; i < 2; ++i) {
      const int g = i * 512 + tid;
      const int key = g >> 5, slot = g & 31;
      gload16(kfb + (size_t)(k0 + key) * D + ((slot ^ (key & 7)) * 8),
              &kbuf[bi][g * 8]);
    }
#pragma unroll
    for (int i = 0; i < 2; ++i) {
      const int g = i * 512 + tid;
      const int r = g >> 3, slot = g & 7;
      const int u = slot ^ (r & 7);
      const int d = r * 2 + (u >> 2);
      gload16(vtb + (size_t)d * N + k0 + ((u & 3) * 8), &vbuf[bi][g * 8]);
    }
  };

  stage(0, kbeg);

  for (int t = 0; t < NTK; ++t) {
    const int cur = t & 3;
    const int prv = (t + 3) & 3;
    // stream Q chunks 8..15 (issued BEFORE next-tile stage so vmcnt(12)
    // drains exactly the current tile's 4 stage loads)
    f16x8 qs[8];
#pragma unroll
    for (int c = 0; c < 8; ++c)
      qs[c] = *(const f16x8*)(qrow + (8 + c) * 16 + h * 8);
    if (t + 1 < NTK) {
      stage((t + 1) & 3, kbeg + (t + 1) * KVB);
      asm volatile("s_waitcnt vmcnt(12)" ::: "memory");  // drain stage(t)
    } else {
      asm volatile("s_waitcnt vmcnt(8)" ::: "memory");   // qs still in flight
    }
    __builtin_amdgcn_sched_barrier(0);
    __builtin_amdgcn_s_barrier();   // the ONLY barrier per tile
    __builtin_amdgcn_sched_barrier(0);

    // ---- QK(t): S^T = K Q, single 16-MFMA chain into p ----
    f32x16 p;
#pragma unroll
    for (int r = 0; r < 16; ++r) p[r] = 0.f;
    const int ksw = (q & 7);
    __builtin_amdgcn_s_setprio(1);
#pragma unroll
    for (int c = 0; c < 16; ++c) {
      const f16x8 qv = (c < 8) ? qfr[c] : qs[c - 8];
      const f16x8 ka = *(const f16x8*)&kbuf[cur][q * 256 +
                                                 (((c * 2 + h) ^ ksw) * 8)];
      p = mfma32(ka, qv, p);
    }
    __builtin_amdgcn_s_setprio(0);

    // ---- deferred: rescale o by f(t-1), then PV(t-1) ----
    if (t > 0) {
      if (need_prev) {
#pragma unroll
        for (int dt = 0; dt < 8; ++dt) o[dt] *= f_prev;
      }
      __builtin_amdgcn_s_setprio(1);
#pragma unroll
      for (int dt = 0; dt < 8; ++dt) {
        const int d = dt * 32 + q;
        const int rr = d >> 1;
#pragma unroll
        for (int kk = 0; kk < 2; ++kk) {
          const int u = (d & 1) * 4 + kk * 2 + h;
          const f16x8 vf = *(const f16x8*)&vbuf[prv][rr * 64 +
                                                     ((u ^ (rr & 7)) * 8)];
          o[dt] = mfma32(vf, pf_prev[kk], o[dt]);
        }
      }
      __builtin_amdgcn_s_setprio(0);
    }

    // ---- softmax(t): runs while PV(t-1) drains the matrix pipe ----
    float tm[8];
#pragma unroll
    for (int j = 0; j < 8; ++j) tm[j] = fmaxf(p[2 * j], p[2 * j + 1]);
    float pmax = fmaxf(fmaxf(fmaxf(tm[0], tm[1]), fmaxf(tm[2], tm[3])),
                       fmaxf(fmaxf(tm[4], tm[5]), fmaxf(tm[6], tm[7])));
    const float pm = fmaxf(pmax, __shfl_xor(pmax, 32));
    const bool need = pm > m + THR;
    if (__any(need)) {
      const float mn = fmaxf(m, pm);
      f_prev = exp2f(m - mn);
      m = mn;
      lsum *= f_prev;
      need_prev = true;
    } else {
      need_prev = false;
    }
#pragma unroll
    for (int r = 0; r < 16; ++r) {
      p[r] = exp2f(p[r] - m);
      lsum += p[r];
    }

    // ---- pack P -> pf_prev (2 B-frags of 16 keys) via cvt_pkrtz + shfl ----
    // lane(q,h) owns packed words: x=keys(4h,4h+1) z=(4h+2,4h+3)
    // y=(8+4h,9+4h) wv=(10+4h,11+4h). B-frag word_j = keys(h*8+2j,+1):
    // word0 = h? partner-y : x ; word1 = h? partner-wv : z ;
    // word2 = h? y : partner-x ; word3 = h? wv : partner-z.
#pragma unroll
    for (int kk = 0; kk < 2; ++kk) {
      const int sub = kk * 8;
      unsigned x = pkh(p[sub + 0], p[sub + 1]);
      unsigned z = pkh(p[sub + 2], p[sub + 3]);
      unsigned y = pkh(p[sub + 4], p[sub + 5]);
      unsigned wv = pkh(p[sub + 6], p[sub + 7]);
      const unsigned xs = __shfl_xor(x, 32);
      const unsigned zs = __shfl_xor(z, 32);
      const unsigned ys = __shfl_xor(y, 32);
      const unsigned ws = __shfl_xor(wv, 32);
      union { f16x8 v; unsigned u[4]; } pu;
      pu.u[0] = h ? ys : x;
      pu.u[1] = h ? ws : z;
      pu.u[2] = h ? y : xs;
      pu.u[3] = h ? wv : zs;
      pf_prev[kk] = pu.v;
    }
  }

  // ---- epilogue: final rescale + PV(NTK-1), then normalize & write ----
  if (need_prev) {
#pragma unroll
    for (int dt = 0; dt < 8; ++dt) o[dt] *= f_prev;
  }
  {
    const int prv = (NTK - 1) & 3;
#pragma unroll
    for (int dt = 0; dt < 8; ++dt) {
      const int d = dt * 32 + q;
      const int rr = d >> 1;
#pragma unroll
      for (int kk = 0; kk < 2; ++kk) {
        const int u = (d & 1) * 4 + kk * 2 + h;
        const f16x8 vf = *(const f16x8*)&vbuf[prv][rr * 64 +
                                                   ((u ^ (rr & 7)) * 8)];
        o[dt] = mfma32(vf, pf_prev[kk], o[dt]);
      }
    }
  }
  const float lt = lsum + __shfl_xor(lsum, 32);
  const float inv = 1.0f / lt;
  ushort* orow = pog + ((size_t)b * N + qw + q) * D;
#pragma unroll
  for (int dt = 0; dt < 8; ++dt)
#pragma unroll
    for (int r4 = 0; r4 < 4; ++r4) {
      const unsigned u0 =
          pkh(o[dt][r4 * 4 + 0] * inv, o[dt][r4 * 4 + 1] * inv);
      const unsigned u1 =
          pkh(o[dt][r4 * 4 + 2] * inv, o[dt][r4 * 4 + 3] * inv);
      uint2 val;
      val.x = u0;
      val.y = u1;
      *(uint2*)(orow + dt * 32 + r4 * 8 + h * 4) = val;
    }
  if (h == 0) {
    const size_t r = (size_t)b * N + qw + q;
    mlg[r * 2] = m;
    mlg[r * 2 + 1] = lt;
  }
}

// -------- fused merge + output projection via MFMA --------------
__global__ __launch_bounds__(256, 4) void projm_kernel(
    const ushort* __restrict__ pob, const float* __restrict__ mlb,
    const ushort* __restrict__ wot, const float* __restrict__ bias,
    float* __restrict__ out) {
  const int t = threadIdx.x;
  const int w = t >> 6, lane = t & 63;
  const int lrow = lane & 15, lhi = lane >> 4;
  const int m0 = blockIdx.x * 128 + w * 32;
  const int c0 = blockIdx.y * 64;

  // per-thread merge weights for rows m0+lrow, m0+16+lrow
  float cw[2][SPLIT];
#pragma unroll
  for (int qs = 0; qs < 2; ++qs) {
    const int row = m0 + qs * 16 + lrow;
    float mv[SPLIT], lv[SPLIT], mm = -1e30f;
#pragma unroll
    for (int s = 0; s < SPLIT; ++s) {
      mv[s] = mlb[(size_t)s * BN * 2 + row * 2];
      lv[s] = mlb[(size_t)s * BN * 2 + row * 2 + 1];
      mm = fmaxf(mm, mv[s]);
    }
    float wsum = 0.f;
#pragma unroll
    for (int s = 0; s < SPLIT; ++s) {
      cw[qs][s] = exp2f(mv[s] - mm) * lv[s];
      wsum += cw[qs][s];
    }
    const float invw = 1.0f / wsum;
#pragma unroll
    for (int s = 0; s < SPLIT; ++s) cw[qs][s] *= invw;
  }

  f32x4 acc[2][4];
#pragma unroll
  for (int qs = 0; qs < 2; ++qs)
#pragma unroll
    for (int nt = 0; nt < 4; ++nt) acc[qs][nt] = f32x4{0.f, 0.f, 0.f, 0.f};

#pragma unroll
  for (int kc = 0; kc < D; kc += 32) {
    f16x8 ah[2], bw[4];
#pragma unroll
    for (int qs = 0; qs < 2; ++qs) {
      const size_t off = (size_t)(m0 + qs * 16 + lrow) * D + kc + lhi * 8;
      float v[8] = {};
#pragma unroll
      for (int s = 0; s < SPLIT; ++s) {
        const f16x8 ps = *(const f16x8*)(pob + (size_t)s * BN * D + off);
        const float c = cw[qs][s];
#pragma unroll
        for (int j = 0; j < 8; ++j) v[j] += c * (float)ps[j];
      }
      f16x8 a;
#pragma unroll
      for (int j = 0; j < 8; ++j) a[j] = (_Float16)v[j];
      ah[qs] = a;
    }
#pragma unroll
    for (int nt = 0; nt < 4; ++nt)
      bw[nt] = *(const f16x8*)(wot + (size_t)(c0 + nt * 16 + lrow) * D + kc +
                               lhi * 8);
#pragma unroll
    for (int qs = 0; qs < 2; ++qs)
#pragma unroll
      for (int nt = 0; nt < 4; ++nt)
        acc[qs][nt] = mfma_f16(ah[qs], bw[nt], acc[qs][nt]);
  }
#pragma unroll
  for (int qs = 0; qs < 2; ++qs)
#pragma unroll
    for (int nt = 0; nt < 4; ++nt)
#pragma unroll
      for (int i = 0; i < 4; ++i) {
        const int row = m0 + qs * 16 + lhi * 4 + i;
        const int col = c0 + nt * 16 + lrow;
        out[(size_t)row * D + col] = acc[qs][nt][i] + bias[col];
      }
}

extern "C" void kernel_launch(void* const* d_in, const int* in_sizes, int n_in,
                              void* d_out, int out_size, void* d_ws, size_t ws_size,
                              hipStream_t stream) {
  const float* x = (const float*)d_in[0];
  const float* coord = (const float*)d_in[1];
  const float* ln_g = (const float*)d_in[2];
  const float* ln_b = (const float*)d_in[3];
  const float* w_qkv = (const float*)d_in[4];
  const float* w_out = (const float*)d_in[5];
  const float* b_out = (const float*)d_in[6];
  float* out = (float*)d_out;

  const size_t P = (size_t)BN * D;

  ushort* qfp = (ushort*)d_ws;
  ushort* kfp = qfp + P;
  ushort* vtp = kfp + P;
  ushort* pob = vtp + P;                      // SPLIT partial-O planes
  float* mlb = (float*)(pob + (size_t)SPLIT * P);
  ushort* wt = (ushort*)(mlb + (size_t)SPLIT * BN * 2);
  ushort* wot = wt + 768 * 256;
  // alias (liveness-disjoint):
  ushort* nxh = pob;       // written by ln, consumed by qkv, dead before attn

  hipLaunchKernelGGL(lncast_kernel, dim3(BN / 8), dim3(256), 0, stream,
                     x, ln_g, ln_b, nxh, w_qkv, w_out, wt, wot);
  hipLaunchKernelGGL(qkv_kernel, dim3(BN / 128, 12), dim3(256), 0, stream,
                     nxh, wt, coord, qfp, kfp, vtp);
  hipLaunchKernelGGL(attn_kernel, dim3(N / 256, B, SPLIT), dim3(512), 0,
                     stream, qfp, kfp, vtp, pob, mlb);
  hipLaunchKernelGGL(projm_kernel, dim3(BN / 128, 4), dim3(256), 0, stream,
                     pob, mlb, wot, b_out, out);
}

// Round 22
// 173.908 us; speedup vs baseline: 1.6344x; 1.0023x over previous
//
#include <hip/hip_runtime.h>
#include <hip/hip_fp16.h>
#include <math.h>

constexpr int B = 4, N = 4096, D = 256;
constexpr int BN = B * N;
constexpr float EPS = 1e-5f;
// softmax scale (D^-0.5 = 1/16) * log2(e), folded into q at f16-cast time
constexpr float QSC2 = 0.0625f * 1.44269504088896340736f;

constexpr int SPLIT = 4;     // KV splits -> grid 256 blocks (1/CU)
constexpr int KVB = 32;      // keys per attn tile
constexpr int NTK = (N / SPLIT) / KVB;  // 32 tiles
constexpr float THR = 8.0f;  // defer-max threshold (base-2)

typedef __attribute__((ext_vector_type(8))) _Float16 f16x8;
typedef __attribute__((ext_vector_type(2))) __fp16 fp16x2;
typedef __attribute__((ext_vector_type(4))) float f32x4;
typedef __attribute__((ext_vector_type(16))) float f32x16;

__device__ inline f32x4 mfma_f16(f16x8 a, f16x8 b, f32x4 c) {
  return __builtin_amdgcn_mfma_f32_16x16x32_f16(a, b, c, 0, 0, 0);
}
__device__ inline f32x16 mfma32(f16x8 a, f16x8 b, f32x16 c) {
  return __builtin_amdgcn_mfma_f32_32x32x16_f16(a, b, c, 0, 0, 0);
}
__device__ inline ushort f2h(float x) {
  __half h = __float2half(x);
  return *(ushort*)&h;
}
__device__ inline float h2f(ushort u) {
  __half h;
  *(ushort*)&h = u;
  return __half2float(h);
}
__device__ inline unsigned pkh(float a, float b) {
  fp16x2 r = __builtin_amdgcn_cvt_pkrtz(a, b);
  return *(unsigned*)&r;
}
// async global->LDS, 16B per lane; lds dest = uniform base + lane*16 (HW rule)
__device__ inline void gload16(const ushort* g, ushort* l) {
  __builtin_amdgcn_global_load_lds(
      (const __attribute__((address_space(1))) void*)g,
      (__attribute__((address_space(3))) void*)l, 16, 0, 0);
}

// ---- LayerNorm (8 rows/block, vectorized) + folded weight cast/transpose --
__global__ __launch_bounds__(256) void lncast_kernel(
    const float* __restrict__ x, const float* __restrict__ g,
    const float* __restrict__ bta, ushort* __restrict__ nxh,
    const float* __restrict__ w_qkv, const float* __restrict__ w_out,
    ushort* __restrict__ wt, ushort* __restrict__ wot) {
  const int tid = threadIdx.x;
  const int lane = tid & 63;
  const int row = blockIdx.x * 8 + (tid >> 6) * 2 + (lane >> 5);
  const int e0 = (lane & 31) * 8;
  const float4 a = *(const float4*)&x[(size_t)row * D + e0];
  const float4 bv = *(const float4*)&x[(size_t)row * D + e0 + 4];
  float s = a.x + a.y + a.z + a.w + bv.x + bv.y + bv.z + bv.w;
  float ss = a.x * a.x + a.y * a.y + a.z * a.z + a.w * a.w +
             bv.x * bv.x + bv.y * bv.y + bv.z * bv.z + bv.w * bv.w;
#pragma unroll
  for (int off = 1; off < 32; off <<= 1) {
    s += __shfl_xor(s, off);
    ss += __shfl_xor(ss, off);
  }
  const float mu = s * (1.0f / D);
  const float rsig = rsqrtf(ss * (1.0f / D) - mu * mu + EPS);
  const float4 g0 = *(const float4*)&g[e0];
  const float4 g1 = *(const float4*)&g[e0 + 4];
  const float4 b0 = *(const float4*)&bta[e0];
  const float4 b1 = *(const float4*)&bta[e0 + 4];
  f16x8 r;
  r[0] = (_Float16)((a.x - mu) * rsig * g0.x + b0.x);
  r[1] = (_Float16)((a.y - mu) * rsig * g0.y + b0.y);
  r[2] = (_Float16)((a.z - mu) * rsig * g0.z + b0.z);
  r[3] = (_Float16)((a.w - mu) * rsig * g0.w + b0.w);
  r[4] = (_Float16)((bv.x - mu) * rsig * g1.x + b1.x);
  r[5] = (_Float16)((bv.y - mu) * rsig * g1.y + b1.y);
  r[6] = (_Float16)((bv.z - mu) * rsig * g1.z + b1.z);
  r[7] = (_Float16)((bv.w - mu) * rsig * g1.w + b1.w);
  *(f16x8*)&nxh[(size_t)row * D + e0] = r;

  if (blockIdx.x < 1024) {
    const int id = blockIdx.x * 256 + tid;
    if (id < 768 * 256) {
      const int n = id >> 8, k = id & 255;
      wt[id] = f2h(w_qkv[(size_t)k * 768 + n]);
    } else {
      const int j = id - 768 * 256;
      const int n = j >> 8, k = j & 255;
      wot[j] = f2h(w_out[(size_t)k * 256 + n]);
    }
  }
}

// ---------------- QKV GEMM via MFMA (no LDS for A/W; weights L2-hot) -------
__global__ __launch_bounds__(256, 4) void qkv_kernel(
    const ushort* __restrict__ nxh, const ushort* __restrict__ wt,
    const float* __restrict__ coord, ushort* __restrict__ qfp,
    ushort* __restrict__ kfp, ushort* __restrict__ vtp) {
  __shared__ ushort vs[64 * 132];  // [col 0..63][n 0..127], stride 132
  const int t = threadIdx.x;
  const int w = t >> 6, lane = t & 63;
  const int lrow = lane & 15, lhi = lane >> 4;
  const int m0 = blockIdx.x * 128 + w * 32;
  const int c0 = blockIdx.y * 64;  // within [0,768)
  f32x4 acc[2][4];
#pragma unroll
  for (int qs = 0; qs < 2; ++qs)
#pragma unroll
    for (int nt = 0; nt < 4; ++nt) acc[qs][nt] = f32x4{0.f, 0.f, 0.f, 0.f};

#pragma unroll
  for (int kc = 0; kc < D; kc += 32) {
    f16x8 ah[2], bw[4];
#pragma unroll
    for (int qs = 0; qs < 2; ++qs)
      ah[qs] = *(const f16x8*)(nxh + (size_t)(m0 + qs * 16 + lrow) * D + kc +
                               lhi * 8);
#pragma unroll
    for (int nt = 0; nt < 4; ++nt)
      bw[nt] = *(const f16x8*)(wt + (size_t)(c0 + nt * 16 + lrow) * D + kc +
                               lhi * 8);
#pragma unroll
    for (int qs = 0; qs < 2; ++qs)
#pragma unroll
      for (int nt = 0; nt < 4; ++nt)
        acc[qs][nt] = mfma_f16(ah[qs], bw[nt], acc[qs][nt]);
  }

  const int region = blockIdx.y >> 2;  // 0:q 1:k 2:v
  const int cbase = c0 & 255;
  if (region < 2) {
    const float sc = (region == 0) ? QSC2 : 1.0f;
    ushort* dp = (region == 0) ? qfp : kfp;
#pragma unroll
    for (int qs = 0; qs < 2; ++qs)
#pragma unroll
      for (int nt = 0; nt < 4; ++nt)
#pragma unroll
        for (int i = 0; i < 4; ++i) {
          const int row = m0 + qs * 16 + lhi * 4 + i;
          const int col = cbase + nt * 16 + lrow;
          const float val =
              (acc[qs][nt][i] + coord[(size_t)row * D + col]) * sc;
          dp[(size_t)row * D + col] = f2h(val);
        }
  } else {
    // stage into LDS: vs[col][n], col = nt*16+lrow, n = w*32+qs*16+lhi*4+i
#pragma unroll
    for (int qs = 0; qs < 2; ++qs)
#pragma unroll
      for (int nt = 0; nt < 4; ++nt) {
        ushort4 pk;
        pk.x = f2h(acc[qs][nt][0]);
        pk.y = f2h(acc[qs][nt][1]);
        pk.z = f2h(acc[qs][nt][2]);
        pk.w = f2h(acc[qs][nt][3]);
        *(ushort4*)&vs[(nt * 16 + lrow) * 132 + w * 32 + qs * 16 + lhi * 4] =
            pk;
      }
    __syncthreads();
    // coalesced write: thread -> 32 consecutive n of one col (64B).
    // Base is BLOCK-uniform (no w term).
    const int c = t >> 2, seg = (t & 3) * 32;
    const int nb0 = blockIdx.x * 128;
    const int bb = nb0 >> 12, nb = nb0 & (N - 1);
    ushort* dst = vtp + ((size_t)bb * D + cbase + c) * N + nb + seg;
    const ushort* src = &vs[c * 132 + seg];
#pragma unroll
    for (int k2 = 0; k2 < 8; ++k2)
      *(uint2*)(dst + k2 * 4) = *(const uint2*)(src + k2 * 4);
  }
}

// ---------------- MFMA flash attention (32x32 swapped-operand) -------------
// 8 warps x 32 q-rows (block = 256 rows), KVB=32 keys/tile, SPLIT=4.
// QUAD-buffered K/V staging (128KB LDS), ONE s_barrier per tile, rolled loop,
// T15 deferred-PV pipeline. Round-22: P-pack uses pre-select + 2 shfls per
// kk (each lane only USES half its shfl results, so select the value the
// partner needs BEFORE the exchange) — 4 ds_bpermute/tile instead of 8.
__global__ __launch_bounds__(512, 2) void attn_kernel(
    const ushort* __restrict__ qf, const ushort* __restrict__ kf,
    const ushort* __restrict__ vt, ushort* __restrict__ pob,
    float* __restrict__ mlb) {
  __shared__ ushort kbuf[4][8192];  // [key 0..31][32 granules]    16KB each
  __shared__ ushort vbuf[4][8192];  // [d-pair 0..127][8 granules] 16KB each

  const int tid = threadIdx.x;
  const int lane = tid & 63;
  const int q = lane & 31, h = lane >> 5;
  const int w = tid >> 6;
  const int b = blockIdx.y, s = blockIdx.z;
  const int qw = blockIdx.x * 256 + w * 32;
  const int kbeg = s * (N / SPLIT);

  const ushort* qrow = qf + ((size_t)b * N + qw + q) * D;
  const ushort* kfb = kf + (size_t)b * N * D;
  const ushort* vtb = vt + (size_t)b * D * N;
  ushort* pog = pob + (size_t)s * BN * D;
  float* mlg = mlb + (size_t)s * BN * 2;

  // persistent Q chunks 0..7 (d 0..127); chunks 8..15 streamed per tile
  f16x8 qfr[8];
#pragma unroll
  for (int c = 0; c < 8; ++c)
    qfr[c] = *(const f16x8*)(qrow + c * 16 + h * 8);

  f32x16 o[8];
#pragma unroll
  for (int dt = 0; dt < 8; ++dt)
#pragma unroll
    for (int r = 0; r < 16; ++r) o[dt][r] = 0.f;
  float m = -1e30f, lsum = 0.f;
  float f_prev = 1.0f;
  bool need_prev = false;
  f16x8 pf_prev[2];

  // stage one 32-key K+V tile; 4 granule-loads per thread (2 K + 2 V).
  // K: granule G -> key=G>>5, slot=G&31; src d-gran = slot^(key&7)
  // V: granule G -> r=G>>3, slot=G&7; u=slot^(r&7); d=2r+(u>>2); sg=u&3
  auto stage = [&](int bi, int k0) {
#pragma unroll
    for (int i = 0; i < 2; ++i) {
      const int g = i * 512 + tid;
      const int key = g >> 5, slot = g & 31;
      gload16(kfb + (size_t)(k0 + key) * D + ((slot ^ (key & 7)) * 8),
              &kbuf[bi][g * 8]);
    }
#pragma unroll
    for (int i = 0; i < 2; ++i) {
      const int g = i * 512 + tid;
      const int r = g >> 3, slot = g & 7;
      const int u = slot ^ (r & 7);
      const int d = r * 2 + (u >> 2);
      gload16(vtb + (size_t)d * N + k0 + ((u & 3) * 8), &vbuf[bi][g * 8]);
    }
  };

  stage(0, kbeg);

  for (int t = 0; t < NTK; ++t) {
    const int cur = t & 3;
    const int prv = (t + 3) & 3;
    // stream Q chunks 8..15 (issued BEFORE next-tile stage so vmcnt(12)
    // drains exactly the current tile's 4 stage loads)
    f16x8 qs[8];
#pragma unroll
    for (int c = 0; c < 8; ++c)
      qs[c] = *(const f16x8*)(qrow + (8 + c) * 16 + h * 8);
    if (t + 1 < NTK) {
      stage((t + 1) & 3, kbeg + (t + 1) * KVB);
      asm volatile("s_waitcnt vmcnt(12)" ::: "memory");  // drain stage(t)
    } else {
      asm volatile("s_waitcnt vmcnt(8)" ::: "memory");   // qs still in flight
    }
    __builtin_amdgcn_sched_barrier(0);
    __builtin_amdgcn_s_barrier();   // the ONLY barrier per tile
    __builtin_amdgcn_sched_barrier(0);

    // ---- QK(t): S^T = K Q, single 16-MFMA chain into p ----
    f32x16 p;
#pragma unroll
    for (int r = 0; r < 16; ++r) p[r] = 0.f;
    const int ksw = (q & 7);
    __builtin_amdgcn_s_setprio(1);
#pragma unroll
    for (int c = 0; c < 16; ++c) {
      const f16x8 qv = (c < 8) ? qfr[c] : qs[c - 8];
      const f16x8 ka = *(const f16x8*)&kbuf[cur][q * 256 +
                                                 (((c * 2 + h) ^ ksw) * 8)];
      p = mfma32(ka, qv, p);
    }
    __builtin_amdgcn_s_setprio(0);

    // ---- deferred: rescale o by f(t-1), then PV(t-1) ----
    if (t > 0) {
      if (need_prev) {
#pragma unroll
        for (int dt = 0; dt < 8; ++dt) o[dt] *= f_prev;
      }
      __builtin_amdgcn_s_setprio(1);
#pragma unroll
      for (int dt = 0; dt < 8; ++dt) {
        const int d = dt * 32 + q;
        const int rr = d >> 1;
#pragma unroll
        for (int kk = 0; kk < 2; ++kk) {
          const int u = (d & 1) * 4 + kk * 2 + h;
          const f16x8 vf = *(const f16x8*)&vbuf[prv][rr * 64 +
                                                     ((u ^ (rr & 7)) * 8)];
          o[dt] = mfma32(vf, pf_prev[kk], o[dt]);
        }
      }
      __builtin_amdgcn_s_setprio(0);
    }

    // ---- softmax(t): runs while PV(t-1) drains the matrix pipe ----
    float tm[8];
#pragma unroll
    for (int j = 0; j < 8; ++j) tm[j] = fmaxf(p[2 * j], p[2 * j + 1]);
    float pmax = fmaxf(fmaxf(fmaxf(tm[0], tm[1]), fmaxf(tm[2], tm[3])),
                       fmaxf(fmaxf(tm[4], tm[5]), fmaxf(tm[6], tm[7])));
    const float pm = fmaxf(pmax, __shfl_xor(pmax, 32));
    const bool need = pm > m + THR;
    if (__any(need)) {
      const float mn = fmaxf(m, pm);
      f_prev = exp2f(m - mn);
      m = mn;
      lsum *= f_prev;
      need_prev = true;
    } else {
      need_prev = false;
    }
#pragma unroll
    for (int r = 0; r < 16; ++r) {
      p[r] = exp2f(p[r] - m);
      lsum += p[r];
    }

    // ---- pack P -> pf_prev: cvt_pkrtz + PRE-SELECTED exchange (2 shfls/kk)
    // lane(q,h) owns packed words: x=keys(4h,4h+1) z=(4h+2,4h+3)
    // y=(8+4h,9+4h) wv=(10+4h,11+4h). B-frag word_j = keys(h*8+2j,+1):
    // h0 needs {x, z, partner-x, partner-z}; h1 needs {partner-y,
    // partner-wv, y, wv}. Each lane only uses the PARTNER's {x,z} (h0) or
    // {y,wv} (h1), so select before the exchange: e1 = h?x:y, e2 = h?z:wv.
#pragma unroll
    for (int kk = 0; kk < 2; ++kk) {
      const int sub = kk * 8;
      const unsigned x = pkh(p[sub + 0], p[sub + 1]);
      const unsigned z = pkh(p[sub + 2], p[sub + 3]);
      const unsigned y = pkh(p[sub + 4], p[sub + 5]);
      const unsigned wv = pkh(p[sub + 6], p[sub + 7]);
      const unsigned e1 = h ? x : y;   // value the partner needs (slot A)
      const unsigned e2 = h ? z : wv;  // value the partner needs (slot B)
      const unsigned r1 = __shfl_xor(e1, 32);  // h0: partner-x ; h1: partner-y
      const unsigned r2 = __shfl_xor(e2, 32);  // h0: partner-z ; h1: partner-wv
      union { f16x8 v; unsigned u[4]; } pu;
      pu.u[0] = h ? r1 : x;
      pu.u[1] = h ? r2 : z;
      pu.u[2] = h ? y : r1;
      pu.u[3] = h ? wv : r2;
      pf_prev[kk] = pu.v;
    }
  }

  // ---- epilogue: final rescale + PV(NTK-1), then normalize & write ----
  if (need_prev) {
#pragma unroll
    for (int dt = 0; dt < 8; ++dt) o[dt] *= f_prev;
  }
  {
    const int prv = (NTK - 1) & 3;
#pragma unroll
    for (int dt = 0; dt < 8; ++dt) {
      const int d = dt * 32 + q;
      const int rr = d >> 1;
#pragma unroll
      for (int kk = 0; kk < 2; ++kk) {
        const int u = (d & 1) * 4 + kk * 2 + h;
        const f16x8 vf = *(const f16x8*)&vbuf[prv][rr * 64 +
                                                   ((u ^ (rr & 7)) * 8)];
        o[dt] = mfma32(vf, pf_prev[kk], o[dt]);
      }
    }
  }
  const float lt = lsum + __shfl_xor(lsum, 32);
  const float inv = 1.0f / lt;
  ushort* orow = pog + ((size_t)b * N + qw + q) * D;
#pragma unroll
  for (int dt = 0; dt < 8; ++dt)
#pragma unroll
    for (int r4 = 0; r4 < 4; ++r4) {
      const unsigned u0 =
          pkh(o[dt][r4 * 4 + 0] * inv, o[dt][r4 * 4 + 1] * inv);
      const unsigned u1 =
          pkh(o[dt][r4 * 4 + 2] * inv, o[dt][r4 * 4 + 3] * inv);
      uint2 val;
      val.x = u0;
      val.y = u1;
      *(uint2*)(orow + dt * 32 + r4 * 8 + h * 4) = val;
    }
  if (h == 0) {
    const size_t r = (size_t)b * N + qw + q;
    mlg[r * 2] = m;
    mlg[r * 2 + 1] = lt;
  }
}

// -------- fused merge + output projection via MFMA --------------
__global__ __launch_bounds__(256, 4) void projm_kernel(
    const ushort* __restrict__ pob, const float* __restrict__ mlb,
    const ushort* __restrict__ wot, const float* __restrict__ bias,
    float* __restrict__ out) {
  const int t = threadIdx.x;
  const int w = t >> 6, lane = t & 63;
  const int lrow = lane & 15, lhi = lane >> 4;
  const int m0 = blockIdx.x * 128 + w * 32;
  const int c0 = blockIdx.y * 64;

  // per-thread merge weights for rows m0+lrow, m0+16+lrow
  float cw[2][SPLIT];
#pragma unroll
  for (int qs = 0; qs < 2; ++qs) {
    const int row = m0 + qs * 16 + lrow;
    float mv[SPLIT], lv[SPLIT], mm = -1e30f;
#pragma unroll
    for (int s = 0; s < SPLIT; ++s) {
      mv[s] = mlb[(size_t)s * BN * 2 + row * 2];
      lv[s] = mlb[(size_t)s * BN * 2 + row * 2 + 1];
      mm = fmaxf(mm, mv[s]);
    }
    float wsum = 0.f;
#pragma unroll
    for (int s = 0; s < SPLIT; ++s) {
      cw[qs][s] = exp2f(mv[s] - mm) * lv[s];
      wsum += cw[qs][s];
    }
    const float invw = 1.0f / wsum;
#pragma unroll
    for (int s = 0; s < SPLIT; ++s) cw[qs][s] *= invw;
  }

  f32x4 acc[2][4];
#pragma unroll
  for (int qs = 0; qs < 2; ++qs)
#pragma unroll
    for (int nt = 0; nt < 4; ++nt) acc[qs][nt] = f32x4{0.f, 0.f, 0.f, 0.f};

#pragma unroll
  for (int kc = 0; kc < D; kc += 32) {
    f16x8 ah[2], bw[4];
#pragma unroll
    for (int qs = 0; qs < 2; ++qs) {
      const size_t off = (size_t)(m0 + qs * 16 + lrow) * D + kc + lhi * 8;
      float v[8] = {};
#pragma unroll
      for (int s = 0; s < SPLIT; ++s) {
        const f16x8 ps = *(const f16x8*)(pob + (size_t)s * BN * D + off);
        const float c = cw[qs][s];
#pragma unroll
        for (int j = 0; j < 8; ++j) v[j] += c * (float)ps[j];
      }
      f16x8 a;
#pragma unroll
      for (int j = 0; j < 8; ++j) a[j] = (_Float16)v[j];
      ah[qs] = a;
    }
#pragma unroll
    for (int nt = 0; nt < 4; ++nt)
      bw[nt] = *(const f16x8*)(wot + (size_t)(c0 + nt * 16 + lrow) * D + kc +
                               lhi * 8);
#pragma unroll
    for (int qs = 0; qs < 2; ++qs)
#pragma unroll
      for (int nt = 0; nt < 4; ++nt)
        acc[qs][nt] = mfma_f16(ah[qs], bw[nt], acc[qs][nt]);
  }
#pragma unroll
  for (int qs = 0; qs < 2; ++qs)
#pragma unroll
    for (int nt = 0; nt < 4; ++nt)
#pragma unroll
      for (int i = 0; i < 4; ++i) {
        const int row = m0 + qs * 16 + lhi * 4 + i;
        const int col = c0 + nt * 16 + lrow;
        out[(size_t)row * D + col] = acc[qs][nt][i] + bias[col];
      }
}

extern "C" void kernel_launch(void* const* d_in, const int* in_sizes, int n_in,
                              void* d_out, int out_size, void* d_ws, size_t ws_size,
                              hipStream_t stream) {
  const float* x = (const float*)d_in[0];
  const float* coord = (const float*)d_in[1];
  const float* ln_g = (const float*)d_in[2];
  const float* ln_b = (const float*)d_in[3];
  const float* w_qkv = (const float*)d_in[4];
  const float* w_out = (const float*)d_in[5];
  const float* b_out = (const float*)d_in[6];
  float* out = (float*)d_out;

  const size_t P = (size_t)BN * D;

  ushort* qfp = (ushort*)d_ws;
  ushort* kfp = qfp + P;
  ushort* vtp = kfp + P;
  ushort* pob = vtp + P;                      // SPLIT partial-O planes
  float* mlb = (float*)(pob + (size_t)SPLIT * P);
  ushort* wt = (ushort*)(mlb + (size_t)SPLIT * BN * 2);
  ushort* wot = wt + 768 * 256;
  // alias (liveness-disjoint):
  ushort* nxh = pob;       // written by ln, consumed by qkv, dead before attn

  hipLaunchKernelGGL(lncast_kernel, dim3(BN / 8), dim3(256), 0, stream,
                     x, ln_g, ln_b, nxh, w_qkv, w_out, wt, wot);
  hipLaunchKernelGGL(qkv_kernel, dim3(BN / 128, 12), dim3(256), 0, stream,
                     nxh, wt, coord, qfp, kfp, vtp);
  hipLaunchKernelGGL(attn_kernel, dim3(N / 256, B, SPLIT), dim3(512), 0,
                     stream, qfp, kfp, vtp, pob, mlb);
  hipLaunchKernelGGL(projm_kernel, dim3(BN / 128, 4), dim3(256), 0, stream,
                     pob, mlb, wot, b_out, out);
}

// Round 23
// 173.384 us; speedup vs baseline: 1.6393x; 1.0030x over previous
//
#include <hip/hip_runtime.h>
#include <hip/hip_fp16.h>
#include <math.h>

constexpr int B = 4, N = 4096, D = 256;
constexpr int BN = B * N;
constexpr float EPS = 1e-5f;
// softmax scale (D^-0.5 = 1/16) * log2(e), folded into q at f16-cast time
constexpr float QSC2 = 0.0625f * 1.44269504088896340736f;

constexpr int SPLIT = 4;     // KV splits -> grid 256 blocks (1/CU)
constexpr int KVB = 32;      // keys per attn tile
constexpr int NTK = (N / SPLIT) / KVB;  // 32 tiles
constexpr float THR = 8.0f;  // defer-max threshold (base-2)

typedef __attribute__((ext_vector_type(8))) _Float16 f16x8;
typedef __attribute__((ext_vector_type(2))) __fp16 fp16x2;
typedef __attribute__((ext_vector_type(4))) float f32x4;
typedef __attribute__((ext_vector_type(16))) float f32x16;

__device__ inline f32x4 mfma_f16(f16x8 a, f16x8 b, f32x4 c) {
  return __builtin_amdgcn_mfma_f32_16x16x32_f16(a, b, c, 0, 0, 0);
}
__device__ inline f32x16 mfma32(f16x8 a, f16x8 b, f32x16 c) {
  return __builtin_amdgcn_mfma_f32_32x32x16_f16(a, b, c, 0, 0, 0);
}
__device__ inline ushort f2h(float x) {
  __half h = __float2half(x);
  return *(ushort*)&h;
}
__device__ inline float h2f(ushort u) {
  __half h;
  *(ushort*)&h = u;
  return __half2float(h);
}
__device__ inline unsigned pkh(float a, float b) {
  fp16x2 r = __builtin_amdgcn_cvt_pkrtz(a, b);
  return *(unsigned*)&r;
}
// async global->LDS, 16B per lane; lds dest = uniform base + lane*16 (HW rule)
__device__ inline void gload16(const ushort* g, ushort* l) {
  __builtin_amdgcn_global_load_lds(
      (const __attribute__((address_space(1))) void*)g,
      (__attribute__((address_space(3))) void*)l, 16, 0, 0);
}

// ---- LayerNorm (8 rows/block, vectorized) + folded weight cast/transpose --
__global__ __launch_bounds__(256) void lncast_kernel(
    const float* __restrict__ x, const float* __restrict__ g,
    const float* __restrict__ bta, ushort* __restrict__ nxh,
    const float* __restrict__ w_qkv, const float* __restrict__ w_out,
    ushort* __restrict__ wt, ushort* __restrict__ wot) {
  const int tid = threadIdx.x;
  const int lane = tid & 63;
  const int row = blockIdx.x * 8 + (tid >> 6) * 2 + (lane >> 5);
  const int e0 = (lane & 31) * 8;
  const float4 a = *(const float4*)&x[(size_t)row * D + e0];
  const float4 bv = *(const float4*)&x[(size_t)row * D + e0 + 4];
  float s = a.x + a.y + a.z + a.w + bv.x + bv.y + bv.z + bv.w;
  float ss = a.x * a.x + a.y * a.y + a.z * a.z + a.w * a.w +
             bv.x * bv.x + bv.y * bv.y + bv.z * bv.z + bv.w * bv.w;
#pragma unroll
  for (int off = 1; off < 32; off <<= 1) {
    s += __shfl_xor(s, off);
    ss += __shfl_xor(ss, off);
  }
  const float mu = s * (1.0f / D);
  const float rsig = rsqrtf(ss * (1.0f / D) - mu * mu + EPS);
  const float4 g0 = *(const float4*)&g[e0];
  const float4 g1 = *(const float4*)&g[e0 + 4];
  const float4 b0 = *(const float4*)&bta[e0];
  const float4 b1 = *(const float4*)&bta[e0 + 4];
  f16x8 r;
  r[0] = (_Float16)((a.x - mu) * rsig * g0.x + b0.x);
  r[1] = (_Float16)((a.y - mu) * rsig * g0.y + b0.y);
  r[2] = (_Float16)((a.z - mu) * rsig * g0.z + b0.z);
  r[3] = (_Float16)((a.w - mu) * rsig * g0.w + b0.w);
  r[4] = (_Float16)((bv.x - mu) * rsig * g1.x + b1.x);
  r[5] = (_Float16)((bv.y - mu) * rsig * g1.y + b1.y);
  r[6] = (_Float16)((bv.z - mu) * rsig * g1.z + b1.z);
  r[7] = (_Float16)((bv.w - mu) * rsig * g1.w + b1.w);
  *(f16x8*)&nxh[(size_t)row * D + e0] = r;

  if (blockIdx.x < 1024) {
    const int id = blockIdx.x * 256 + tid;
    if (id < 768 * 256) {
      const int n = id >> 8, k = id & 255;
      wt[id] = f2h(w_qkv[(size_t)k * 768 + n]);
    } else {
      const int j = id - 768 * 256;
      const int n = j >> 8, k = j & 255;
      wot[j] = f2h(w_out[(size_t)k * 256 + n]);
    }
  }
}

// ---------------- QKV GEMM via MFMA (no LDS for A/W; weights L2-hot) -------
__global__ __launch_bounds__(256, 4) void qkv_kernel(
    const ushort* __restrict__ nxh, const ushort* __restrict__ wt,
    const float* __restrict__ coord, ushort* __restrict__ qfp,
    ushort* __restrict__ kfp, ushort* __restrict__ vtp) {
  __shared__ ushort vs[64 * 132];  // [col 0..63][n 0..127], stride 132
  const int t = threadIdx.x;
  const int w = t >> 6, lane = t & 63;
  const int lrow = lane & 15, lhi = lane >> 4;
  const int m0 = blockIdx.x * 128 + w * 32;
  const int c0 = blockIdx.y * 64;  // within [0,768)
  f32x4 acc[2][4];
#pragma unroll
  for (int qs = 0; qs < 2; ++qs)
#pragma unroll
    for (int nt = 0; nt < 4; ++nt) acc[qs][nt] = f32x4{0.f, 0.f, 0.f, 0.f};

#pragma unroll
  for (int kc = 0; kc < D; kc += 32) {
    f16x8 ah[2], bw[4];
#pragma unroll
    for (int qs = 0; qs < 2; ++qs)
      ah[qs] = *(const f16x8*)(nxh + (size_t)(m0 + qs * 16 + lrow) * D + kc +
                               lhi * 8);
#pragma unroll
    for (int nt = 0; nt < 4; ++nt)
      bw[nt] = *(const f16x8*)(wt + (size_t)(c0 + nt * 16 + lrow) * D + kc +
                               lhi * 8);
#pragma unroll
    for (int qs = 0; qs < 2; ++qs)
#pragma unroll
      for (int nt = 0; nt < 4; ++nt)
        acc[qs][nt] = mfma_f16(ah[qs], bw[nt], acc[qs][nt]);
  }

  const int region = blockIdx.y >> 2;  // 0:q 1:k 2:v
  const int cbase = c0 & 255;
  if (region < 2) {
    const float sc = (region == 0) ? QSC2 : 1.0f;
    ushort* dp = (region == 0) ? qfp : kfp;
#pragma unroll
    for (int qs = 0; qs < 2; ++qs)
#pragma unroll
      for (int nt = 0; nt < 4; ++nt)
#pragma unroll
        for (int i = 0; i < 4; ++i) {
          const int row = m0 + qs * 16 + lhi * 4 + i;
          const int col = cbase + nt * 16 + lrow;
          const float val =
              (acc[qs][nt][i] + coord[(size_t)row * D + col]) * sc;
          dp[(size_t)row * D + col] = f2h(val);
        }
  } else {
    // stage into LDS: vs[col][n], col = nt*16+lrow, n = w*32+qs*16+lhi*4+i
#pragma unroll
    for (int qs = 0; qs < 2; ++qs)
#pragma unroll
      for (int nt = 0; nt < 4; ++nt) {
        ushort4 pk;
        pk.x = f2h(acc[qs][nt][0]);
        pk.y = f2h(acc[qs][nt][1]);
        pk.z = f2h(acc[qs][nt][2]);
        pk.w = f2h(acc[qs][nt][3]);
        *(ushort4*)&vs[(nt * 16 + lrow) * 132 + w * 32 + qs * 16 + lhi * 4] =
            pk;
      }
    __syncthreads();
    // coalesced write: thread -> 32 consecutive n of one col (64B).
    // Base is BLOCK-uniform (no w term).
    const int c = t >> 2, seg = (t & 3) * 32;
    const int nb0 = blockIdx.x * 128;
    const int bb = nb0 >> 12, nb = nb0 & (N - 1);
    ushort* dst = vtp + ((size_t)bb * D + cbase + c) * N + nb + seg;
    const ushort* src = &vs[c * 132 + seg];
#pragma unroll
    for (int k2 = 0; k2 < 8; ++k2)
      *(uint2*)(dst + k2 * 4) = *(const uint2*)(src + k2 * 4);
  }
}

// ---------------- MFMA flash attention (32x32 swapped-operand) -------------
// 8 warps x 32 q-rows (block = 256 rows), KVB=32 keys/tile, SPLIT=4.
// QUAD-buffered K/V staging (128KB LDS), ONE s_barrier per tile, rolled loop,
// T15 deferred-PV pipeline. Round-23: FULL-WIDTH K swizzle — stage content
// of kbuf[key][slot] = K d-granule slot^key (all 5 bits, was key&7); read
// granule (c*2+h)^q. Half-wave's 32 lanes now hit 32 DISTINCT granules ->
// conflict-free K reads (was 4-way: lanes {q,q+8,q+16,q+24} shared a slot,
// 8.39M conflict cycles). V stays 2-way (free per m136).
__global__ __launch_bounds__(512, 2) void attn_kernel(
    const ushort* __restrict__ qf, const ushort* __restrict__ kf,
    const ushort* __restrict__ vt, ushort* __restrict__ pob,
    float* __restrict__ mlb) {
  __shared__ ushort kbuf[4][8192];  // [key 0..31][32 granules]    16KB each
  __shared__ ushort vbuf[4][8192];  // [d-pair 0..127][8 granules] 16KB each

  const int tid = threadIdx.x;
  const int lane = tid & 63;
  const int q = lane & 31, h = lane >> 5;
  const int w = tid >> 6;
  const int b = blockIdx.y, s = blockIdx.z;
  const int qw = blockIdx.x * 256 + w * 32;
  const int kbeg = s * (N / SPLIT);

  const ushort* qrow = qf + ((size_t)b * N + qw + q) * D;
  const ushort* kfb = kf + (size_t)b * N * D;
  const ushort* vtb = vt + (size_t)b * D * N;
  ushort* pog = pob + (size_t)s * BN * D;
  float* mlg = mlb + (size_t)s * BN * 2;

  // persistent Q chunks 0..7 (d 0..127); chunks 8..15 streamed per tile
  f16x8 qfr[8];
#pragma unroll
  for (int c = 0; c < 8; ++c)
    qfr[c] = *(const f16x8*)(qrow + c * 16 + h * 8);

  f32x16 o[8];
#pragma unroll
  for (int dt = 0; dt < 8; ++dt)
#pragma unroll
    for (int r = 0; r < 16; ++r) o[dt][r] = 0.f;
  float m = -1e30f, lsum = 0.f;
  float f_prev = 1.0f;
  bool need_prev = false;
  f16x8 pf_prev[2];

  // stage one 32-key K+V tile; 4 granule-loads per thread (2 K + 2 V).
  // K: granule G -> key=G>>5, slot=G&31; src d-gran = slot^key (full width)
  // V: granule G -> r=G>>3, slot=G&7; u=slot^(r&7); d=2r+(u>>2); sg=u&3
  auto stage = [&](int bi, int k0) {
#pragma unroll
    for (int i = 0; i < 2; ++i) {
      const int g = i * 512 + tid;
      const int key = g >> 5, slot = g & 31;
      gload16(kfb + (size_t)(k0 + key) * D + ((slot ^ key) * 8),
              &kbuf[bi][g * 8]);
    }
#pragma unroll
    for (int i = 0; i < 2; ++i) {
      const int g = i * 512 + tid;
      const int r = g >> 3, slot = g & 7;
      const int u = slot ^ (r & 7);
      const int d = r * 2 + (u >> 2);
      gload16(vtb + (size_t)d * N + k0 + ((u & 3) * 8), &vbuf[bi][g * 8]);
    }
  };

  stage(0, kbeg);

  for (int t = 0; t < NTK; ++t) {
    const int cur = t & 3;
    const int prv = (t + 3) & 3;
    // stream Q chunks 8..15 (issued BEFORE next-tile stage so vmcnt(12)
    // drains exactly the current tile's 4 stage loads)
    f16x8 qs[8];
#pragma unroll
    for (int c = 0; c < 8; ++c)
      qs[c] = *(const f16x8*)(qrow + (8 + c) * 16 + h * 8);
    if (t + 1 < NTK) {
      stage((t + 1) & 3, kbeg + (t + 1) * KVB);
      asm volatile("s_waitcnt vmcnt(12)" ::: "memory");  // drain stage(t)
    } else {
      asm volatile("s_waitcnt vmcnt(8)" ::: "memory");   // qs still in flight
    }
    __builtin_amdgcn_sched_barrier(0);
    __builtin_amdgcn_s_barrier();   // the ONLY barrier per tile
    __builtin_amdgcn_sched_barrier(0);

    // ---- QK(t): S^T = K Q, single 16-MFMA chain into p ----
    f32x16 p;
#pragma unroll
    for (int r = 0; r < 16; ++r) p[r] = 0.f;
    __builtin_amdgcn_s_setprio(1);
#pragma unroll
    for (int c = 0; c < 16; ++c) {
      const f16x8 qv = (c < 8) ? qfr[c] : qs[c - 8];
      const f16x8 ka = *(const f16x8*)&kbuf[cur][q * 256 +
                                                 (((c * 2 + h) ^ q) * 8)];
      p = mfma32(ka, qv, p);
    }
    __builtin_amdgcn_s_setprio(0);

    // ---- deferred: rescale o by f(t-1), then PV(t-1) ----
    if (t > 0) {
      if (need_prev) {
#pragma unroll
        for (int dt = 0; dt < 8; ++dt) o[dt] *= f_prev;
      }
      __builtin_amdgcn_s_setprio(1);
#pragma unroll
      for (int dt = 0; dt < 8; ++dt) {
        const int d = dt * 32 + q;
        const int rr = d >> 1;
#pragma unroll
        for (int kk = 0; kk < 2; ++kk) {
          const int u = (d & 1) * 4 + kk * 2 + h;
          const f16x8 vf = *(const f16x8*)&vbuf[prv][rr * 64 +
                                                     ((u ^ (rr & 7)) * 8)];
          o[dt] = mfma32(vf, pf_prev[kk], o[dt]);
        }
      }
      __builtin_amdgcn_s_setprio(0);
    }

    // ---- softmax(t): runs while PV(t-1) drains the matrix pipe ----
    float tm[8];
#pragma unroll
    for (int j = 0; j < 8; ++j) tm[j] = fmaxf(p[2 * j], p[2 * j + 1]);
    float pmax = fmaxf(fmaxf(fmaxf(tm[0], tm[1]), fmaxf(tm[2], tm[3])),
                       fmaxf(fmaxf(tm[4], tm[5]), fmaxf(tm[6], tm[7])));
    const float pm = fmaxf(pmax, __shfl_xor(pmax, 32));
    const bool need = pm > m + THR;
    if (__any(need)) {
      const float mn = fmaxf(m, pm);
      f_prev = exp2f(m - mn);
      m = mn;
      lsum *= f_prev;
      need_prev = true;
    } else {
      need_prev = false;
    }
#pragma unroll
    for (int r = 0; r < 16; ++r) {
      p[r] = exp2f(p[r] - m);
      lsum += p[r];
    }

    // ---- pack P -> pf_prev: cvt_pkrtz + PRE-SELECTED exchange (2 shfls/kk)
    // lane(q,h) owns packed words: x=keys(4h,4h+1) z=(4h+2,4h+3)
    // y=(8+4h,9+4h) wv=(10+4h,11+4h). B-frag word_j = keys(h*8+2j,+1):
    // h0 needs {x, z, partner-x, partner-z}; h1 needs {partner-y,
    // partner-wv, y, wv}. Select before the exchange: e1 = h?x:y, e2 = h?z:wv.
#pragma unroll
    for (int kk = 0; kk < 2; ++kk) {
      const int sub = kk * 8;
      const unsigned x = pkh(p[sub + 0], p[sub + 1]);
      const unsigned z = pkh(p[sub + 2], p[sub + 3]);
      const unsigned y = pkh(p[sub + 4], p[sub + 5]);
      const unsigned wv = pkh(p[sub + 6], p[sub + 7]);
      const unsigned e1 = h ? x : y;   // value the partner needs (slot A)
      const unsigned e2 = h ? z : wv;  // value the partner needs (slot B)
      const unsigned r1 = __shfl_xor(e1, 32);  // h0: partner-x ; h1: partner-y
      const unsigned r2 = __shfl_xor(e2, 32);  // h0: partner-z ; h1: partner-wv
      union { f16x8 v; unsigned u[4]; } pu;
      pu.u[0] = h ? r1 : x;
      pu.u[1] = h ? r2 : z;
      pu.u[2] = h ? y : r1;
      pu.u[3] = h ? wv : r2;
      pf_prev[kk] = pu.v;
    }
  }

  // ---- epilogue: final rescale + PV(NTK-1), then normalize & write ----
  if (need_prev) {
#pragma unroll
    for (int dt = 0; dt < 8; ++dt) o[dt] *= f_prev;
  }
  {
    const int prv = (NTK - 1) & 3;
#pragma unroll
    for (int dt = 0; dt < 8; ++dt) {
      const int d = dt * 32 + q;
      const int rr = d >> 1;
#pragma unroll
      for (int kk = 0; kk < 2; ++kk) {
        const int u = (d & 1) * 4 + kk * 2 + h;
        const f16x8 vf = *(const f16x8*)&vbuf[prv][rr * 64 +
                                                   ((u ^ (rr & 7)) * 8)];
        o[dt] = mfma32(vf, pf_prev[kk], o[dt]);
      }
    }
  }
  const float lt = lsum + __shfl_xor(lsum, 32);
  const float inv = 1.0f / lt;
  ushort* orow = pog + ((size_t)b * N + qw + q) * D;
#pragma unroll
  for (int dt = 0; dt < 8; ++dt)
#pragma unroll
    for (int r4 = 0; r4 < 4; ++r4) {
      const unsigned u0 =
          pkh(o[dt][r4 * 4 + 0] * inv, o[dt][r4 * 4 + 1] * inv);
      const unsigned u1 =
          pkh(o[dt][r4 * 4 + 2] * inv, o[dt][r4 * 4 + 3] * inv);
      uint2 val;
      val.x = u0;
      val.y = u1;
      *(uint2*)(orow + dt * 32 + r4 * 8 + h * 4) = val;
    }
  if (h == 0) {
    const size_t r = (size_t)b * N + qw + q;
    mlg[r * 2] = m;
    mlg[r * 2 + 1] = lt;
  }
}

// -------- fused merge + output projection via MFMA --------------
__global__ __launch_bounds__(256, 4) void projm_kernel(
    const ushort* __restrict__ pob, const float* __restrict__ mlb,
    const ushort* __restrict__ wot, const float* __restrict__ bias,
    float* __restrict__ out) {
  const int t = threadIdx.x;
  const int w = t >> 6, lane = t & 63;
  const int lrow = lane & 15, lhi = lane >> 4;
  const int m0 = blockIdx.x * 128 + w * 32;
  const int c0 = blockIdx.y * 64;

  // per-thread merge weights for rows m0+lrow, m0+16+lrow
  float cw[2][SPLIT];
#pragma unroll
  for (int qs = 0; qs < 2; ++qs) {
    const int row = m0 + qs * 16 + lrow;
    float mv[SPLIT], lv[SPLIT], mm = -1e30f;
#pragma unroll
    for (int s = 0; s < SPLIT; ++s) {
      mv[s] = mlb[(size_t)s * BN * 2 + row * 2];
      lv[s] = mlb[(size_t)s * BN * 2 + row * 2 + 1];
      mm = fmaxf(mm, mv[s]);
    }
    float wsum = 0.f;
#pragma unroll
    for (int s = 0; s < SPLIT; ++s) {
      cw[qs][s] = exp2f(mv[s] - mm) * lv[s];
      wsum += cw[qs][s];
    }
    const float invw = 1.0f / wsum;
#pragma unroll
    for (int s = 0; s < SPLIT; ++s) cw[qs][s] *= invw;
  }

  f32x4 acc[2][4];
#pragma unroll
  for (int qs = 0; qs < 2; ++qs)
#pragma unroll
    for (int nt = 0; nt < 4; ++nt) acc[qs][nt] = f32x4{0.f, 0.f, 0.f, 0.f};

#pragma unroll
  for (int kc = 0; kc < D; kc += 32) {
    f16x8 ah[2], bw[4];
#pragma unroll
    for (int qs = 0; qs < 2; ++qs) {
      const size_t off = (size_t)(m0 + qs * 16 + lrow) * D + kc + lhi * 8;
      float v[8] = {};
#pragma unroll
      for (int s = 0; s < SPLIT; ++s) {
        const f16x8 ps = *(const f16x8*)(pob + (size_t)s * BN * D + off);
        const float c = cw[qs][s];
#pragma unroll
        for (int j = 0; j < 8; ++j) v[j] += c * (float)ps[j];
      }
      f16x8 a;
#pragma unroll
      for (int j = 0; j < 8; ++j) a[j] = (_Float16)v[j];
      ah[qs] = a;
    }
#pragma unroll
    for (int nt = 0; nt < 4; ++nt)
      bw[nt] = *(const f16x8*)(wot + (size_t)(c0 + nt * 16 + lrow) * D + kc +
                               lhi * 8);
#pragma unroll
    for (int qs = 0; qs < 2; ++qs)
#pragma unroll
      for (int nt = 0; nt < 4; ++nt)
        acc[qs][nt] = mfma_f16(ah[qs], bw[nt], acc[qs][nt]);
  }
#pragma unroll
  for (int qs = 0; qs < 2; ++qs)
#pragma unroll
    for (int nt = 0; nt < 4; ++nt)
#pragma unroll
      for (int i = 0; i < 4; ++i) {
        const int row = m0 + qs * 16 + lhi * 4 + i;
        const int col = c0 + nt * 16 + lrow;
        out[(size_t)row * D + col] = acc[qs][nt][i] + bias[col];
      }
}

extern "C" void kernel_launch(void* const* d_in, const int* in_sizes, int n_in,
                              void* d_out, int out_size, void* d_ws, size_t ws_size,
                              hipStream_t stream) {
  const float* x = (const float*)d_in[0];
  const float* coord = (const float*)d_in[1];
  const float* ln_g = (const float*)d_in[2];
  const float* ln_b = (const float*)d_in[3];
  const float* w_qkv = (const float*)d_in[4];
  const float* w_out = (const float*)d_in[5];
  const float* b_out = (const float*)d_in[6];
  float* out = (float*)d_out;

  const size_t P = (size_t)BN * D;

  ushort* qfp = (ushort*)d_ws;
  ushort* kfp = qfp + P;
  ushort* vtp = kfp + P;
  ushort* pob = vtp + P;                      // SPLIT partial-O planes
  float* mlb = (float*)(pob + (size_t)SPLIT * P);
  ushort* wt = (ushort*)(mlb + (size_t)SPLIT * BN * 2);
  ushort* wot = wt + 768 * 256;
  // alias (liveness-disjoint):
  ushort* nxh = pob;       // written by ln, consumed by qkv, dead before attn

  hipLaunchKernelGGL(lncast_kernel, dim3(BN / 8), dim3(256), 0, stream,
                     x, ln_g, ln_b, nxh, w_qkv, w_out, wt, wot);
  hipLaunchKernelGGL(qkv_kernel, dim3(BN / 128, 12), dim3(256), 0, stream,
                     nxh, wt, coord, qfp, kfp, vtp);
  hipLaunchKernelGGL(attn_kernel, dim3(N / 256, B, SPLIT), dim3(512), 0,
                     stream, qfp, kfp, vtp, pob, mlb);
  hipLaunchKernelGGL(projm_kernel, dim3(BN / 128, 4), dim3(256), 0, stream,
                     pob, mlb, wot, b_out, out);
}

// Round 24
// 170.429 us; speedup vs baseline: 1.6677x; 1.0173x over previous
//
#include <hip/hip_runtime.h>
#include <hip/hip_fp16.h>
#include <math.h>

constexpr int B = 4, N = 4096, D = 256;
constexpr int BN = B * N;
constexpr float EPS = 1e-5f;
// softmax scale (D^-0.5 = 1/16) * log2(e), folded into q at f16-cast time
constexpr float QSC2 = 0.0625f * 1.44269504088896340736f;

constexpr int SPLIT = 4;     // KV splits -> grid 256 blocks (1/CU)
constexpr int KVB = 32;      // keys per attn tile
constexpr int NTK = (N / SPLIT) / KVB;  // 32 tiles
constexpr float THR = 8.0f;  // defer-max threshold (base-2)

typedef __attribute__((ext_vector_type(8))) _Float16 f16x8;
typedef __attribute__((ext_vector_type(2))) __fp16 fp16x2;
typedef __attribute__((ext_vector_type(4))) float f32x4;
typedef __attribute__((ext_vector_type(16))) float f32x16;

__device__ inline f32x4 mfma_f16(f16x8 a, f16x8 b, f32x4 c) {
  return __builtin_amdgcn_mfma_f32_16x16x32_f16(a, b, c, 0, 0, 0);
}
__device__ inline f32x16 mfma32(f16x8 a, f16x8 b, f32x16 c) {
  return __builtin_amdgcn_mfma_f32_32x32x16_f16(a, b, c, 0, 0, 0);
}
__device__ inline ushort f2h(float x) {
  __half h = __float2half(x);
  return *(ushort*)&h;
}
__device__ inline float h2f(ushort u) {
  __half h;
  *(ushort*)&h = u;
  return __half2float(h);
}
__device__ inline unsigned pkh(float a, float b) {
  fp16x2 r = __builtin_amdgcn_cvt_pkrtz(a, b);
  return *(unsigned*)&r;
}
// async global->LDS, 16B per lane; lds dest = uniform base + lane*16 (HW rule)
__device__ inline void gload16(const ushort* g, ushort* l) {
  __builtin_amdgcn_global_load_lds(
      (const __attribute__((address_space(1))) void*)g,
      (__attribute__((address_space(3))) void*)l, 16, 0, 0);
}

// ---- LayerNorm (8 rows/block, vectorized) + folded weight cast/transpose --
__global__ __launch_bounds__(256) void lncast_kernel(
    const float* __restrict__ x, const float* __restrict__ g,
    const float* __restrict__ bta, ushort* __restrict__ nxh,
    const float* __restrict__ w_qkv, const float* __restrict__ w_out,
    ushort* __restrict__ wt, ushort* __restrict__ wot) {
  const int tid = threadIdx.x;
  const int lane = tid & 63;
  const int row = blockIdx.x * 8 + (tid >> 6) * 2 + (lane >> 5);
  const int e0 = (lane & 31) * 8;
  const float4 a = *(const float4*)&x[(size_t)row * D + e0];
  const float4 bv = *(const float4*)&x[(size_t)row * D + e0 + 4];
  float s = a.x + a.y + a.z + a.w + bv.x + bv.y + bv.z + bv.w;
  float ss = a.x * a.x + a.y * a.y + a.z * a.z + a.w * a.w +
             bv.x * bv.x + bv.y * bv.y + bv.z * bv.z + bv.w * bv.w;
#pragma unroll
  for (int off = 1; off < 32; off <<= 1) {
    s += __shfl_xor(s, off);
    ss += __shfl_xor(ss, off);
  }
  const float mu = s * (1.0f / D);
  const float rsig = rsqrtf(ss * (1.0f / D) - mu * mu + EPS);
  const float4 g0 = *(const float4*)&g[e0];
  const float4 g1 = *(const float4*)&g[e0 + 4];
  const float4 b0 = *(const float4*)&bta[e0];
  const float4 b1 = *(const float4*)&bta[e0 + 4];
  f16x8 r;
  r[0] = (_Float16)((a.x - mu) * rsig * g0.x + b0.x);
  r[1] = (_Float16)((a.y - mu) * rsig * g0.y + b0.y);
  r[2] = (_Float16)((a.z - mu) * rsig * g0.z + b0.z);
  r[3] = (_Float16)((a.w - mu) * rsig * g0.w + b0.w);
  r[4] = (_Float16)((bv.x - mu) * rsig * g1.x + b1.x);
  r[5] = (_Float16)((bv.y - mu) * rsig * g1.y + b1.y);
  r[6] = (_Float16)((bv.z - mu) * rsig * g1.z + b1.z);
  r[7] = (_Float16)((bv.w - mu) * rsig * g1.w + b1.w);
  *(f16x8*)&nxh[(size_t)row * D + e0] = r;

  if (blockIdx.x < 1024) {
    const int id = blockIdx.x * 256 + tid;
    if (id < 768 * 256) {
      const int n = id >> 8, k = id & 255;
      wt[id] = f2h(w_qkv[(size_t)k * 768 + n]);
    } else {
      const int j = id - 768 * 256;
      const int n = j >> 8, k = j & 255;
      wot[j] = f2h(w_out[(size_t)k * 256 + n]);
    }
  }
}

// ---------------- QKV GEMM via MFMA (no LDS for A/W; weights L2-hot) -------
__global__ __launch_bounds__(256, 4) void qkv_kernel(
    const ushort* __restrict__ nxh, const ushort* __restrict__ wt,
    const float* __restrict__ coord, ushort* __restrict__ qfp,
    ushort* __restrict__ kfp, ushort* __restrict__ vtp) {
  __shared__ ushort vs[64 * 132];  // [col 0..63][n 0..127], stride 132
  const int t = threadIdx.x;
  const int w = t >> 6, lane = t & 63;
  const int lrow = lane & 15, lhi = lane >> 4;
  const int m0 = blockIdx.x * 128 + w * 32;
  const int c0 = blockIdx.y * 64;  // within [0,768)
  f32x4 acc[2][4];
#pragma unroll
  for (int qs = 0; qs < 2; ++qs)
#pragma unroll
    for (int nt = 0; nt < 4; ++nt) acc[qs][nt] = f32x4{0.f, 0.f, 0.f, 0.f};

#pragma unroll
  for (int kc = 0; kc < D; kc += 32) {
    f16x8 ah[2], bw[4];
#pragma unroll
    for (int qs = 0; qs < 2; ++qs)
      ah[qs] = *(const f16x8*)(nxh + (size_t)(m0 + qs * 16 + lrow) * D + kc +
                               lhi * 8);
#pragma unroll
    for (int nt = 0; nt < 4; ++nt)
      bw[nt] = *(const f16x8*)(wt + (size_t)(c0 + nt * 16 + lrow) * D + kc +
                               lhi * 8);
#pragma unroll
    for (int qs = 0; qs < 2; ++qs)
#pragma unroll
      for (int nt = 0; nt < 4; ++nt)
        acc[qs][nt] = mfma_f16(ah[qs], bw[nt], acc[qs][nt]);
  }

  const int region = blockIdx.y >> 2;  // 0:q 1:k 2:v
  const int cbase = c0 & 255;
  if (region < 2) {
    const float sc = (region == 0) ? QSC2 : 1.0f;
    ushort* dp = (region == 0) ? qfp : kfp;
#pragma unroll
    for (int qs = 0; qs < 2; ++qs)
#pragma unroll
      for (int nt = 0; nt < 4; ++nt)
#pragma unroll
        for (int i = 0; i < 4; ++i) {
          const int row = m0 + qs * 16 + lhi * 4 + i;
          const int col = cbase + nt * 16 + lrow;
          const float val =
              (acc[qs][nt][i] + coord[(size_t)row * D + col]) * sc;
          dp[(size_t)row * D + col] = f2h(val);
        }
  } else {
    // stage into LDS: vs[col][n], col = nt*16+lrow, n = w*32+qs*16+lhi*4+i
#pragma unroll
    for (int qs = 0; qs < 2; ++qs)
#pragma unroll
      for (int nt = 0; nt < 4; ++nt) {
        ushort4 pk;
        pk.x = f2h(acc[qs][nt][0]);
        pk.y = f2h(acc[qs][nt][1]);
        pk.z = f2h(acc[qs][nt][2]);
        pk.w = f2h(acc[qs][nt][3]);
        *(ushort4*)&vs[(nt * 16 + lrow) * 132 + w * 32 + qs * 16 + lhi * 4] =
            pk;
      }
    __syncthreads();
    // coalesced write: thread -> 32 consecutive n of one col (64B).
    // Base is BLOCK-uniform (no w term).
    const int c = t >> 2, seg = (t & 3) * 32;
    const int nb0 = blockIdx.x * 128;
    const int bb = nb0 >> 12, nb = nb0 & (N - 1);
    ushort* dst = vtp + ((size_t)bb * D + cbase + c) * N + nb + seg;
    const ushort* src = &vs[c * 132 + seg];
#pragma unroll
    for (int k2 = 0; k2 < 8; ++k2)
      *(uint2*)(dst + k2 * 4) = *(const uint2*)(src + k2 * 4);
  }
}

// ---------------- MFMA flash attention (32x32 swapped-operand) -------------
// 8 warps x 32 q-rows (block = 256 rows), KVB=32 keys/tile, SPLIT=4.
// QUAD-buffered K/V staging (128KB LDS), ONE s_barrier per tile, rolled loop,
// T15 deferred-PV pipeline, full-width K swizzle (round-23, conflict-free K).
// Round-24: ALL 16 Q chunks persistent (qfr[16]) — removes the per-tile
// re-stream of Q chunks 8..15 (8 loads/lane/tile, pure issue + L1-contention
// overhead; register PEAK unchanged: old QK phase held qfr[8]+qs[8] = same
// 64 regs). vmcnt simplifies: only stage loads outstanding -> vmcnt(4)/0.
__global__ __launch_bounds__(512, 2) void attn_kernel(
    const ushort* __restrict__ qf, const ushort* __restrict__ kf,
    const ushort* __restrict__ vt, ushort* __restrict__ pob,
    float* __restrict__ mlb) {
  __shared__ ushort kbuf[4][8192];  // [key 0..31][32 granules]    16KB each
  __shared__ ushort vbuf[4][8192];  // [d-pair 0..127][8 granules] 16KB each

  const int tid = threadIdx.x;
  const int lane = tid & 63;
  const int q = lane & 31, h = lane >> 5;
  const int w = tid >> 6;
  const int b = blockIdx.y, s = blockIdx.z;
  const int qw = blockIdx.x * 256 + w * 32;
  const int kbeg = s * (N / SPLIT);

  const ushort* qrow = qf + ((size_t)b * N + qw + q) * D;
  const ushort* kfb = kf + (size_t)b * N * D;
  const ushort* vtb = vt + (size_t)b * D * N;
  ushort* pog = pob + (size_t)s * BN * D;
  float* mlg = mlb + (size_t)s * BN * 2;

  // ALL 16 Q chunks persistent (d 0..255)
  f16x8 qfr[16];
#pragma unroll
  for (int c = 0; c < 16; ++c)
    qfr[c] = *(const f16x8*)(qrow + c * 16 + h * 8);

  f32x16 o[8];
#pragma unroll
  for (int dt = 0; dt < 8; ++dt)
#pragma unroll
    for (int r = 0; r < 16; ++r) o[dt][r] = 0.f;
  float m = -1e30f, lsum = 0.f;
  float f_prev = 1.0f;
  bool need_prev = false;
  f16x8 pf_prev[2];

  // stage one 32-key K+V tile; 4 granule-loads per thread (2 K + 2 V).
  // K: granule G -> key=G>>5, slot=G&31; src d-gran = slot^key (full width)
  // V: granule G -> r=G>>3, slot=G&7; u=slot^(r&7); d=2r+(u>>2); sg=u&3
  auto stage = [&](int bi, int k0) {
#pragma unroll
    for (int i = 0; i < 2; ++i) {
      const int g = i * 512 + tid;
      const int key = g >> 5, slot = g & 31;
      gload16(kfb + (size_t)(k0 + key) * D + ((slot ^ key) * 8),
              &kbuf[bi][g * 8]);
    }
#pragma unroll
    for (int i = 0; i < 2; ++i) {
      const int g = i * 512 + tid;
      const int r = g >> 3, slot = g & 7;
      const int u = slot ^ (r & 7);
      const int d = r * 2 + (u >> 2);
      gload16(vtb + (size_t)d * N + k0 + ((u & 3) * 8), &vbuf[bi][g * 8]);
    }
  };

  stage(0, kbeg);

  for (int t = 0; t < NTK; ++t) {
    const int cur = t & 3;
    const int prv = (t + 3) & 3;
    if (t + 1 < NTK) {
      stage((t + 1) & 3, kbeg + (t + 1) * KVB);
      asm volatile("s_waitcnt vmcnt(4)" ::: "memory");  // drain stage(t)
    } else {
      asm volatile("s_waitcnt vmcnt(0)" ::: "memory");
    }
    __builtin_amdgcn_sched_barrier(0);
    __builtin_amdgcn_s_barrier();   // the ONLY barrier per tile
    __builtin_amdgcn_sched_barrier(0);

    // ---- QK(t): S^T = K Q, single 16-MFMA chain into p ----
    f32x16 p;
#pragma unroll
    for (int r = 0; r < 16; ++r) p[r] = 0.f;
    __builtin_amdgcn_s_setprio(1);
#pragma unroll
    for (int c = 0; c < 16; ++c) {
      const f16x8 ka = *(const f16x8*)&kbuf[cur][q * 256 +
                                                 (((c * 2 + h) ^ q) * 8)];
      p = mfma32(ka, qfr[c], p);
    }
    __builtin_amdgcn_s_setprio(0);

    // ---- deferred: rescale o by f(t-1), then PV(t-1) ----
    if (t > 0) {
      if (need_prev) {
#pragma unroll
        for (int dt = 0; dt < 8; ++dt) o[dt] *= f_prev;
      }
      __builtin_amdgcn_s_setprio(1);
#pragma unroll
      for (int dt = 0; dt < 8; ++dt) {
        const int d = dt * 32 + q;
        const int rr = d >> 1;
#pragma unroll
        for (int kk = 0; kk < 2; ++kk) {
          const int u = (d & 1) * 4 + kk * 2 + h;
          const f16x8 vf = *(const f16x8*)&vbuf[prv][rr * 64 +
                                                     ((u ^ (rr & 7)) * 8)];
          o[dt] = mfma32(vf, pf_prev[kk], o[dt]);
        }
      }
      __builtin_amdgcn_s_setprio(0);
    }

    // ---- softmax(t): runs while PV(t-1) drains the matrix pipe ----
    float tm[8];
#pragma unroll
    for (int j = 0; j < 8; ++j) tm[j] = fmaxf(p[2 * j], p[2 * j + 1]);
    float pmax = fmaxf(fmaxf(fmaxf(tm[0], tm[1]), fmaxf(tm[2], tm[3])),
                       fmaxf(fmaxf(tm[4], tm[5]), fmaxf(tm[6], tm[7])));
    const float pm = fmaxf(pmax, __shfl_xor(pmax, 32));
    const bool need = pm > m + THR;
    if (__any(need)) {
      const float mn = fmaxf(m, pm);
      f_prev = exp2f(m - mn);
      m = mn;
      lsum *= f_prev;
      need_prev = true;
    } else {
      need_prev = false;
    }
#pragma unroll
    for (int r = 0; r < 16; ++r) {
      p[r] = exp2f(p[r] - m);
      lsum += p[r];
    }

    // ---- pack P -> pf_prev: cvt_pkrtz + PRE-SELECTED exchange (2 shfls/kk)
    // lane(q,h) owns packed words: x=keys(4h,4h+1) z=(4h+2,4h+3)
    // y=(8+4h,9+4h) wv=(10+4h,11+4h). B-frag word_j = keys(h*8+2j,+1):
    // h0 needs {x, z, partner-x, partner-z}; h1 needs {partner-y,
    // partner-wv, y, wv}. Select before the exchange: e1 = h?x:y, e2 = h?z:wv.
#pragma unroll
    for (int kk = 0; kk < 2; ++kk) {
      const int sub = kk * 8;
      const unsigned x = pkh(p[sub + 0], p[sub + 1]);
      const unsigned z = pkh(p[sub + 2], p[sub + 3]);
      const unsigned y = pkh(p[sub + 4], p[sub + 5]);
      const unsigned wv = pkh(p[sub + 6], p[sub + 7]);
      const unsigned e1 = h ? x : y;   // value the partner needs (slot A)
      const unsigned e2 = h ? z : wv;  // value the partner needs (slot B)
      const unsigned r1 = __shfl_xor(e1, 32);  // h0: partner-x ; h1: partner-y
      const unsigned r2 = __shfl_xor(e2, 32);  // h0: partner-z ; h1: partner-wv
      union { f16x8 v; unsigned u[4]; } pu;
      pu.u[0] = h ? r1 : x;
      pu.u[1] = h ? r2 : z;
      pu.u[2] = h ? y : r1;
      pu.u[3] = h ? wv : r2;
      pf_prev[kk] = pu.v;
    }
  }

  // ---- epilogue: final rescale + PV(NTK-1), then normalize & write ----
  if (need_prev) {
#pragma unroll
    for (int dt = 0; dt < 8; ++dt) o[dt] *= f_prev;
  }
  {
    const int prv = (NTK - 1) & 3;
#pragma unroll
    for (int dt = 0; dt < 8; ++dt) {
      const int d = dt * 32 + q;
      const int rr = d >> 1;
#pragma unroll
      for (int kk = 0; kk < 2; ++kk) {
        const int u = (d & 1) * 4 + kk * 2 + h;
        const f16x8 vf = *(const f16x8*)&vbuf[prv][rr * 64 +
                                                   ((u ^ (rr & 7)) * 8)];
        o[dt] = mfma32(vf, pf_prev[kk], o[dt]);
      }
    }
  }
  const float lt = lsum + __shfl_xor(lsum, 32);
  const float inv = 1.0f / lt;
  ushort* orow = pog + ((size_t)b * N + qw + q) * D;
#pragma unroll
  for (int dt = 0; dt < 8; ++dt)
#pragma unroll
    for (int r4 = 0; r4 < 4; ++r4) {
      const unsigned u0 =
          pkh(o[dt][r4 * 4 + 0] * inv, o[dt][r4 * 4 + 1] * inv);
      const unsigned u1 =
          pkh(o[dt][r4 * 4 + 2] * inv, o[dt][r4 * 4 + 3] * inv);
      uint2 val;
      val.x = u0;
      val.y = u1;
      *(uint2*)(orow + dt * 32 + r4 * 8 + h * 4) = val;
    }
  if (h == 0) {
    const size_t r = (size_t)b * N + qw + q;
    mlg[r * 2] = m;
    mlg[r * 2 + 1] = lt;
  }
}

// -------- fused merge + output projection via MFMA --------------
__global__ __launch_bounds__(256, 4) void projm_kernel(
    const ushort* __restrict__ pob, const float* __restrict__ mlb,
    const ushort* __restrict__ wot, const float* __restrict__ bias,
    float* __restrict__ out) {
  const int t = threadIdx.x;
  const int w = t >> 6, lane = t & 63;
  const int lrow = lane & 15, lhi = lane >> 4;
  const int m0 = blockIdx.x * 128 + w * 32;
  const int c0 = blockIdx.y * 64;

  // per-thread merge weights for rows m0+lrow, m0+16+lrow
  float cw[2][SPLIT];
#pragma unroll
  for (int qs = 0; qs < 2; ++qs) {
    const int row = m0 + qs * 16 + lrow;
    float mv[SPLIT], lv[SPLIT], mm = -1e30f;
#pragma unroll
    for (int s = 0; s < SPLIT; ++s) {
      mv[s] = mlb[(size_t)s * BN * 2 + row * 2];
      lv[s] = mlb[(size_t)s * BN * 2 + row * 2 + 1];
      mm = fmaxf(mm, mv[s]);
    }
    float wsum = 0.f;
#pragma unroll
    for (int s = 0; s < SPLIT; ++s) {
      cw[qs][s] = exp2f(mv[s] - mm) * lv[s];
      wsum += cw[qs][s];
    }
    const float invw = 1.0f / wsum;
#pragma unroll
    for (int s = 0; s < SPLIT; ++s) cw[qs][s] *= invw;
  }

  f32x4 acc[2][4];
#pragma unroll
  for (int qs = 0; qs < 2; ++qs)
#pragma unroll
    for (int nt = 0; nt < 4; ++nt) acc[qs][nt] = f32x4{0.f, 0.f, 0.f, 0.f};

#pragma unroll
  for (int kc = 0; kc < D; kc += 32) {
    f16x8 ah[2], bw[4];
#pragma unroll
    for (int qs = 0; qs < 2; ++qs) {
      const size_t off = (size_t)(m0 + qs * 16 + lrow) * D + kc + lhi * 8;
      float v[8] = {};
#pragma unroll
      for (int s = 0; s < SPLIT; ++s) {
        const f16x8 ps = *(const f16x8*)(pob + (size_t)s * BN * D + off);
        const float c = cw[qs][s];
#pragma unroll
        for (int j = 0; j < 8; ++j) v[j] += c * (float)ps[j];
      }
      f16x8 a;
#pragma unroll
      for (int j = 0; j < 8; ++j) a[j] = (_Float16)v[j];
      ah[qs] = a;
    }
#pragma unroll
    for (int nt = 0; nt < 4; ++nt)
      bw[nt] = *(const f16x8*)(wot + (size_t)(c0 + nt * 16 + lrow) * D + kc +
                               lhi * 8);
#pragma unroll
    for (int qs = 0; qs < 2; ++qs)
#pragma unroll
      for (int nt = 0; nt < 4; ++nt)
        acc[qs][nt] = mfma_f16(ah[qs], bw[nt], acc[qs][nt]);
  }
#pragma unroll
  for (int qs = 0; qs < 2; ++qs)
#pragma unroll
    for (int nt = 0; nt < 4; ++nt)
#pragma unroll
      for (int i = 0; i < 4; ++i) {
        const int row = m0 + qs * 16 + lhi * 4 + i;
        const int col = c0 + nt * 16 + lrow;
        out[(size_t)row * D + col] = acc[qs][nt][i] + bias[col];
      }
}

extern "C" void kernel_launch(void* const* d_in, const int* in_sizes, int n_in,
                              void* d_out, int out_size, void* d_ws, size_t ws_size,
                              hipStream_t stream) {
  const float* x = (const float*)d_in[0];
  const float* coord = (const float*)d_in[1];
  const float* ln_g = (const float*)d_in[2];
  const float* ln_b = (const float*)d_in[3];
  const float* w_qkv = (const float*)d_in[4];
  const float* w_out = (const float*)d_in[5];
  const float* b_out = (const float*)d_in[6];
  float* out = (float*)d_out;

  const size_t P = (size_t)BN * D;

  ushort* qfp = (ushort*)d_ws;
  ushort* kfp = qfp + P;
  ushort* vtp = kfp + P;
  ushort* pob = vtp + P;                      // SPLIT partial-O planes
  float* mlb = (float*)(pob + (size_t)SPLIT * P);
  ushort* wt = (ushort*)(mlb + (size_t)SPLIT * BN * 2);
  ushort* wot = wt + 768 * 256;
  // alias (liveness-disjoint):
  ushort* nxh = pob;       // written by ln, consumed by qkv, dead before attn

  hipLaunchKernelGGL(lncast_kernel, dim3(BN / 8), dim3(256), 0, stream,
                     x, ln_g, ln_b, nxh, w_qkv, w_out, wt, wot);
  hipLaunchKernelGGL(qkv_kernel, dim3(BN / 128, 12), dim3(256), 0, stream,
                     nxh, wt, coord, qfp, kfp, vtp);
  hipLaunchKernelGGL(attn_kernel, dim3(N / 256, B, SPLIT), dim3(512), 0,
                     stream, qfp, kfp, vtp, pob, mlb);
  hipLaunchKernelGGL(projm_kernel, dim3(BN / 128, 4), dim3(256), 0, stream,
                     pob, mlb, wot, b_out, out);
}

// Round 25
// 168.769 us; speedup vs baseline: 1.6841x; 1.0098x over previous
//
#include <hip/hip_runtime.h>
#include <hip/hip_fp16.h>
#include <math.h>

constexpr int B = 4, N = 4096, D = 256;
constexpr int BN = B * N;
constexpr float EPS = 1e-5f;
// softmax scale (D^-0.5 = 1/16) * log2(e), folded into q at f16-cast time
constexpr float QSC2 = 0.0625f * 1.44269504088896340736f;

constexpr int SPLIT = 4;     // KV splits -> grid 256 blocks (1/CU)
constexpr int KVB = 32;      // keys per attn tile
constexpr int NTK = (N / SPLIT) / KVB;  // 32 tiles
constexpr float THR = 8.0f;  // defer-max threshold (base-2)

typedef __attribute__((ext_vector_type(8))) _Float16 f16x8;
typedef __attribute__((ext_vector_type(2))) __fp16 fp16x2;
typedef __attribute__((ext_vector_type(4))) float f32x4;
typedef __attribute__((ext_vector_type(16))) float f32x16;

__device__ inline f32x4 mfma_f16(f16x8 a, f16x8 b, f32x4 c) {
  return __builtin_amdgcn_mfma_f32_16x16x32_f16(a, b, c, 0, 0, 0);
}
__device__ inline f32x16 mfma32(f16x8 a, f16x8 b, f32x16 c) {
  return __builtin_amdgcn_mfma_f32_32x32x16_f16(a, b, c, 0, 0, 0);
}
__device__ inline ushort f2h(float x) {
  __half h = __float2half(x);
  return *(ushort*)&h;
}
__device__ inline float h2f(ushort u) {
  __half h;
  *(ushort*)&h = u;
  return __half2float(h);
}
__device__ inline unsigned pkh(float a, float b) {
  fp16x2 r = __builtin_amdgcn_cvt_pkrtz(a, b);
  return *(unsigned*)&r;
}
// async global->LDS, 16B per lane; lds dest = uniform base + lane*16 (HW rule)
__device__ inline void gload16(const ushort* g, ushort* l) {
  __builtin_amdgcn_global_load_lds(
      (const __attribute__((address_space(1))) void*)g,
      (__attribute__((address_space(3))) void*)l, 16, 0, 0);
}

// ---- LayerNorm (8 rows/block, vectorized) + folded weight cast/transpose --
__global__ __launch_bounds__(256) void lncast_kernel(
    const float* __restrict__ x, const float* __restrict__ g,
    const float* __restrict__ bta, ushort* __restrict__ nxh,
    const float* __restrict__ w_qkv, const float* __restrict__ w_out,
    ushort* __restrict__ wt, ushort* __restrict__ wot) {
  const int tid = threadIdx.x;
  const int lane = tid & 63;
  const int row = blockIdx.x * 8 + (tid >> 6) * 2 + (lane >> 5);
  const int e0 = (lane & 31) * 8;
  const float4 a = *(const float4*)&x[(size_t)row * D + e0];
  const float4 bv = *(const float4*)&x[(size_t)row * D + e0 + 4];
  float s = a.x + a.y + a.z + a.w + bv.x + bv.y + bv.z + bv.w;
  float ss = a.x * a.x + a.y * a.y + a.z * a.z + a.w * a.w +
             bv.x * bv.x + bv.y * bv.y + bv.z * bv.z + bv.w * bv.w;
#pragma unroll
  for (int off = 1; off < 32; off <<= 1) {
    s += __shfl_xor(s, off);
    ss += __shfl_xor(ss, off);
  }
  const float mu = s * (1.0f / D);
  const float rsig = rsqrtf(ss * (1.0f / D) - mu * mu + EPS);
  const float4 g0 = *(const float4*)&g[e0];
  const float4 g1 = *(const float4*)&g[e0 + 4];
  const float4 b0 = *(const float4*)&bta[e0];
  const float4 b1 = *(const float4*)&bta[e0 + 4];
  f16x8 r;
  r[0] = (_Float16)((a.x - mu) * rsig * g0.x + b0.x);
  r[1] = (_Float16)((a.y - mu) * rsig * g0.y + b0.y);
  r[2] = (_Float16)((a.z - mu) * rsig * g0.z + b0.z);
  r[3] = (_Float16)((a.w - mu) * rsig * g0.w + b0.w);
  r[4] = (_Float16)((bv.x - mu) * rsig * g1.x + b1.x);
  r[5] = (_Float16)((bv.y - mu) * rsig * g1.y + b1.y);
  r[6] = (_Float16)((bv.z - mu) * rsig * g1.z + b1.z);
  r[7] = (_Float16)((bv.w - mu) * rsig * g1.w + b1.w);
  *(f16x8*)&nxh[(size_t)row * D + e0] = r;

  if (blockIdx.x < 1024) {
    const int id = blockIdx.x * 256 + tid;
    if (id < 768 * 256) {
      const int n = id >> 8, k = id & 255;
      wt[id] = f2h(w_qkv[(size_t)k * 768 + n]);
    } else {
      const int j = id - 768 * 256;
      const int n = j >> 8, k = j & 255;
      wot[j] = f2h(w_out[(size_t)k * 256 + n]);
    }
  }
}

// ---------------- QKV GEMM via MFMA (no LDS for A/W; weights L2-hot) -------
// Round-25: 128-col tiles (grid y 12 -> 6) halve A re-reads (~100MB -> 50MB
// through L2). 128-col tiles never cross a q/k/v region boundary (regions
// are 256-aligned; tiles sit at c0 = 0,128 within each region).
__global__ __launch_bounds__(256, 4) void qkv_kernel(
    const ushort* __restrict__ nxh, const ushort* __restrict__ wt,
    const float* __restrict__ coord, ushort* __restrict__ qfp,
    ushort* __restrict__ kfp, ushort* __restrict__ vtp) {
  __shared__ ushort vs[128 * 132];  // [col 0..127][n 0..127], stride 132
  const int t = threadIdx.x;
  const int w = t >> 6, lane = t & 63;
  const int lrow = lane & 15, lhi = lane >> 4;
  const int m0 = blockIdx.x * 128 + w * 32;
  const int c0 = blockIdx.y * 128;  // within [0,768)
  f32x4 acc[2][8];
#pragma unroll
  for (int qs = 0; qs < 2; ++qs)
#pragma unroll
    for (int nt = 0; nt < 8; ++nt) acc[qs][nt] = f32x4{0.f, 0.f, 0.f, 0.f};

#pragma unroll
  for (int kc = 0; kc < D; kc += 32) {
    f16x8 ah[2], bw[8];
#pragma unroll
    for (int qs = 0; qs < 2; ++qs)
      ah[qs] = *(const f16x8*)(nxh + (size_t)(m0 + qs * 16 + lrow) * D + kc +
                               lhi * 8);
#pragma unroll
    for (int nt = 0; nt < 8; ++nt)
      bw[nt] = *(const f16x8*)(wt + (size_t)(c0 + nt * 16 + lrow) * D + kc +
                               lhi * 8);
#pragma unroll
    for (int qs = 0; qs < 2; ++qs)
#pragma unroll
      for (int nt = 0; nt < 8; ++nt)
        acc[qs][nt] = mfma_f16(ah[qs], bw[nt], acc[qs][nt]);
  }

  const int region = c0 >> 8;  // 0:q 1:k 2:v (uniform per block)
  const int cbase = c0 & 255;
  if (region < 2) {
    const float sc = (region == 0) ? QSC2 : 1.0f;
    ushort* dp = (region == 0) ? qfp : kfp;
#pragma unroll
    for (int qs = 0; qs < 2; ++qs)
#pragma unroll
      for (int nt = 0; nt < 8; ++nt)
#pragma unroll
        for (int i = 0; i < 4; ++i) {
          const int row = m0 + qs * 16 + lhi * 4 + i;
          const int col = cbase + nt * 16 + lrow;
          const float val =
              (acc[qs][nt][i] + coord[(size_t)row * D + col]) * sc;
          dp[(size_t)row * D + col] = f2h(val);
        }
  } else {
    // stage into LDS: vs[col][n], col = nt*16+lrow (0..127),
    // n = w*32 + qs*16 + lhi*4 + i
#pragma unroll
    for (int qs = 0; qs < 2; ++qs)
#pragma unroll
      for (int nt = 0; nt < 8; ++nt) {
        ushort4 pk;
        pk.x = f2h(acc[qs][nt][0]);
        pk.y = f2h(acc[qs][nt][1]);
        pk.z = f2h(acc[qs][nt][2]);
        pk.w = f2h(acc[qs][nt][3]);
        *(ushort4*)&vs[(nt * 16 + lrow) * 132 + w * 32 + qs * 16 + lhi * 4] =
            pk;
      }
    __syncthreads();
    // coalesced write: thread -> 64 consecutive n of one col (128B).
    // Base is BLOCK-uniform.
    const int c = t >> 1, seg = (t & 1) * 64;
    const int nb0 = blockIdx.x * 128;
    const int bb = nb0 >> 12, nb = nb0 & (N - 1);
    ushort* dst = vtp + ((size_t)bb * D + cbase + c) * N + nb + seg;
    const ushort* src = &vs[c * 132 + seg];
#pragma unroll
    for (int k2 = 0; k2 < 16; ++k2)
      *(uint2*)(dst + k2 * 4) = *(const uint2*)(src + k2 * 4);
  }
}

// ---------------- MFMA flash attention (32x32 swapped-operand) -------------
// 8 warps x 32 q-rows (block = 256 rows), KVB=32 keys/tile, SPLIT=4.
// QUAD-buffered K/V staging (128KB LDS), ONE s_barrier per tile, rolled loop,
// T15 deferred-PV pipeline, full-width K swizzle, all-16 persistent Q.
// FROZEN since round 24 (105us, MfmaUtil 27.5%, VALU 31%).
__global__ __launch_bounds__(512, 2) void attn_kernel(
    const ushort* __restrict__ qf, const ushort* __restrict__ kf,
    const ushort* __restrict__ vt, ushort* __restrict__ pob,
    float* __restrict__ mlb) {
  __shared__ ushort kbuf[4][8192];  // [key 0..31][32 granules]    16KB each
  __shared__ ushort vbuf[4][8192];  // [d-pair 0..127][8 granules] 16KB each

  const int tid = threadIdx.x;
  const int lane = tid & 63;
  const int q = lane & 31, h = lane >> 5;
  const int w = tid >> 6;
  const int b = blockIdx.y, s = blockIdx.z;
  const int qw = blockIdx.x * 256 + w * 32;
  const int kbeg = s * (N / SPLIT);

  const ushort* qrow = qf + ((size_t)b * N + qw + q) * D;
  const ushort* kfb = kf + (size_t)b * N * D;
  const ushort* vtb = vt + (size_t)b * D * N;
  ushort* pog = pob + (size_t)s * BN * D;
  float* mlg = mlb + (size_t)s * BN * 2;

  // ALL 16 Q chunks persistent (d 0..255)
  f16x8 qfr[16];
#pragma unroll
  for (int c = 0; c < 16; ++c)
    qfr[c] = *(const f16x8*)(qrow + c * 16 + h * 8);

  f32x16 o[8];
#pragma unroll
  for (int dt = 0; dt < 8; ++dt)
#pragma unroll
    for (int r = 0; r < 16; ++r) o[dt][r] = 0.f;
  float m = -1e30f, lsum = 0.f;
  float f_prev = 1.0f;
  bool need_prev = false;
  f16x8 pf_prev[2];

  // stage one 32-key K+V tile; 4 granule-loads per thread (2 K + 2 V).
  // K: granule G -> key=G>>5, slot=G&31; src d-gran = slot^key (full width)
  // V: granule G -> r=G>>3, slot=G&7; u=slot^(r&7); d=2r+(u>>2); sg=u&3
  auto stage = [&](int bi, int k0) {
#pragma unroll
    for (int i = 0; i < 2; ++i) {
      const int g = i * 512 + tid;
      const int key = g >> 5, slot = g & 31;
      gload16(kfb + (size_t)(k0 + key) * D + ((slot ^ key) * 8),
              &kbuf[bi][g * 8]);
    }
#pragma unroll
    for (int i = 0; i < 2; ++i) {
      const int g = i * 512 + tid;
      const int r = g >> 3, slot = g & 7;
      const int u = slot ^ (r & 7);
      const int d = r * 2 + (u >> 2);
      gload16(vtb + (size_t)d * N + k0 + ((u & 3) * 8), &vbuf[bi][g * 8]);
    }
  };

  stage(0, kbeg);

  for (int t = 0; t < NTK; ++t) {
    const int cur = t & 3;
    const int prv = (t + 3) & 3;
    if (t + 1 < NTK) {
      stage((t + 1) & 3, kbeg + (t + 1) * KVB);
      asm volatile("s_waitcnt vmcnt(4)" ::: "memory");  // drain stage(t)
    } else {
      asm volatile("s_waitcnt vmcnt(0)" ::: "memory");
    }
    __builtin_amdgcn_sched_barrier(0);
    __builtin_amdgcn_s_barrier();   // the ONLY barrier per tile
    __builtin_amdgcn_sched_barrier(0);

    // ---- QK(t): S^T = K Q, single 16-MFMA chain into p ----
    f32x16 p;
#pragma unroll
    for (int r = 0; r < 16; ++r) p[r] = 0.f;
    __builtin_amdgcn_s_setprio(1);
#pragma unroll
    for (int c = 0; c < 16; ++c) {
      const f16x8 ka = *(const f16x8*)&kbuf[cur][q * 256 +
                                                 (((c * 2 + h) ^ q) * 8)];
      p = mfma32(ka, qfr[c], p);
    }
    __builtin_amdgcn_s_setprio(0);

    // ---- deferred: rescale o by f(t-1), then PV(t-1) ----
    if (t > 0) {
      if (need_prev) {
#pragma unroll
        for (int dt = 0; dt < 8; ++dt) o[dt] *= f_prev;
      }
      __builtin_amdgcn_s_setprio(1);
#pragma unroll
      for (int dt = 0; dt < 8; ++dt) {
        const int d = dt * 32 + q;
        const int rr = d >> 1;
#pragma unroll
        for (int kk = 0; kk < 2; ++kk) {
          const int u = (d & 1) * 4 + kk * 2 + h;
          const f16x8 vf = *(const f16x8*)&vbuf[prv][rr * 64 +
                                                     ((u ^ (rr & 7)) * 8)];
          o[dt] = mfma32(vf, pf_prev[kk], o[dt]);
        }
      }
      __builtin_amdgcn_s_setprio(0);
    }

    // ---- softmax(t): runs while PV(t-1) drains the matrix pipe ----
    float tm[8];
#pragma unroll
    for (int j = 0; j < 8; ++j) tm[j] = fmaxf(p[2 * j], p[2 * j + 1]);
    float pmax = fmaxf(fmaxf(fmaxf(tm[0], tm[1]), fmaxf(tm[2], tm[3])),
                       fmaxf(fmaxf(tm[4], tm[5]), fmaxf(tm[6], tm[7])));
    const float pm = fmaxf(pmax, __shfl_xor(pmax, 32));
    const bool need = pm > m + THR;
    if (__any(need)) {
      const float mn = fmaxf(m, pm);
      f_prev = exp2f(m - mn);
      m = mn;
      lsum *= f_prev;
      need_prev = true;
    } else {
      need_prev = false;
    }
#pragma unroll
    for (int r = 0; r < 16; ++r) {
      p[r] = exp2f(p[r] - m);
      lsum += p[r];
    }

    // ---- pack P -> pf_prev: cvt_pkrtz + PRE-SELECTED exchange (2 shfls/kk)
#pragma unroll
    for (int kk = 0; kk < 2; ++kk) {
      const int sub = kk * 8;
      const unsigned x = pkh(p[sub + 0], p[sub + 1]);
      const unsigned z = pkh(p[sub + 2], p[sub + 3]);
      const unsigned y = pkh(p[sub + 4], p[sub + 5]);
      const unsigned wv = pkh(p[sub + 6], p[sub + 7]);
      const unsigned e1 = h ? x : y;   // value the partner needs (slot A)
      const unsigned e2 = h ? z : wv;  // value the partner needs (slot B)
      const unsigned r1 = __shfl_xor(e1, 32);  // h0: partner-x ; h1: partner-y
      const unsigned r2 = __shfl_xor(e2, 32);  // h0: partner-z ; h1: partner-wv
      union { f16x8 v; unsigned u[4]; } pu;
      pu.u[0] = h ? r1 : x;
      pu.u[1] = h ? r2 : z;
      pu.u[2] = h ? y : r1;
      pu.u[3] = h ? wv : r2;
      pf_prev[kk] = pu.v;
    }
  }

  // ---- epilogue: final rescale + PV(NTK-1), then normalize & write ----
  if (need_prev) {
#pragma unroll
    for (int dt = 0; dt < 8; ++dt) o[dt] *= f_prev;
  }
  {
    const int prv = (NTK - 1) & 3;
#pragma unroll
    for (int dt = 0; dt < 8; ++dt) {
      const int d = dt * 32 + q;
      const int rr = d >> 1;
#pragma unroll
      for (int kk = 0; kk < 2; ++kk) {
        const int u = (d & 1) * 4 + kk * 2 + h;
        const f16x8 vf = *(const f16x8*)&vbuf[prv][rr * 64 +
                                                   ((u ^ (rr & 7)) * 8)];
        o[dt] = mfma32(vf, pf_prev[kk], o[dt]);
      }
    }
  }
  const float lt = lsum + __shfl_xor(lsum, 32);
  const float inv = 1.0f / lt;
  ushort* orow = pog + ((size_t)b * N + qw + q) * D;
#pragma unroll
  for (int dt = 0; dt < 8; ++dt)
#pragma unroll
    for (int r4 = 0; r4 < 4; ++r4) {
      const unsigned u0 =
          pkh(o[dt][r4 * 4 + 0] * inv, o[dt][r4 * 4 + 1] * inv);
      const unsigned u1 =
          pkh(o[dt][r4 * 4 + 2] * inv, o[dt][r4 * 4 + 3] * inv);
      uint2 val;
      val.x = u0;
      val.y = u1;
      *(uint2*)(orow + dt * 32 + r4 * 8 + h * 4) = val;
    }
  if (h == 0) {
    const size_t r = (size_t)b * N + qw + q;
    mlg[r * 2] = m;
    mlg[r * 2 + 1] = lt;
  }
}

// -------- fused merge + output projection via MFMA --------------
__global__ __launch_bounds__(256, 4) void projm_kernel(
    const ushort* __restrict__ pob, const float* __restrict__ mlb,
    const ushort* __restrict__ wot, const float* __restrict__ bias,
    float* __restrict__ out) {
  const int t = threadIdx.x;
  const int w = t >> 6, lane = t & 63;
  const int lrow = lane & 15, lhi = lane >> 4;
  const int m0 = blockIdx.x * 128 + w * 32;
  const int c0 = blockIdx.y * 64;

  // per-thread merge weights for rows m0+lrow, m0+16+lrow
  float cw[2][SPLIT];
#pragma unroll
  for (int qs = 0; qs < 2; ++qs) {
    const int row = m0 + qs * 16 + lrow;
    float mv[SPLIT], lv[SPLIT], mm = -1e30f;
#pragma unroll
    for (int s = 0; s < SPLIT; ++s) {
      mv[s] = mlb[(size_t)s * BN * 2 + row * 2];
      lv[s] = mlb[(size_t)s * BN * 2 + row * 2 + 1];
      mm = fmaxf(mm, mv[s]);
    }
    float wsum = 0.f;
#pragma unroll
    for (int s = 0; s < SPLIT; ++s) {
      cw[qs][s] = exp2f(mv[s] - mm) * lv[s];
      wsum += cw[qs][s];
    }
    const float invw = 1.0f / wsum;
#pragma unroll
    for (int s = 0; s < SPLIT; ++s) cw[qs][s] *= invw;
  }

  f32x4 acc[2][4];
#pragma unroll
  for (int qs = 0; qs < 2; ++qs)
#pragma unroll
    for (int nt = 0; nt < 4; ++nt) acc[qs][nt] = f32x4{0.f, 0.f, 0.f, 0.f};

#pragma unroll
  for (int kc = 0; kc < D; kc += 32) {
    f16x8 ah[2], bw[4];
#pragma unroll
    for (int qs = 0; qs < 2; ++qs) {
      const size_t off = (size_t)(m0 + qs * 16 + lrow) * D + kc + lhi * 8;
      float v[8] = {};
#pragma unroll
      for (int s = 0; s < SPLIT; ++s) {
        const f16x8 ps = *(const f16x8*)(pob + (size_t)s * BN * D + off);
        const float c = cw[qs][s];
#pragma unroll
        for (int j = 0; j < 8; ++j) v[j] += c * (float)ps[j];
      }
      f16x8 a;
#pragma unroll
      for (int j = 0; j < 8; ++j) a[j] = (_Float16)v[j];
      ah[qs] = a;
    }
#pragma unroll
    for (int nt = 0; nt < 4; ++nt)
      bw[nt] = *(const f16x8*)(wot + (size_t)(c0 + nt * 16 + lrow) * D + kc +
                               lhi * 8);
#pragma unroll
    for (int qs = 0; qs < 2; ++qs)
#pragma unroll
      for (int nt = 0; nt < 4; ++nt)
        acc[qs][nt] = mfma_f16(ah[qs], bw[nt], acc[qs][nt]);
  }
#pragma unroll
  for (int qs = 0; qs < 2; ++qs)
#pragma unroll
    for (int nt = 0; nt < 4; ++nt)
#pragma unroll
      for (int i = 0; i < 4; ++i) {
        const int row = m0 + qs * 16 + lhi * 4 + i;
        const int col = c0 + nt * 16 + lrow;
        out[(size_t)row * D + col] = acc[qs][nt][i] + bias[col];
      }
}

extern "C" void kernel_launch(void* const* d_in, const int* in_sizes, int n_in,
                              void* d_out, int out_size, void* d_ws, size_t ws_size,
                              hipStream_t stream) {
  const float* x = (const float*)d_in[0];
  const float* coord = (const float*)d_in[1];
  const float* ln_g = (const float*)d_in[2];
  const float* ln_b = (const float*)d_in[3];
  const float* w_qkv = (const float*)d_in[4];
  const float* w_out = (const float*)d_in[5];
  const float* b_out = (const float*)d_in[6];
  float* out = (float*)d_out;

  const size_t P = (size_t)BN * D;

  ushort* qfp = (ushort*)d_ws;
  ushort* kfp = qfp + P;
  ushort* vtp = kfp + P;
  ushort* pob = vtp + P;                      // SPLIT partial-O planes
  float* mlb = (float*)(pob + (size_t)SPLIT * P);
  ushort* wt = (ushort*)(mlb + (size_t)SPLIT * BN * 2);
  ushort* wot = wt + 768 * 256;
  // alias (liveness-disjoint):
  ushort* nxh = pob;       // written by ln, consumed by qkv, dead before attn

  hipLaunchKernelGGL(lncast_kernel, dim3(BN / 8), dim3(256), 0, stream,
                     x, ln_g, ln_b, nxh, w_qkv, w_out, wt, wot);
  hipLaunchKernelGGL(qkv_kernel, dim3(BN / 128, 6), dim3(256), 0, stream,
                     nxh, wt, coord, qfp, kfp, vtp);
  hipLaunchKernelGGL(attn_kernel, dim3(N / 256, B, SPLIT), dim3(512), 0,
                     stream, qfp, kfp, vtp, pob, mlb);
  hipLaunchKernelGGL(projm_kernel, dim3(BN / 128, 4), dim3(256), 0, stream,
                     pob, mlb, wot, b_out, out);
}